// Round 1
// baseline (1846.654 us; speedup 1.0000x reference)
//
#include <hip/hip_runtime.h>
#include <hip/hip_bf16.h>
#include <math.h>

#define NN 100000
#define EE 1600000
#define BB 256
#define DD 128

// ---------------------------------------------------------------- LayerNorm
__global__ __launch_bounds__(256) void ln_kernel(const float* __restrict__ x,
                                                 const float* __restrict__ g,
                                                 const float* __restrict__ b,
                                                 float* __restrict__ xn) {
    int node = (blockIdx.x * 256 + threadIdx.x) >> 6;
    int lane = threadIdx.x & 63;
    if (node >= NN) return;
    float2 v = *(const float2*)(x + (size_t)node * 128 + lane * 2);
    float s = v.x + v.y;
    float sq = v.x * v.x + v.y * v.y;
    #pragma unroll
    for (int m = 1; m < 64; m <<= 1) { s += __shfl_xor(s, m); sq += __shfl_xor(sq, m); }
    float mu = s * (1.0f / 128.0f);
    float var = sq * (1.0f / 128.0f) - mu * mu;
    float rs = rsqrtf(var + 1e-5f);
    float2 gg = *(const float2*)(g + lane * 2);
    float2 bb = *(const float2*)(b + lane * 2);
    float2 o;
    o.x = (v.x - mu) * rs * gg.x + bb.x;
    o.y = (v.y - mu) * rs * gg.y + bb.y;
    *(float2*)(xn + (size_t)node * 128 + lane * 2) = o;
}

// ---------------------------------------------------------------- GEMM [N,128]x[128,128]
// ACT: 0 = none, 1 = leaky_relu(0.01)
template <int ACT>
__global__ __launch_bounds__(256) void gemm128(const float* __restrict__ A,
                                               const float* __restrict__ W,
                                               const float* __restrict__ bias,
                                               float* __restrict__ Out) {
    __shared__ float Ws[64 * 128];   // 32 KB chunk of W
    __shared__ float As[32 * 128];   // 16 KB tile of A
    int tid = threadIdx.x;
    int row0 = blockIdx.x * 32;

    // load A tile (32 rows)
    const float4* A4 = (const float4*)(A + (size_t)row0 * 128);
    float4* As4 = (float4*)As;
    #pragma unroll
    for (int i = 0; i < 4; i++) As4[tid + 256 * i] = A4[tid + 256 * i];

    int c4 = (tid & 31) * 4;
    int r0 = (tid >> 5) * 4;
    float acc[4][4];
    float4 bb = bias ? *(const float4*)(bias + c4) : make_float4(0.f, 0.f, 0.f, 0.f);
    #pragma unroll
    for (int r = 0; r < 4; r++) { acc[r][0] = bb.x; acc[r][1] = bb.y; acc[r][2] = bb.z; acc[r][3] = bb.w; }

    for (int kc = 0; kc < 128; kc += 64) {
        __syncthreads();
        const float4* W4 = (const float4*)(W + (size_t)kc * 128);
        float4* Ws4 = (float4*)Ws;
        #pragma unroll
        for (int i = 0; i < 8; i++) Ws4[tid + 256 * i] = W4[tid + 256 * i];
        __syncthreads();
        #pragma unroll 4
        for (int k = 0; k < 64; k += 4) {
            float4 wq[4];
            #pragma unroll
            for (int kk = 0; kk < 4; kk++) wq[kk] = *(const float4*)(Ws + (k + kk) * 128 + c4);
            #pragma unroll
            for (int r = 0; r < 4; r++) {
                float4 a = *(const float4*)(As + (r0 + r) * 128 + kc + k);
                float av[4] = {a.x, a.y, a.z, a.w};
                #pragma unroll
                for (int kk = 0; kk < 4; kk++) {
                    acc[r][0] = fmaf(av[kk], wq[kk].x, acc[r][0]);
                    acc[r][1] = fmaf(av[kk], wq[kk].y, acc[r][1]);
                    acc[r][2] = fmaf(av[kk], wq[kk].z, acc[r][2]);
                    acc[r][3] = fmaf(av[kk], wq[kk].w, acc[r][3]);
                }
            }
        }
    }
    #pragma unroll
    for (int r = 0; r < 4; r++) {
        float4 o = make_float4(acc[r][0], acc[r][1], acc[r][2], acc[r][3]);
        if (ACT == 1) {
            o.x = o.x > 0.f ? o.x : 0.01f * o.x;
            o.y = o.y > 0.f ? o.y : 0.01f * o.y;
            o.z = o.z > 0.f ? o.z : 0.01f * o.z;
            o.w = o.w > 0.f ? o.w : 0.01f * o.w;
        }
        *(float4*)(Out + (size_t)(row0 + r0 + r) * 128 + c4) = o;
    }
}

// ---------------------------------------------------------------- attention scalars a_src/a_dst
__global__ __launch_bounds__(256) void att_kernel(const float* __restrict__ xh,
                                                  const float* __restrict__ asw,
                                                  const float* __restrict__ adw,
                                                  float* __restrict__ a_src,
                                                  float* __restrict__ a_dst) {
    int node = (blockIdx.x * 256 + threadIdx.x) >> 6;
    int lane = threadIdx.x & 63;
    if (node >= NN) return;
    int h = lane >> 4, c = lane & 15;
    int base = h * 32 + c;
    float x1 = xh[(size_t)node * 128 + base];
    float x2 = xh[(size_t)node * 128 + base + 16];
    float ps = x1 * asw[base] + x2 * asw[base + 16];
    float pd = x1 * adw[base] + x2 * adw[base + 16];
    #pragma unroll
    for (int m = 1; m < 16; m <<= 1) { ps += __shfl_xor(ps, m); pd += __shfl_xor(pd, m); }
    if (c == 0) {
        a_src[node * 4 + h] = ps;
        a_dst[node * 4 + h] = pd;
    }
}

// ---------------------------------------------------------------- CSR build
__global__ __launch_bounds__(256) void count_kernel(const int* __restrict__ ei, int* __restrict__ deg) {
    int e = blockIdx.x * 256 + threadIdx.x;
    if (e < EE) atomicAdd(&deg[ei[EE + e]], 1);
}

__global__ __launch_bounds__(256) void offsets_kernel(const int* __restrict__ deg,
                                                      int* __restrict__ counter,
                                                      int* __restrict__ start) {
    int n = blockIdx.x * 256 + threadIdx.x;
    int lane = threadIdx.x & 63;
    int d = (n < NN) ? deg[n] : 0;
    int incl = d;
    #pragma unroll
    for (int m = 1; m < 64; m <<= 1) {
        int t = __shfl_up(incl, m);
        if (lane >= m) incl += t;
    }
    int total = __shfl(incl, 63);
    int base = 0;
    if (lane == 0) base = atomicAdd(counter, total);
    base = __shfl(base, 0);
    if (n < NN) start[n] = base + incl - d;
}

__global__ __launch_bounds__(256) void fill_kernel(const int* __restrict__ ei,
                                                   const int* __restrict__ start,
                                                   int* __restrict__ cursor,
                                                   int* __restrict__ ebuf) {
    int e = blockIdx.x * 256 + threadIdx.x;
    if (e < EE) {
        int s = ei[e];
        int d = ei[EE + e];
        int pos = start[d] + atomicAdd(&cursor[d], 1);
        ebuf[pos] = s;
    }
}

// ---------------------------------------------------------------- GAT aggregate (wave per dst node)
__global__ __launch_bounds__(256) void aggregate_kernel(const float* __restrict__ xh,
                                                        const float* __restrict__ a_src,
                                                        const float* __restrict__ a_dst,
                                                        const int* __restrict__ start,
                                                        const int* __restrict__ deg,
                                                        const int* __restrict__ ebuf,
                                                        const float* __restrict__ bias,
                                                        const float* __restrict__ gw,
                                                        const float* __restrict__ gb,
                                                        float* __restrict__ hv,
                                                        float* __restrict__ gexpv) {
    int node = (blockIdx.x * 256 + threadIdx.x) >> 6;
    int lane = threadIdx.x & 63;
    if (node >= NN) return;
    int h = lane >> 4;  // channel pair 2*lane, head = (2*lane)>>5
    float ad = a_dst[node * 4 + h];
    int st = start[node];
    int cnt = deg[node];

    float accx = 0.f, accy = 0.f, den = 0.f;
    // self loop
    {
        float t = a_src[node * 4 + h] + ad;
        t = t > 0.f ? t : 0.2f * t;
        float e = expf(t);
        float2 xv = *(const float2*)(xh + (size_t)node * 128 + lane * 2);
        den += e; accx += e * xv.x; accy += e * xv.y;
    }
    for (int j = 0; j < cnt; j++) {
        int src = ebuf[st + j];
        float t = a_src[src * 4 + h] + ad;
        t = t > 0.f ? t : 0.2f * t;
        float e = expf(t);
        float2 xv = *(const float2*)(xh + (size_t)src * 128 + lane * 2);
        den += e; accx += e * xv.x; accy += e * xv.y;
    }
    float inv = 1.0f / den;
    float2 bb = *(const float2*)(bias + lane * 2);
    float o0 = accx * inv + bb.x;
    float o1 = accy * inv + bb.y;
    // ELU
    o0 = o0 > 0.f ? o0 : expf(o0) - 1.0f;
    o1 = o1 > 0.f ? o1 : expf(o1) - 1.0f;
    *(float2*)(hv + (size_t)node * 128 + lane * 2) = make_float2(o0, o1);
    // gate logit
    float2 g2 = *(const float2*)(gw + lane * 2);
    float gp = o0 * g2.x + o1 * g2.y;
    #pragma unroll
    for (int m = 1; m < 64; m <<= 1) gp += __shfl_xor(gp, m);
    if (lane == 0) gexpv[node] = expf(gp + gb[0]);
}

// ---------------------------------------------------------------- global-attention pool (block per graph)
__global__ __launch_bounds__(128) void pool_kernel(const float* __restrict__ hv,
                                                   const float* __restrict__ gexpv,
                                                   const int* __restrict__ batch,
                                                   float* __restrict__ gout,
                                                   int voff) {
    int b = blockIdx.x;
    int ch = threadIdx.x;
    // lower_bound(batch, b)
    int l = 0, r = NN;
    while (l < r) { int m = (l + r) >> 1; if (batch[m] < b) l = m + 1; else r = m; }
    int s0 = l;
    r = NN;
    while (l < r) { int m = (l + r) >> 1; if (batch[m] < b + 1) l = m + 1; else r = m; }
    int s1 = l;
    float acc = 0.f, wsum = 0.f;
    for (int n = s0; n < s1; n++) {
        float w = gexpv[n];
        wsum += w;
        acc += w * hv[(size_t)n * 128 + ch];
    }
    gout[b * 384 + voff + ch] = (s1 > s0) ? acc / wsum : 0.f;
}

// ---------------------------------------------------------------- classifier (block per graph)
__global__ __launch_bounds__(128) void clf_kernel(const float* __restrict__ gout,
                                                  const float* __restrict__ W1,
                                                  const float* __restrict__ b1,
                                                  const float* __restrict__ W2,
                                                  const float* __restrict__ b2,
                                                  float* __restrict__ out) {
    int b = blockIdx.x;
    int j = threadIdx.x;
    float acc = b1[j];
    for (int k = 0; k < 384; k++) acc = fmaf(gout[b * 384 + k], W1[k * 128 + j], acc);
    acc = acc > 0.f ? acc : 0.01f * acc;
    float p = acc * W2[j];
    #pragma unroll
    for (int m = 1; m < 64; m <<= 1) p += __shfl_xor(p, m);
    __shared__ float sh[2];
    if ((j & 63) == 0) sh[j >> 6] = p;
    __syncthreads();
    if (j == 0) out[b] = sh[0] + sh[1] + b2[0];
}

// ---------------------------------------------------------------- launch
extern "C" void kernel_launch(void* const* d_in, const int* in_sizes, int n_in,
                              void* d_out, int out_size, void* d_ws, size_t ws_size,
                              hipStream_t stream) {
    const float* x      = (const float*)d_in[0];
    const int*   ei[3]  = {(const int*)d_in[1], (const int*)d_in[2], (const int*)d_in[3]};
    const int*   batch  = (const int*)d_in[4];
    const float* ln_g   = (const float*)d_in[5];
    const float* ln_b   = (const float*)d_in[6];
    const float* proj_W = (const float*)d_in[7];
    const float* proj_b = (const float*)d_in[8];
    const float* Wv[3]  = {(const float*)d_in[9],  (const float*)d_in[13], (const float*)d_in[17]};
    const float* asv[3] = {(const float*)d_in[10], (const float*)d_in[14], (const float*)d_in[18]};
    const float* adv[3] = {(const float*)d_in[11], (const float*)d_in[15], (const float*)d_in[19]};
    const float* bv[3]  = {(const float*)d_in[12], (const float*)d_in[16], (const float*)d_in[20]};
    const float* gate_W = (const float*)d_in[21];
    const float* gate_b = (const float*)d_in[22];
    const float* clf_W1 = (const float*)d_in[23];
    const float* clf_b1 = (const float*)d_in[24];
    const float* clf_W2 = (const float*)d_in[25];
    const float* clf_b2 = (const float*)d_in[26];
    float* out = (float*)d_out;

    // workspace layout (floats)
    float* f = (float*)d_ws;
    float* xn    = f;                 // N*128 (aliased as hv later)
    float* h0    = f + 12800000;      // N*128
    float* xh    = f + 25600000;      // N*128
    float* a_src = f + 38400000;      // N*4
    float* a_dst = f + 38800000;      // N*4
    float* gexpv = f + 39200000;      // N
    float* gout  = f + 39300000;      // B*384
    int* ip      = (int*)(f + 39400000);
    int* deg     = ip;                // N
    int* cursor  = ip + 100000;       // N
    int* counter = ip + 200000;       // 1
    int* start   = ip + 200001;       // N
    int* ebuf    = ip + 300001;       // E
    float* hv    = xn;                // alias: xn dead after proj GEMM

    (void)in_sizes; (void)n_in; (void)out_size; (void)ws_size;

    // 1. LayerNorm
    ln_kernel<<<25000, 256, 0, stream>>>(x, ln_g, ln_b, xn);
    // 2. h0 = leaky(xn @ proj_W + proj_b)
    gemm128<1><<<3125, 256, 0, stream>>>(xn, proj_W, proj_b, h0);

    for (int v = 0; v < 3; v++) {
        // xh = h0 @ W_v
        gemm128<0><<<3125, 256, 0, stream>>>(h0, Wv[v], nullptr, xh);
        // per-node attention scalars
        att_kernel<<<25000, 256, 0, stream>>>(xh, asv[v], adv[v], a_src, a_dst);
        // CSR by destination
        hipMemsetAsync(ip, 0, (size_t)(200001) * sizeof(int), stream);
        count_kernel<<<6250, 256, 0, stream>>>(ei[v], deg);
        offsets_kernel<<<391, 256, 0, stream>>>(deg, counter, start);
        fill_kernel<<<6250, 256, 0, stream>>>(ei[v], start, cursor, ebuf);
        // fused softmax + message aggregation + bias + ELU + gate
        aggregate_kernel<<<25000, 256, 0, stream>>>(xh, a_src, a_dst, start, deg, ebuf,
                                                    bv[v], gate_W, gate_b, hv, gexpv);
        // global attention pooling (batch is sorted)
        pool_kernel<<<256, 128, 0, stream>>>(hv, gexpv, batch, gout, v * 128);
    }
    // classifier
    clf_kernel<<<256, 128, 0, stream>>>(gout, clf_W1, clf_b1, clf_W2, clf_b2, out);
}

// Round 2
// 1232.535 us; speedup vs baseline: 1.4983x; 1.4983x over previous
//
#include <hip/hip_runtime.h>
#include <hip/hip_bf16.h>
#include <math.h>

#define NN 100000
#define EE 1600000
#define BB 256
#define DD 128

__device__ __forceinline__ float bf2f(unsigned short u) {
    return __uint_as_float(((unsigned int)u) << 16);
}
__device__ __forceinline__ unsigned short f2bf(float f) {
    __hip_bfloat16 h = __float2bfloat16(f);   // RNE
    return *(unsigned short*)&h;
}

// ---------------------------------------------------------------- LayerNorm
__global__ __launch_bounds__(256) void ln_kernel(const float* __restrict__ x,
                                                 const float* __restrict__ g,
                                                 const float* __restrict__ b,
                                                 float* __restrict__ xn) {
    int node = (blockIdx.x * 256 + threadIdx.x) >> 6;
    int lane = threadIdx.x & 63;
    if (node >= NN) return;
    float2 v = *(const float2*)(x + (size_t)node * 128 + lane * 2);
    float s = v.x + v.y;
    float sq = v.x * v.x + v.y * v.y;
    #pragma unroll
    for (int m = 1; m < 64; m <<= 1) { s += __shfl_xor(s, m); sq += __shfl_xor(sq, m); }
    float mu = s * (1.0f / 128.0f);
    float var = sq * (1.0f / 128.0f) - mu * mu;
    float rs = rsqrtf(var + 1e-5f);
    float2 gg = *(const float2*)(g + lane * 2);
    float2 bb = *(const float2*)(b + lane * 2);
    float2 o;
    o.x = (v.x - mu) * rs * gg.x + bb.x;
    o.y = (v.y - mu) * rs * gg.y + bb.y;
    *(float2*)(xn + (size_t)node * 128 + lane * 2) = o;
}

// ---------------------------------------------------------------- GEMM [N,128]x[128,128]
// ACT: 0 = none, 1 = leaky_relu(0.01); OUTBF: 1 = write bf16 (ushort)
template <int ACT, int OUTBF>
__global__ __launch_bounds__(256) void gemm128(const float* __restrict__ A,
                                               const float* __restrict__ W,
                                               const float* __restrict__ bias,
                                               void* __restrict__ OutV) {
    __shared__ float Ws[64 * 128];
    __shared__ float As[32 * 128];
    int tid = threadIdx.x;
    int row0 = blockIdx.x * 32;

    const float4* A4 = (const float4*)(A + (size_t)row0 * 128);
    float4* As4 = (float4*)As;
    #pragma unroll
    for (int i = 0; i < 4; i++) As4[tid + 256 * i] = A4[tid + 256 * i];

    int c4 = (tid & 31) * 4;
    int r0 = (tid >> 5) * 4;
    float acc[4][4];
    float4 bb = bias ? *(const float4*)(bias + c4) : make_float4(0.f, 0.f, 0.f, 0.f);
    #pragma unroll
    for (int r = 0; r < 4; r++) { acc[r][0] = bb.x; acc[r][1] = bb.y; acc[r][2] = bb.z; acc[r][3] = bb.w; }

    for (int kc = 0; kc < 128; kc += 64) {
        __syncthreads();
        const float4* W4 = (const float4*)(W + (size_t)kc * 128);
        float4* Ws4 = (float4*)Ws;
        #pragma unroll
        for (int i = 0; i < 8; i++) Ws4[tid + 256 * i] = W4[tid + 256 * i];
        __syncthreads();
        #pragma unroll 4
        for (int k = 0; k < 64; k += 4) {
            float4 wq[4];
            #pragma unroll
            for (int kk = 0; kk < 4; kk++) wq[kk] = *(const float4*)(Ws + (k + kk) * 128 + c4);
            #pragma unroll
            for (int r = 0; r < 4; r++) {
                float4 a = *(const float4*)(As + (r0 + r) * 128 + kc + k);
                float av[4] = {a.x, a.y, a.z, a.w};
                #pragma unroll
                for (int kk = 0; kk < 4; kk++) {
                    acc[r][0] = fmaf(av[kk], wq[kk].x, acc[r][0]);
                    acc[r][1] = fmaf(av[kk], wq[kk].y, acc[r][1]);
                    acc[r][2] = fmaf(av[kk], wq[kk].z, acc[r][2]);
                    acc[r][3] = fmaf(av[kk], wq[kk].w, acc[r][3]);
                }
            }
        }
    }
    #pragma unroll
    for (int r = 0; r < 4; r++) {
        float o[4] = {acc[r][0], acc[r][1], acc[r][2], acc[r][3]};
        if (ACT == 1) {
            #pragma unroll
            for (int q = 0; q < 4; q++) o[q] = o[q] > 0.f ? o[q] : 0.01f * o[q];
        }
        if (OUTBF) {
            ushort4 u;
            u.x = f2bf(o[0]); u.y = f2bf(o[1]); u.z = f2bf(o[2]); u.w = f2bf(o[3]);
            *(ushort4*)((unsigned short*)OutV + (size_t)(row0 + r0 + r) * 128 + c4) = u;
        } else {
            *(float4*)((float*)OutV + (size_t)(row0 + r0 + r) * 128 + c4) =
                make_float4(o[0], o[1], o[2], o[3]);
        }
    }
}

// ---------------------------------------------------------------- attention scalars (xh bf16)
__global__ __launch_bounds__(256) void att_kernel(const unsigned short* __restrict__ xh,
                                                  const float* __restrict__ asw,
                                                  const float* __restrict__ adw,
                                                  float* __restrict__ a_src,
                                                  float* __restrict__ a_dst) {
    int node = (blockIdx.x * 256 + threadIdx.x) >> 6;
    int lane = threadIdx.x & 63;
    if (node >= NN) return;
    int h = lane >> 4;
    ushort2 xv = *(const ushort2*)(xh + (size_t)node * 128 + lane * 2);
    float fx = bf2f(xv.x), fy = bf2f(xv.y);
    float2 aw = *(const float2*)(asw + lane * 2);
    float2 dw = *(const float2*)(adw + lane * 2);
    float ps = fx * aw.x + fy * aw.y;
    float pd = fx * dw.x + fy * dw.y;
    #pragma unroll
    for (int m = 1; m < 16; m <<= 1) { ps += __shfl_xor(ps, m); pd += __shfl_xor(pd, m); }
    if ((lane & 15) == 0) {
        a_src[node * 4 + h] = ps;
        a_dst[node * 4 + h] = pd;
    }
}

// ---------------------------------------------------------------- CSR build (all 3 views fused)
__global__ __launch_bounds__(256) void count3_kernel(const int* __restrict__ e0,
                                                     const int* __restrict__ e1,
                                                     const int* __restrict__ e2,
                                                     int* __restrict__ deg3) {
    int e3 = blockIdx.x * 256 + threadIdx.x;
    if (e3 >= 3 * EE) return;
    int v = e3 / EE;
    int e = e3 - v * EE;
    const int* ei = (v == 0) ? e0 : (v == 1) ? e1 : e2;
    atomicAdd(&deg3[v * NN + ei[EE + e]], 1);
}

__global__ __launch_bounds__(256) void offsets_kernel(const int* __restrict__ deg,
                                                      int* __restrict__ counter,
                                                      int* __restrict__ start) {
    int n = blockIdx.x * 256 + threadIdx.x;
    int lane = threadIdx.x & 63;
    int d = (n < NN) ? deg[n] : 0;
    int incl = d;
    #pragma unroll
    for (int m = 1; m < 64; m <<= 1) {
        int t = __shfl_up(incl, m);
        if (lane >= m) incl += t;
    }
    int total = __shfl(incl, 63);
    int base = 0;
    if (lane == 0) base = atomicAdd(counter, total);
    base = __shfl(base, 0);
    if (n < NN) start[n] = base + incl - d;
}

__global__ __launch_bounds__(256) void fill3_kernel(const int* __restrict__ e0,
                                                    const int* __restrict__ e1,
                                                    const int* __restrict__ e2,
                                                    const int* __restrict__ start3,
                                                    int* __restrict__ cursor3,
                                                    int* __restrict__ ebuf3) {
    int e3 = blockIdx.x * 256 + threadIdx.x;
    if (e3 >= 3 * EE) return;
    int v = e3 / EE;
    int e = e3 - v * EE;
    const int* ei = (v == 0) ? e0 : (v == 1) ? e1 : e2;
    int s = ei[e];
    int d = ei[EE + e];
    int pos = start3[v * NN + d] + atomicAdd(&cursor3[v * NN + d], 1);
    ebuf3[v * EE + pos] = s;
}

// ---------------------------------------------------------------- GAT aggregate (wave/dst, bf16 xh)
__device__ __forceinline__ float edge_e(float as_, float ad) {
    float t = as_ + ad;
    t = t > 0.f ? t : 0.2f * t;
    return exp2f(t * 1.442695041f);
}

__global__ __launch_bounds__(256) void aggregate_kernel(const unsigned short* __restrict__ xh,
                                                        const float* __restrict__ a_src,
                                                        const float* __restrict__ a_dst,
                                                        const int* __restrict__ start,
                                                        const int* __restrict__ deg,
                                                        const int* __restrict__ ebuf,
                                                        const float* __restrict__ bias,
                                                        const float* __restrict__ gw,
                                                        const float* __restrict__ gb,
                                                        float* __restrict__ hv,
                                                        float* __restrict__ gexpv) {
    int node = (blockIdx.x * 256 + threadIdx.x) >> 6;
    int lane = threadIdx.x & 63;
    if (node >= NN) return;
    int h = lane >> 4;
    float ad = a_dst[node * 4 + h];
    int st = start[node];
    int cnt = deg[node];

    float accx, accy, den;
    {   // self loop
        float e = edge_e(a_src[node * 4 + h], ad);
        ushort2 xv = *(const ushort2*)(xh + (size_t)node * 128 + lane * 2);
        den = e; accx = e * bf2f(xv.x); accy = e * bf2f(xv.y);
    }
    for (int j0 = 0; j0 < cnt; j0 += 64) {
        int nj = min(64, cnt - j0);
        int src_l = (lane < nj) ? ebuf[st + j0 + lane] : 0;
        int jj = 0;
        for (; jj + 4 <= nj; jj += 4) {
            int s0 = __shfl(src_l, jj),     s1 = __shfl(src_l, jj + 1);
            int s2 = __shfl(src_l, jj + 2), s3 = __shfl(src_l, jj + 3);
            float a0 = a_src[s0 * 4 + h], a1 = a_src[s1 * 4 + h];
            float a2 = a_src[s2 * 4 + h], a3 = a_src[s3 * 4 + h];
            ushort2 x0 = *(const ushort2*)(xh + (size_t)s0 * 128 + lane * 2);
            ushort2 x1 = *(const ushort2*)(xh + (size_t)s1 * 128 + lane * 2);
            ushort2 x2 = *(const ushort2*)(xh + (size_t)s2 * 128 + lane * 2);
            ushort2 x3 = *(const ushort2*)(xh + (size_t)s3 * 128 + lane * 2);
            float e0 = edge_e(a0, ad), e1 = edge_e(a1, ad);
            float e2 = edge_e(a2, ad), e3 = edge_e(a3, ad);
            den += (e0 + e1) + (e2 + e3);
            accx = fmaf(e0, bf2f(x0.x), accx); accy = fmaf(e0, bf2f(x0.y), accy);
            accx = fmaf(e1, bf2f(x1.x), accx); accy = fmaf(e1, bf2f(x1.y), accy);
            accx = fmaf(e2, bf2f(x2.x), accx); accy = fmaf(e2, bf2f(x2.y), accy);
            accx = fmaf(e3, bf2f(x3.x), accx); accy = fmaf(e3, bf2f(x3.y), accy);
        }
        for (; jj < nj; jj++) {
            int s = __shfl(src_l, jj);
            float e = edge_e(a_src[s * 4 + h], ad);
            ushort2 xv = *(const ushort2*)(xh + (size_t)s * 128 + lane * 2);
            den += e;
            accx = fmaf(e, bf2f(xv.x), accx);
            accy = fmaf(e, bf2f(xv.y), accy);
        }
    }
    float inv = 1.0f / den;
    float2 bb = *(const float2*)(bias + lane * 2);
    float o0 = accx * inv + bb.x;
    float o1 = accy * inv + bb.y;
    o0 = o0 > 0.f ? o0 : exp2f(o0 * 1.442695041f) - 1.0f;   // ELU
    o1 = o1 > 0.f ? o1 : exp2f(o1 * 1.442695041f) - 1.0f;
    *(float2*)(hv + (size_t)node * 128 + lane * 2) = make_float2(o0, o1);
    float2 g2 = *(const float2*)(gw + lane * 2);
    float gp = o0 * g2.x + o1 * g2.y;
    #pragma unroll
    for (int m = 1; m < 64; m <<= 1) gp += __shfl_xor(gp, m);
    if (lane == 0) gexpv[node] = exp2f((gp + gb[0]) * 1.442695041f);
}

// ---------------------------------------------------------------- pool: block/graph, 8 node-groups
__global__ __launch_bounds__(1024) void pool_kernel(const float* __restrict__ hv,
                                                    const float* __restrict__ gexpv,
                                                    const int* __restrict__ batch,
                                                    float* __restrict__ gout,
                                                    int voff) {
    int b = blockIdx.x;
    int g = threadIdx.x >> 7;          // 0..7
    int ch = threadIdx.x & 127;
    int l = 0, r = NN;
    while (l < r) { int m = (l + r) >> 1; if (batch[m] < b) l = m + 1; else r = m; }
    int s0 = l;
    r = NN;
    while (l < r) { int m = (l + r) >> 1; if (batch[m] < b + 1) l = m + 1; else r = m; }
    int s1 = l;
    float acc = 0.f, wsum = 0.f;
    for (int n = s0 + g; n < s1; n += 8) {
        float w = gexpv[n];
        wsum += w;
        acc = fmaf(w, hv[(size_t)n * 128 + ch], acc);
    }
    __shared__ float sacc[8][128];
    __shared__ float sws[8];
    sacc[g][ch] = acc;
    if (ch == 0) sws[g] = wsum;
    __syncthreads();
    if (g == 0) {
        float a = 0.f, w = 0.f;
        #pragma unroll
        for (int i = 0; i < 8; i++) { a += sacc[i][ch]; w += sws[i]; }
        gout[b * 384 + voff + ch] = (s1 > s0) ? a / w : 0.f;
    }
}

// ---------------------------------------------------------------- classifier
__global__ __launch_bounds__(128) void clf_kernel(const float* __restrict__ gout,
                                                  const float* __restrict__ W1,
                                                  const float* __restrict__ b1,
                                                  const float* __restrict__ W2,
                                                  const float* __restrict__ b2,
                                                  float* __restrict__ out) {
    int b = blockIdx.x;
    int j = threadIdx.x;
    float acc = b1[j];
    for (int k = 0; k < 384; k++) acc = fmaf(gout[b * 384 + k], W1[k * 128 + j], acc);
    acc = acc > 0.f ? acc : 0.01f * acc;
    float p = acc * W2[j];
    #pragma unroll
    for (int m = 1; m < 64; m <<= 1) p += __shfl_xor(p, m);
    __shared__ float sh[2];
    if ((j & 63) == 0) sh[j >> 6] = p;
    __syncthreads();
    if (j == 0) out[b] = sh[0] + sh[1] + b2[0];
}

// ---------------------------------------------------------------- launch
extern "C" void kernel_launch(void* const* d_in, const int* in_sizes, int n_in,
                              void* d_out, int out_size, void* d_ws, size_t ws_size,
                              hipStream_t stream) {
    const float* x      = (const float*)d_in[0];
    const int*   ei[3]  = {(const int*)d_in[1], (const int*)d_in[2], (const int*)d_in[3]};
    const int*   batch  = (const int*)d_in[4];
    const float* ln_g   = (const float*)d_in[5];
    const float* ln_b   = (const float*)d_in[6];
    const float* proj_W = (const float*)d_in[7];
    const float* proj_b = (const float*)d_in[8];
    const float* Wv[3]  = {(const float*)d_in[9],  (const float*)d_in[13], (const float*)d_in[17]};
    const float* asv[3] = {(const float*)d_in[10], (const float*)d_in[14], (const float*)d_in[18]};
    const float* adv[3] = {(const float*)d_in[11], (const float*)d_in[15], (const float*)d_in[19]};
    const float* bv[3]  = {(const float*)d_in[12], (const float*)d_in[16], (const float*)d_in[20]};
    const float* gate_W = (const float*)d_in[21];
    const float* gate_b = (const float*)d_in[22];
    const float* clf_W1 = (const float*)d_in[23];
    const float* clf_b1 = (const float*)d_in[24];
    const float* clf_W2 = (const float*)d_in[25];
    const float* clf_b2 = (const float*)d_in[26];
    float* out = (float*)d_out;

    // workspace layout (float offsets)
    float* f = (float*)d_ws;
    float* xn    = f;                       // N*128 fp32, aliased as hv
    float* h0    = f + 12800000;            // N*128 fp32
    unsigned short* xh = (unsigned short*)(f + 25600000);  // N*128 bf16 (6.4M floats)
    float* a_src = f + 32000000;            // N*4
    float* a_dst = f + 32400000;            // N*4
    float* gexpv = f + 32800000;            // N
    float* gout  = f + 32900000;            // B*384
    int* ip      = (int*)(f + 33000000);
    int* deg3    = ip;                      // 3N
    int* cursor3 = ip + 300000;             // 3N
    int* counter3= ip + 600000;             // 64
    int* start3  = ip + 600064;             // 3N
    int* ebuf3   = ip + 900064;             // 3E
    float* hv    = xn;

    (void)in_sizes; (void)n_in; (void)out_size; (void)ws_size;

    // 1. LayerNorm
    ln_kernel<<<25000, 256, 0, stream>>>(x, ln_g, ln_b, xn);
    // 2. h0 = leaky(xn @ proj_W + proj_b)   (fp32 out)
    gemm128<1, 0><<<3125, 256, 0, stream>>>(xn, proj_W, proj_b, h0);

    // 3. CSR for all three views
    hipMemsetAsync(ip, 0, (size_t)600064 * sizeof(int), stream);
    count3_kernel<<<18750, 256, 0, stream>>>(ei[0], ei[1], ei[2], deg3);
    for (int v = 0; v < 3; v++)
        offsets_kernel<<<391, 256, 0, stream>>>(deg3 + v * NN, &counter3[v], start3 + v * NN);
    fill3_kernel<<<18750, 256, 0, stream>>>(ei[0], ei[1], ei[2], start3, cursor3, ebuf3);

    for (int v = 0; v < 3; v++) {
        gemm128<0, 1><<<3125, 256, 0, stream>>>(h0, Wv[v], nullptr, xh);   // bf16 out
        att_kernel<<<25000, 256, 0, stream>>>(xh, asv[v], adv[v], a_src, a_dst);
        aggregate_kernel<<<25000, 256, 0, stream>>>(xh, a_src, a_dst,
                                                    start3 + v * NN, deg3 + v * NN, ebuf3 + v * EE,
                                                    bv[v], gate_W, gate_b, hv, gexpv);
        pool_kernel<<<256, 1024, 0, stream>>>(hv, gexpv, batch, gout, v * 128);
    }
    clf_kernel<<<256, 128, 0, stream>>>(gout, clf_W1, clf_b1, clf_W2, clf_b2, out);
}

// Round 3
// 800.987 us; speedup vs baseline: 2.3055x; 1.5388x over previous
//
#include <hip/hip_runtime.h>
#include <hip/hip_bf16.h>
#include <math.h>

#define NN 100000
#define EE 1600000
#define BB 256
#define DD 128
#define NBUCK 391          // ceil(NN/256) coarse buckets (dst>>8)
#define PBLK 96            // blocks per view in bucket pass
#define CH 16667           // edges per block (96*16667 >= EE)
#define ROWS_PAD 100096    // 782*128

typedef short bf16x8 __attribute__((ext_vector_type(8)));
typedef float f32x4 __attribute__((ext_vector_type(4)));

__device__ __forceinline__ float bf2f(unsigned short u) {
    return __uint_as_float(((unsigned int)u) << 16);
}
__device__ __forceinline__ unsigned short f2bf(float f) {
    __hip_bfloat16 h = __float2bfloat16(f);   // RNE
    return *(unsigned short*)&h;
}

// ---------------------------------------------------------------- LayerNorm (bf16 out)
__global__ __launch_bounds__(256) void ln_kernel(const float* __restrict__ x,
                                                 const float* __restrict__ g,
                                                 const float* __restrict__ b,
                                                 unsigned short* __restrict__ xn) {
    int node = (blockIdx.x * 256 + threadIdx.x) >> 6;
    int lane = threadIdx.x & 63;
    if (node >= NN) return;
    float2 v = *(const float2*)(x + (size_t)node * 128 + lane * 2);
    float s = v.x + v.y;
    float sq = v.x * v.x + v.y * v.y;
    #pragma unroll
    for (int m = 1; m < 64; m <<= 1) { s += __shfl_xor(s, m); sq += __shfl_xor(sq, m); }
    float mu = s * (1.0f / 128.0f);
    float var = sq * (1.0f / 128.0f) - mu * mu;
    float rs = rsqrtf(var + 1e-5f);
    float2 gg = *(const float2*)(g + lane * 2);
    float2 bb = *(const float2*)(b + lane * 2);
    ushort2 o;
    o.x = f2bf((v.x - mu) * rs * gg.x + bb.x);
    o.y = f2bf((v.y - mu) * rs * gg.y + bb.y);
    *(ushort2*)(xn + (size_t)node * 128 + lane * 2) = o;
}

// ---------------------------------------------------------------- pack W^T to bf16 [n][k]
__global__ __launch_bounds__(256) void pack_wt(const float* __restrict__ W0,
                                               const float* __restrict__ W1,
                                               const float* __restrict__ W2,
                                               const float* __restrict__ W3,
                                               unsigned short* __restrict__ WT) {
    int which = blockIdx.y;
    const float* W = which == 0 ? W0 : which == 1 ? W1 : which == 2 ? W2 : W3;
    int i = blockIdx.x * 256 + threadIdx.x;   // 0..16383
    int n = i >> 7, k = i & 127;
    WT[which * 16384 + i] = f2bf(W[k * 128 + n]);
}

// ---------------------------------------------------------------- bf16 MFMA GEMM [N,128]x[128,128]
// A row-major bf16, WT = W^T row-major bf16 ([n][k]). Out bf16.
// ACT: leaky 0.01; BIAS: add bias[col]; FUSE: fused att partial reduction.
template <int ACT, int BIAS, int FUSE>
__global__ __launch_bounds__(256) void gemm_mfma(const unsigned short* __restrict__ A,
                                                 const unsigned short* __restrict__ WT,
                                                 const float* __restrict__ bias,
                                                 unsigned short* __restrict__ Out,
                                                 const float* __restrict__ asw,
                                                 const float* __restrict__ adw,
                                                 float* __restrict__ a_src,
                                                 float* __restrict__ a_dst) {
    int w = threadIdx.x >> 6, lane = threadIdx.x & 63;
    int ln = lane & 15, oct = lane >> 4;
    int row0 = blockIdx.x * 128 + w * 32;

    f32x4 acc[2][8];
    #pragma unroll
    for (int i = 0; i < 2; i++)
        #pragma unroll
        for (int j = 0; j < 8; j++) acc[i][j] = (f32x4){0.f, 0.f, 0.f, 0.f};

    const bf16x8* Ar0 = (const bf16x8*)(A + (size_t)(row0 + ln) * 128);
    const bf16x8* Ar1 = (const bf16x8*)(A + (size_t)(row0 + 16 + ln) * 128);
    const bf16x8* Wr  = (const bf16x8*)(WT + (size_t)ln * 128);

    #pragma unroll
    for (int kq = 0; kq < 4; kq++) {
        int koff = kq * 4 + oct;              // k = kq*32 + oct*8, in 8-elem units
        bf16x8 a0 = Ar0[koff];
        bf16x8 a1 = Ar1[koff];
        #pragma unroll
        for (int ct = 0; ct < 8; ct++) {
            bf16x8 bfr = Wr[ct * 16 * 16 + koff];   // row (ct*16+ln), stride 128 shorts = 16 bf16x8
            acc[0][ct] = __builtin_amdgcn_mfma_f32_16x16x32_bf16(a0, bfr, acc[0][ct], 0, 0, 0);
            acc[1][ct] = __builtin_amdgcn_mfma_f32_16x16x32_bf16(a1, bfr, acc[1][ct], 0, 0, 0);
        }
    }

    float biasv[8], aswv[8], adwv[8];
    if (BIAS) {
        #pragma unroll
        for (int ct = 0; ct < 8; ct++) biasv[ct] = bias[ct * 16 + ln];
    }
    if (FUSE) {
        #pragma unroll
        for (int ct = 0; ct < 8; ct++) { aswv[ct] = asw[ct * 16 + ln]; adwv[ct] = adw[ct * 16 + ln]; }
    }

    #pragma unroll
    for (int rt = 0; rt < 2; rt++) {
        #pragma unroll
        for (int r = 0; r < 4; r++) {
            int row = row0 + rt * 16 + oct * 4 + r;
            float sh_[4] = {0.f, 0.f, 0.f, 0.f}, dh_[4] = {0.f, 0.f, 0.f, 0.f};
            #pragma unroll
            for (int ct = 0; ct < 8; ct++) {
                float v = acc[rt][ct][r];
                if (BIAS) v += biasv[ct];
                if (ACT) v = v > 0.f ? v : 0.01f * v;
                Out[(size_t)row * 128 + ct * 16 + ln] = f2bf(v);
                if (FUSE) {
                    sh_[ct >> 1] = fmaf(v, aswv[ct], sh_[ct >> 1]);
                    dh_[ct >> 1] = fmaf(v, adwv[ct], dh_[ct >> 1]);
                }
            }
            if (FUSE) {
                #pragma unroll
                for (int off = 1; off < 16; off <<= 1) {
                    #pragma unroll
                    for (int h = 0; h < 4; h++) {
                        sh_[h] += __shfl_xor(sh_[h], off);
                        dh_[h] += __shfl_xor(dh_[h], off);
                    }
                }
                if (ln == 0) {
                    *(float4*)(a_src + (size_t)row * 4) = make_float4(sh_[0], sh_[1], sh_[2], sh_[3]);
                    *(float4*)(a_dst + (size_t)row * 4) = make_float4(dh_[0], dh_[1], dh_[2], dh_[3]);
                }
            }
        }
    }
}

// ---------------------------------------------------------------- CSR: coarse histogram
__global__ __launch_bounds__(256) void csr_hist(const int* __restrict__ e0,
                                                const int* __restrict__ e1,
                                                const int* __restrict__ e2,
                                                int* __restrict__ blockHist) {
    int v = blockIdx.x / PBLK, p = blockIdx.x % PBLK;
    const int* ei = v == 0 ? e0 : v == 1 ? e1 : e2;
    __shared__ int h[NBUCK];
    for (int i = threadIdx.x; i < NBUCK; i += 256) h[i] = 0;
    __syncthreads();
    int ea = p * CH, eb = min(EE, ea + CH);
    for (int e = ea + threadIdx.x; e < eb; e += 256)
        atomicAdd(&h[((unsigned)ei[EE + e]) >> 8], 1);
    __syncthreads();
    for (int i = threadIdx.x; i < NBUCK; i += 256) blockHist[blockIdx.x * NBUCK + i] = h[i];
}

// ---------------------------------------------------------------- CSR: bucket totals + starts
__global__ __launch_bounds__(1024) void csr_scan(const int* __restrict__ blockHist,
                                                 int* __restrict__ btot,
                                                 int* __restrict__ bstart) {
    __shared__ int tot[3 * NBUCK];
    for (int i = threadIdx.x; i < 3 * NBUCK; i += 1024) {
        int v = i / NBUCK, b = i - v * NBUCK;
        int s = 0;
        for (int p = 0; p < PBLK; p++) s += blockHist[(v * PBLK + p) * NBUCK + b];
        tot[i] = s; btot[i] = s;
    }
    __syncthreads();
    if (threadIdx.x < 3) {
        int v = threadIdx.x, run = 0;
        for (int b = 0; b < NBUCK; b++) { bstart[v * NBUCK + b] = run; run += tot[v * NBUCK + b]; }
    }
}

// ---------------------------------------------------------------- CSR: per-block bucket offsets
__global__ __launch_bounds__(256) void csr_boff(const int* __restrict__ blockHist,
                                                const int* __restrict__ bstart,
                                                int* __restrict__ blockOff) {
    int i = blockIdx.x * 256 + threadIdx.x;
    if (i >= 3 * NBUCK) return;
    int v = i / NBUCK, b = i - v * NBUCK;
    int run = bstart[i];
    for (int p = 0; p < PBLK; p++) {
        int idx = (v * PBLK + p) * NBUCK + b;
        blockOff[idx] = run;
        run += blockHist[idx];
    }
}

// ---------------------------------------------------------------- CSR: coarse scatter (LDS cursors)
__global__ __launch_bounds__(256) void csr_scatter(const int* __restrict__ e0,
                                                   const int* __restrict__ e1,
                                                   const int* __restrict__ e2,
                                                   const int* __restrict__ blockOff,
                                                   uint2* __restrict__ pairbuf) {
    int v = blockIdx.x / PBLK, p = blockIdx.x % PBLK;
    const int* ei = v == 0 ? e0 : v == 1 ? e1 : e2;
    __shared__ int cur[NBUCK];
    for (int i = threadIdx.x; i < NBUCK; i += 256) cur[i] = blockOff[blockIdx.x * NBUCK + i];
    __syncthreads();
    int ea = p * CH, eb = min(EE, ea + CH);
    uint2* pb = pairbuf + (size_t)v * EE;
    for (int e = ea + threadIdx.x; e < eb; e += 256) {
        int s = ei[e], d = ei[EE + e];
        int pos = atomicAdd(&cur[((unsigned)d) >> 8], 1);
        pb[pos] = make_uint2((unsigned)s, (unsigned)d);
    }
}

// ---------------------------------------------------------------- CSR: fine sort within bucket
__global__ __launch_bounds__(256) void csr_fine(const uint2* __restrict__ pairbuf,
                                                const int* __restrict__ btot,
                                                const int* __restrict__ bstart,
                                                int* __restrict__ deg3,
                                                int* __restrict__ start3,
                                                int* __restrict__ ebuf3) {
    int v = blockIdx.x / NBUCK, b = blockIdx.x - v * NBUCK;
    int base = bstart[v * NBUCK + b], cnt = btot[v * NBUCK + b];
    const uint2* pb = pairbuf + (size_t)v * EE + base;
    __shared__ int hist[256], scan[256], cur[256];
    int t = threadIdx.x;
    hist[t] = 0;
    __syncthreads();
    for (int i = t; i < cnt; i += 256) atomicAdd(&hist[pb[i].y & 255], 1);
    __syncthreads();
    scan[t] = hist[t];
    __syncthreads();
    for (int s = 1; s < 256; s <<= 1) {
        int u = (t >= s) ? scan[t - s] : 0;
        __syncthreads();
        scan[t] += u;
        __syncthreads();
    }
    int excl = scan[t] - hist[t];
    cur[t] = excl;
    __syncthreads();
    int* eb = ebuf3 + (size_t)v * EE + base;
    for (int i = t; i < cnt; i += 256) {
        uint2 pr = pb[i];
        int pos = atomicAdd(&cur[pr.y & 255], 1);
        eb[pos] = (int)pr.x;
    }
    int node = b * 256 + t;
    if (node < NN) {
        deg3[v * NN + node] = hist[t];
        start3[v * NN + node] = base + excl;
    }
}

// ---------------------------------------------------------------- GAT aggregate (wave/dst, bf16 xh)
__device__ __forceinline__ float edge_e(float as_, float ad) {
    float t = as_ + ad;
    t = t > 0.f ? t : 0.2f * t;
    return exp2f(t * 1.442695041f);
}

__global__ __launch_bounds__(256) void aggregate_kernel(const unsigned short* __restrict__ xh,
                                                        const float* __restrict__ a_src,
                                                        const float* __restrict__ a_dst,
                                                        const int* __restrict__ start,
                                                        const int* __restrict__ deg,
                                                        const int* __restrict__ ebuf,
                                                        const float* __restrict__ bias,
                                                        const float* __restrict__ gw,
                                                        const float* __restrict__ gb,
                                                        float* __restrict__ hv,
                                                        float* __restrict__ gexpv) {
    int node = (blockIdx.x * 256 + threadIdx.x) >> 6;
    int lane = threadIdx.x & 63;
    if (node >= NN) return;
    int h = lane >> 4;
    float ad = a_dst[node * 4 + h];
    int st = start[node];
    int cnt = deg[node];

    float accx, accy, den;
    {   // self loop
        float e = edge_e(a_src[node * 4 + h], ad);
        ushort2 xv = *(const ushort2*)(xh + (size_t)node * 128 + lane * 2);
        den = e; accx = e * bf2f(xv.x); accy = e * bf2f(xv.y);
    }
    for (int j0 = 0; j0 < cnt; j0 += 64) {
        int nj = min(64, cnt - j0);
        int src_l = (lane < nj) ? ebuf[st + j0 + lane] : 0;
        int jj = 0;
        for (; jj + 4 <= nj; jj += 4) {
            int s0 = __shfl(src_l, jj),     s1 = __shfl(src_l, jj + 1);
            int s2 = __shfl(src_l, jj + 2), s3 = __shfl(src_l, jj + 3);
            float a0 = a_src[s0 * 4 + h], a1 = a_src[s1 * 4 + h];
            float a2 = a_src[s2 * 4 + h], a3 = a_src[s3 * 4 + h];
            ushort2 x0 = *(const ushort2*)(xh + (size_t)s0 * 128 + lane * 2);
            ushort2 x1 = *(const ushort2*)(xh + (size_t)s1 * 128 + lane * 2);
            ushort2 x2 = *(const ushort2*)(xh + (size_t)s2 * 128 + lane * 2);
            ushort2 x3 = *(const ushort2*)(xh + (size_t)s3 * 128 + lane * 2);
            float e0 = edge_e(a0, ad), e1 = edge_e(a1, ad);
            float e2 = edge_e(a2, ad), e3 = edge_e(a3, ad);
            den += (e0 + e1) + (e2 + e3);
            accx = fmaf(e0, bf2f(x0.x), accx); accy = fmaf(e0, bf2f(x0.y), accy);
            accx = fmaf(e1, bf2f(x1.x), accx); accy = fmaf(e1, bf2f(x1.y), accy);
            accx = fmaf(e2, bf2f(x2.x), accx); accy = fmaf(e2, bf2f(x2.y), accy);
            accx = fmaf(e3, bf2f(x3.x), accx); accy = fmaf(e3, bf2f(x3.y), accy);
        }
        for (; jj < nj; jj++) {
            int s = __shfl(src_l, jj);
            float e = edge_e(a_src[s * 4 + h], ad);
            ushort2 xv = *(const ushort2*)(xh + (size_t)s * 128 + lane * 2);
            den += e;
            accx = fmaf(e, bf2f(xv.x), accx);
            accy = fmaf(e, bf2f(xv.y), accy);
        }
    }
    float inv = 1.0f / den;
    float2 bb = *(const float2*)(bias + lane * 2);
    float o0 = accx * inv + bb.x;
    float o1 = accy * inv + bb.y;
    o0 = o0 > 0.f ? o0 : exp2f(o0 * 1.442695041f) - 1.0f;   // ELU
    o1 = o1 > 0.f ? o1 : exp2f(o1 * 1.442695041f) - 1.0f;
    *(float2*)(hv + (size_t)node * 128 + lane * 2) = make_float2(o0, o1);
    float2 g2 = *(const float2*)(gw + lane * 2);
    float gp = o0 * g2.x + o1 * g2.y;
    #pragma unroll
    for (int m = 1; m < 64; m <<= 1) gp += __shfl_xor(gp, m);
    if (lane == 0) gexpv[node] = exp2f((gp + gb[0]) * 1.442695041f);
}

// ---------------------------------------------------------------- pool: block/graph, 8 node-groups
__global__ __launch_bounds__(1024) void pool_kernel(const float* __restrict__ hv,
                                                    const float* __restrict__ gexpv,
                                                    const int* __restrict__ batch,
                                                    float* __restrict__ gout,
                                                    int voff) {
    int b = blockIdx.x;
    int g = threadIdx.x >> 7;
    int ch = threadIdx.x & 127;
    int l = 0, r = NN;
    while (l < r) { int m = (l + r) >> 1; if (batch[m] < b) l = m + 1; else r = m; }
    int s0 = l;
    r = NN;
    while (l < r) { int m = (l + r) >> 1; if (batch[m] < b + 1) l = m + 1; else r = m; }
    int s1 = l;
    float acc = 0.f, wsum = 0.f;
    for (int n = s0 + g; n < s1; n += 8) {
        float w = gexpv[n];
        wsum += w;
        acc = fmaf(w, hv[(size_t)n * 128 + ch], acc);
    }
    __shared__ float sacc[8][128];
    __shared__ float sws[8];
    sacc[g][ch] = acc;
    if (ch == 0) sws[g] = wsum;
    __syncthreads();
    if (g == 0) {
        float a = 0.f, w = 0.f;
        #pragma unroll
        for (int i = 0; i < 8; i++) { a += sacc[i][ch]; w += sws[i]; }
        gout[b * 384 + voff + ch] = (s1 > s0) ? a / w : 0.f;
    }
}

// ---------------------------------------------------------------- classifier
__global__ __launch_bounds__(128) void clf_kernel(const float* __restrict__ gout,
                                                  const float* __restrict__ W1,
                                                  const float* __restrict__ b1,
                                                  const float* __restrict__ W2,
                                                  const float* __restrict__ b2,
                                                  float* __restrict__ out) {
    int b = blockIdx.x;
    int j = threadIdx.x;
    float acc = b1[j];
    for (int k = 0; k < 384; k++) acc = fmaf(gout[b * 384 + k], W1[k * 128 + j], acc);
    acc = acc > 0.f ? acc : 0.01f * acc;
    float p = acc * W2[j];
    #pragma unroll
    for (int m = 1; m < 64; m <<= 1) p += __shfl_xor(p, m);
    __shared__ float sh[2];
    if ((j & 63) == 0) sh[j >> 6] = p;
    __syncthreads();
    if (j == 0) out[b] = sh[0] + sh[1] + b2[0];
}

// ---------------------------------------------------------------- launch
extern "C" void kernel_launch(void* const* d_in, const int* in_sizes, int n_in,
                              void* d_out, int out_size, void* d_ws, size_t ws_size,
                              hipStream_t stream) {
    const float* x      = (const float*)d_in[0];
    const int*   ei[3]  = {(const int*)d_in[1], (const int*)d_in[2], (const int*)d_in[3]};
    const int*   batch  = (const int*)d_in[4];
    const float* ln_g   = (const float*)d_in[5];
    const float* ln_b   = (const float*)d_in[6];
    const float* proj_W = (const float*)d_in[7];
    const float* proj_b = (const float*)d_in[8];
    const float* Wv[3]  = {(const float*)d_in[9],  (const float*)d_in[13], (const float*)d_in[17]};
    const float* asv[3] = {(const float*)d_in[10], (const float*)d_in[14], (const float*)d_in[18]};
    const float* adv[3] = {(const float*)d_in[11], (const float*)d_in[15], (const float*)d_in[19]};
    const float* bv[3]  = {(const float*)d_in[12], (const float*)d_in[16], (const float*)d_in[20]};
    const float* gate_W = (const float*)d_in[21];
    const float* gate_b = (const float*)d_in[22];
    const float* clf_W1 = (const float*)d_in[23];
    const float* clf_b1 = (const float*)d_in[24];
    const float* clf_W2 = (const float*)d_in[25];
    const float* clf_b2 = (const float*)d_in[26];
    float* out = (float*)d_out;

    (void)in_sizes; (void)n_in; (void)out_size; (void)ws_size;

    // ---- workspace layout (byte offsets, 256B aligned) ----
    char* base = (char*)d_ws;
    size_t off = 0;
    auto nxt = [&](size_t bytes) { char* r = base + off; off += (bytes + 255) & ~(size_t)255; return r; };
    unsigned short* xn   = (unsigned short*)nxt((size_t)ROWS_PAD * 128 * 2);   // 25.6 MB
    unsigned short* h0   = (unsigned short*)nxt((size_t)ROWS_PAD * 128 * 2);
    unsigned short* xh   = (unsigned short*)nxt((size_t)ROWS_PAD * 128 * 2);
    unsigned short* WT   = (unsigned short*)nxt(4 * 16384 * 2);
    float* a_src  = (float*)nxt((size_t)ROWS_PAD * 4 * 4);
    float* a_dst  = (float*)nxt((size_t)ROWS_PAD * 4 * 4);
    float* gexpv  = (float*)nxt(NN * 4);
    float* gout   = (float*)nxt(BB * 384 * 4);
    int* deg3     = (int*)nxt(3 * NN * 4);
    int* start3   = (int*)nxt(3 * NN * 4);
    int* ebuf3    = (int*)nxt((size_t)3 * EE * 4);                              // 19.2 MB
    int* btot     = (int*)nxt(3 * NBUCK * 4);
    int* bstart   = (int*)nxt(3 * NBUCK * 4);
    int* blockHist= (int*)nxt((size_t)3 * PBLK * NBUCK * 4);
    int* blockOff = (int*)nxt((size_t)3 * PBLK * NBUCK * 4);
    char* unionr  = nxt((size_t)NN * 128 * 4);                                  // 51.2 MB union
    uint2* pairbuf = (uint2*)unionr;        // 3*EE*8 = 38.4 MB, dead before aggregate
    float* hv      = (float*)unionr;        // N*128*4, alive after CSR build

    // 1. pack all four W^T (bf16)
    pack_wt<<<dim3(64, 4), 256, 0, stream>>>(proj_W, Wv[0], Wv[1], Wv[2], WT);
    // 2. LayerNorm -> bf16
    ln_kernel<<<25000, 256, 0, stream>>>(x, ln_g, ln_b, xn);
    // 3. CSR build (bucket sort, no global data atomics)
    csr_hist<<<3 * PBLK, 256, 0, stream>>>(ei[0], ei[1], ei[2], blockHist);
    csr_scan<<<1, 1024, 0, stream>>>(blockHist, btot, bstart);
    csr_boff<<<(3 * NBUCK + 255) / 256, 256, 0, stream>>>(blockHist, bstart, blockOff);
    csr_scatter<<<3 * PBLK, 256, 0, stream>>>(ei[0], ei[1], ei[2], blockOff, pairbuf);
    csr_fine<<<3 * NBUCK, 256, 0, stream>>>(pairbuf, btot, bstart, deg3, start3, ebuf3);
    // 4. h0 = leaky(xn @ proj_W + proj_b)   (bf16 MFMA)
    gemm_mfma<1, 1, 0><<<782, 256, 0, stream>>>(xn, WT, proj_b, h0,
                                                nullptr, nullptr, nullptr, nullptr);
    // 5. views
    for (int v = 0; v < 3; v++) {
        gemm_mfma<0, 0, 1><<<782, 256, 0, stream>>>(h0, WT + (1 + v) * 16384, nullptr, xh,
                                                    asv[v], adv[v], a_src, a_dst);
        aggregate_kernel<<<25000, 256, 0, stream>>>(xh, a_src, a_dst,
                                                    start3 + v * NN, deg3 + v * NN, ebuf3 + (size_t)v * EE,
                                                    bv[v], gate_W, gate_b, hv, gexpv);
        pool_kernel<<<256, 1024, 0, stream>>>(hv, gexpv, batch, gout, v * 128);
    }
    // 6. classifier
    clf_kernel<<<256, 128, 0, stream>>>(gout, clf_W1, clf_b1, clf_W2, clf_b2, out);
}

// Round 4
// 784.920 us; speedup vs baseline: 2.3527x; 1.0205x over previous
//
#include <hip/hip_runtime.h>
#include <hip/hip_bf16.h>
#include <hip/hip_fp16.h>
#include <math.h>

#define NN 100000
#define EE 1600000
#define BB 256
#define DD 128
#define NBUCK 391          // ceil(NN/256) coarse buckets (dst>>8)
#define PBLK 96            // blocks per view in bucket pass
#define CH 16667           // edges per block (96*16667 >= EE)
#define ROWS_PAD 100096    // 782*128
#define EPV (EE + NN)      // entries per view incl self-loops

typedef short bf16x8 __attribute__((ext_vector_type(8)));
typedef float f32x4 __attribute__((ext_vector_type(4)));

__device__ __forceinline__ float bf2f(unsigned short u) {
    return __uint_as_float(((unsigned int)u) << 16);
}
__device__ __forceinline__ unsigned short f2bf(float f) {
    __hip_bfloat16 h = __float2bfloat16(f);   // RNE
    return *(unsigned short*)&h;
}
__device__ __forceinline__ unsigned short f2h(float f) {
    __half h = __float2half(f);               // RNE
    return *(unsigned short*)&h;
}

// ---------------------------------------------------------------- LayerNorm (bf16 out)
__global__ __launch_bounds__(256) void ln_kernel(const float* __restrict__ x,
                                                 const float* __restrict__ g,
                                                 const float* __restrict__ b,
                                                 unsigned short* __restrict__ xn) {
    int node = (blockIdx.x * 256 + threadIdx.x) >> 6;
    int lane = threadIdx.x & 63;
    if (node >= NN) return;
    float2 v = *(const float2*)(x + (size_t)node * 128 + lane * 2);
    float s = v.x + v.y;
    float sq = v.x * v.x + v.y * v.y;
    #pragma unroll
    for (int m = 1; m < 64; m <<= 1) { s += __shfl_xor(s, m); sq += __shfl_xor(sq, m); }
    float mu = s * (1.0f / 128.0f);
    float var = sq * (1.0f / 128.0f) - mu * mu;
    float rs = rsqrtf(var + 1e-5f);
    float2 gg = *(const float2*)(g + lane * 2);
    float2 bb = *(const float2*)(b + lane * 2);
    ushort2 o;
    o.x = f2bf((v.x - mu) * rs * gg.x + bb.x);
    o.y = f2bf((v.y - mu) * rs * gg.y + bb.y);
    *(ushort2*)(xn + (size_t)node * 128 + lane * 2) = o;
}

// ---------------------------------------------------------------- pack W^T to bf16 [n][k]
__global__ __launch_bounds__(256) void pack_wt(const float* __restrict__ W0,
                                               const float* __restrict__ W1,
                                               const float* __restrict__ W2,
                                               const float* __restrict__ W3,
                                               unsigned short* __restrict__ WT) {
    int which = blockIdx.y;
    const float* W = which == 0 ? W0 : which == 1 ? W1 : which == 2 ? W2 : W3;
    int i = blockIdx.x * 256 + threadIdx.x;   // 0..16383
    int n = i >> 7, k = i & 127;
    WT[which * 16384 + i] = f2bf(W[k * 128 + n]);
}

// ---------------------------------------------------------------- bf16 MFMA GEMM [N,128]x[128,128]
template <int ACT, int BIAS, int FUSE>
__global__ __launch_bounds__(256) void gemm_mfma(const unsigned short* __restrict__ A,
                                                 const unsigned short* __restrict__ WT,
                                                 const float* __restrict__ bias,
                                                 unsigned short* __restrict__ Out,
                                                 const float* __restrict__ asw,
                                                 const float* __restrict__ adw,
                                                 float* __restrict__ a_src,
                                                 float* __restrict__ a_dst) {
    int w = threadIdx.x >> 6, lane = threadIdx.x & 63;
    int ln = lane & 15, oct = lane >> 4;
    int row0 = blockIdx.x * 128 + w * 32;

    f32x4 acc[2][8];
    #pragma unroll
    for (int i = 0; i < 2; i++)
        #pragma unroll
        for (int j = 0; j < 8; j++) acc[i][j] = (f32x4){0.f, 0.f, 0.f, 0.f};

    const bf16x8* Ar0 = (const bf16x8*)(A + (size_t)(row0 + ln) * 128);
    const bf16x8* Ar1 = (const bf16x8*)(A + (size_t)(row0 + 16 + ln) * 128);
    const bf16x8* Wr  = (const bf16x8*)(WT + (size_t)ln * 128);

    #pragma unroll
    for (int kq = 0; kq < 4; kq++) {
        int koff = kq * 4 + oct;
        bf16x8 a0 = Ar0[koff];
        bf16x8 a1 = Ar1[koff];
        #pragma unroll
        for (int ct = 0; ct < 8; ct++) {
            bf16x8 bfr = Wr[ct * 16 * 16 + koff];
            acc[0][ct] = __builtin_amdgcn_mfma_f32_16x16x32_bf16(a0, bfr, acc[0][ct], 0, 0, 0);
            acc[1][ct] = __builtin_amdgcn_mfma_f32_16x16x32_bf16(a1, bfr, acc[1][ct], 0, 0, 0);
        }
    }

    float biasv[8], aswv[8], adwv[8];
    if (BIAS) {
        #pragma unroll
        for (int ct = 0; ct < 8; ct++) biasv[ct] = bias[ct * 16 + ln];
    }
    if (FUSE) {
        #pragma unroll
        for (int ct = 0; ct < 8; ct++) { aswv[ct] = asw[ct * 16 + ln]; adwv[ct] = adw[ct * 16 + ln]; }
    }

    #pragma unroll
    for (int rt = 0; rt < 2; rt++) {
        #pragma unroll
        for (int r = 0; r < 4; r++) {
            int row = row0 + rt * 16 + oct * 4 + r;
            float sh_[4] = {0.f, 0.f, 0.f, 0.f}, dh_[4] = {0.f, 0.f, 0.f, 0.f};
            #pragma unroll
            for (int ct = 0; ct < 8; ct++) {
                float v = acc[rt][ct][r];
                if (BIAS) v += biasv[ct];
                if (ACT) v = v > 0.f ? v : 0.01f * v;
                Out[(size_t)row * 128 + ct * 16 + ln] = f2bf(v);
                if (FUSE) {
                    sh_[ct >> 1] = fmaf(v, aswv[ct], sh_[ct >> 1]);
                    dh_[ct >> 1] = fmaf(v, adwv[ct], dh_[ct >> 1]);
                }
            }
            if (FUSE) {
                #pragma unroll
                for (int off = 1; off < 16; off <<= 1) {
                    #pragma unroll
                    for (int h = 0; h < 4; h++) {
                        sh_[h] += __shfl_xor(sh_[h], off);
                        dh_[h] += __shfl_xor(dh_[h], off);
                    }
                }
                if (ln == 0) {
                    *(float4*)(a_src + (size_t)row * 4) = make_float4(sh_[0], sh_[1], sh_[2], sh_[3]);
                    *(float4*)(a_dst + (size_t)row * 4) = make_float4(dh_[0], dh_[1], dh_[2], dh_[3]);
                }
            }
        }
    }
}

// ---------------------------------------------------------------- CSR: coarse histogram
__global__ __launch_bounds__(256) void csr_hist(const int* __restrict__ e0,
                                                const int* __restrict__ e1,
                                                const int* __restrict__ e2,
                                                int* __restrict__ blockHist) {
    int v = blockIdx.x / PBLK, p = blockIdx.x % PBLK;
    const int* ei = v == 0 ? e0 : v == 1 ? e1 : e2;
    __shared__ int h[NBUCK];
    for (int i = threadIdx.x; i < NBUCK; i += 256) h[i] = 0;
    __syncthreads();
    int ea = p * CH, eb = min(EE, ea + CH);
    for (int e = ea + threadIdx.x; e < eb; e += 256)
        atomicAdd(&h[((unsigned)ei[EE + e]) >> 8], 1);
    __syncthreads();
    for (int i = threadIdx.x; i < NBUCK; i += 256) blockHist[blockIdx.x * NBUCK + i] = h[i];
}

// ---------------------------------------------------------------- CSR: totals + starts (per view)
// btot: edge-only count per bucket; ebstart: excl-prefix of edges (pairbuf coords);
// bstart: excl-prefix of edges+selfloops (ebuf coords), with sentinel at [NBUCK].
__global__ __launch_bounds__(512) void csr_scan(const int* __restrict__ blockHist,
                                                int* __restrict__ btot,
                                                int* __restrict__ ebstart,
                                                int* __restrict__ bstart) {
    int v = blockIdx.x, t = threadIdx.x;
    __shared__ int se[512], ss[512];
    int tot_e = 0;
    if (t < NBUCK)
        for (int p = 0; p < PBLK; p++) tot_e += blockHist[(v * PBLK + p) * NBUCK + t];
    int nval = (t < NBUCK) ? min(256, NN - t * 256) : 0;
    int tot_s = tot_e + nval;
    se[t] = tot_e; ss[t] = tot_s;
    __syncthreads();
    for (int s = 1; s < 512; s <<= 1) {
        int ae = (t >= s) ? se[t - s] : 0;
        int as_ = (t >= s) ? ss[t - s] : 0;
        __syncthreads();
        se[t] += ae; ss[t] += as_;
        __syncthreads();
    }
    if (t < NBUCK) {
        btot[v * NBUCK + t] = tot_e;
        ebstart[v * (NBUCK + 1) + t] = se[t] - tot_e;
        bstart[v * (NBUCK + 1) + t] = ss[t] - tot_s;
    }
    if (t == NBUCK - 1) {
        ebstart[v * (NBUCK + 1) + NBUCK] = se[t];
        bstart[v * (NBUCK + 1) + NBUCK] = ss[t];
    }
}

// ---------------------------------------------------------------- CSR: per-block bucket offsets
__global__ __launch_bounds__(256) void csr_boff(const int* __restrict__ blockHist,
                                                const int* __restrict__ ebstart,
                                                int* __restrict__ blockOff) {
    int i = blockIdx.x * 256 + threadIdx.x;
    if (i >= 3 * NBUCK) return;
    int v = i / NBUCK, b = i - v * NBUCK;
    int run = ebstart[v * (NBUCK + 1) + b];
    for (int p = 0; p < PBLK; p++) {
        int idx = (v * PBLK + p) * NBUCK + b;
        blockOff[idx] = run;
        run += blockHist[idx];
    }
}

// ---------------------------------------------------------------- CSR: coarse scatter (packed)
__global__ __launch_bounds__(256) void csr_scatter(const int* __restrict__ e0,
                                                   const int* __restrict__ e1,
                                                   const int* __restrict__ e2,
                                                   const int* __restrict__ blockOff,
                                                   unsigned int* __restrict__ pairbuf) {
    int v = blockIdx.x / PBLK, p = blockIdx.x % PBLK;
    const int* ei = v == 0 ? e0 : v == 1 ? e1 : e2;
    __shared__ int cur[NBUCK];
    for (int i = threadIdx.x; i < NBUCK; i += 256) cur[i] = blockOff[blockIdx.x * NBUCK + i];
    __syncthreads();
    int ea = p * CH, eb = min(EE, ea + CH);
    unsigned int* pb = pairbuf + (size_t)v * EE;
    for (int e = ea + threadIdx.x; e < eb; e += 256) {
        unsigned s = (unsigned)ei[e], d = (unsigned)ei[EE + e];
        int pos = atomicAdd(&cur[d >> 8], 1);
        pb[pos] = (s << 8) | (d & 255u);
    }
}

// ---------------------------------------------------------------- CSR: fine sort + self-loops
__global__ __launch_bounds__(256) void csr_fine(const unsigned int* __restrict__ pairbuf,
                                                const int* __restrict__ btot,
                                                const int* __restrict__ ebstart,
                                                const int* __restrict__ bstart,
                                                int* __restrict__ deg3,
                                                int* __restrict__ start3,
                                                unsigned int* __restrict__ ebuf3) {
    int v = blockIdx.x / NBUCK, b = blockIdx.x - v * NBUCK;
    int cnt   = btot[v * NBUCK + b];
    int pbase = ebstart[v * (NBUCK + 1) + b];
    int obase = bstart[v * (NBUCK + 1) + b];
    const unsigned int* pb = pairbuf + (size_t)v * EE + pbase;
    unsigned int* eb = ebuf3 + (size_t)v * EPV + obase;
    __shared__ int hist[256], scan[256], cur[256];
    int t = threadIdx.x;
    int node = b * 256 + t;
    int valid = (node < NN) ? 1 : 0;
    hist[t] = valid;
    __syncthreads();
    for (int i = t; i < cnt; i += 256) atomicAdd(&hist[pb[i] & 255u], 1);
    __syncthreads();
    scan[t] = hist[t];
    __syncthreads();
    for (int s = 1; s < 256; s <<= 1) {
        int u = (t >= s) ? scan[t - s] : 0;
        __syncthreads();
        scan[t] += u;
        __syncthreads();
    }
    int excl = scan[t] - hist[t];
    cur[t] = excl + valid;
    if (valid) eb[excl] = (((unsigned)node) << 8) | ((unsigned)node & 255u);   // self-loop first
    __syncthreads();
    for (int i = t; i < cnt; i += 256) {
        unsigned int val = pb[i];
        int pos = atomicAdd(&cur[val & 255u], 1);
        eb[pos] = val;
    }
    if (valid) {
        deg3[v * NN + node] = hist[t];
        start3[v * NN + node] = obase + excl;
    }
}

// ---------------------------------------------------------------- per-edge softmax weights (fp16)
__global__ __launch_bounds__(256) void wcalc_kernel(const unsigned int* __restrict__ ebuf,
                                                    const int* __restrict__ bstart,
                                                    const float* __restrict__ a_src,
                                                    const float* __restrict__ a_dst,
                                                    uint2* __restrict__ wbuf) {
    __shared__ int sb[NBUCK + 1];
    for (int i = threadIdx.x; i < NBUCK + 1; i += 256) sb[i] = bstart[i];
    __syncthreads();
    int e = blockIdx.x * 256 + threadIdx.x;
    if (e >= EPV) return;
    unsigned int val = ebuf[e];
    int lo = 0, hi = NBUCK;                 // find bucket: sb[lo] <= e < sb[lo+1]
    while (hi - lo > 1) { int m = (lo + hi) >> 1; if (sb[m] <= e) lo = m; else hi = m; }
    int dst = lo * 256 + (int)(val & 255u);
    int src = (int)(val >> 8);
    float4 as4 = *(const float4*)(a_src + (size_t)src * 4);
    float4 ad4 = *(const float4*)(a_dst + (size_t)dst * 4);
    float tv[4] = {as4.x + ad4.x, as4.y + ad4.y, as4.z + ad4.z, as4.w + ad4.w};
    unsigned short hw[4];
    #pragma unroll
    for (int h = 0; h < 4; h++) {
        float tt = tv[h];
        tt = fmaxf(tt, 0.f) + 0.2f * fminf(tt, 0.f);          // leaky 0.2
        hw[h] = f2h(exp2f(tt * 1.442695041f));
    }
    wbuf[e] = make_uint2((unsigned)hw[0] | ((unsigned)hw[1] << 16),
                         (unsigned)hw[2] | ((unsigned)hw[3] << 16));
}

// ---------------------------------------------------------------- GAT aggregate (wave/dst)
__global__ __launch_bounds__(256) void aggregate_kernel(const unsigned short* __restrict__ xh,
                                                        const int* __restrict__ start,
                                                        const int* __restrict__ deg,
                                                        const unsigned int* __restrict__ ebuf,
                                                        const unsigned short* __restrict__ wbuf,
                                                        const float* __restrict__ bias,
                                                        const float* __restrict__ gw,
                                                        const float* __restrict__ gb,
                                                        unsigned short* __restrict__ hvb,
                                                        float* __restrict__ gexpv) {
    int node = (blockIdx.x * 256 + threadIdx.x) >> 6;
    int lane = threadIdx.x & 63;
    if (node >= NN) return;
    int h = lane >> 4;
    int st = start[node];
    int cnt = deg[node];
    const char* xb = (const char*)xh;
    int laneoff = lane * 4;                 // byte offset within 256B row

    float accx = 0.f, accy = 0.f, den = 0.f;
    for (int j0 = 0; j0 < cnt; j0 += 64) {
        int nj = min(64, cnt - j0);
        int src_l = (lane < nj) ? (int)(ebuf[st + j0 + lane] >> 8) : 0;
        const unsigned short* wp = wbuf + (size_t)(st + j0) * 4 + h;
        int jj = 0;
        for (; jj + 4 <= nj; jj += 4) {
            int s0 = __builtin_amdgcn_readlane(src_l, jj);
            int s1 = __builtin_amdgcn_readlane(src_l, jj + 1);
            int s2 = __builtin_amdgcn_readlane(src_l, jj + 2);
            int s3 = __builtin_amdgcn_readlane(src_l, jj + 3);
            float w0 = __half2float(*(const __half*)(wp + (size_t)(jj + 0) * 4));
            float w1 = __half2float(*(const __half*)(wp + (size_t)(jj + 1) * 4));
            float w2 = __half2float(*(const __half*)(wp + (size_t)(jj + 2) * 4));
            float w3 = __half2float(*(const __half*)(wp + (size_t)(jj + 3) * 4));
            unsigned int x0 = *(const unsigned int*)(xb + (((size_t)(unsigned)s0) << 8) + laneoff);
            unsigned int x1 = *(const unsigned int*)(xb + (((size_t)(unsigned)s1) << 8) + laneoff);
            unsigned int x2 = *(const unsigned int*)(xb + (((size_t)(unsigned)s2) << 8) + laneoff);
            unsigned int x3 = *(const unsigned int*)(xb + (((size_t)(unsigned)s3) << 8) + laneoff);
            den += (w0 + w1) + (w2 + w3);
            accx = fmaf(w0, __uint_as_float(x0 << 16), accx);
            accy = fmaf(w0, __uint_as_float(x0 & 0xffff0000u), accy);
            accx = fmaf(w1, __uint_as_float(x1 << 16), accx);
            accy = fmaf(w1, __uint_as_float(x1 & 0xffff0000u), accy);
            accx = fmaf(w2, __uint_as_float(x2 << 16), accx);
            accy = fmaf(w2, __uint_as_float(x2 & 0xffff0000u), accy);
            accx = fmaf(w3, __uint_as_float(x3 << 16), accx);
            accy = fmaf(w3, __uint_as_float(x3 & 0xffff0000u), accy);
        }
        for (; jj < nj; jj++) {
            int s = __builtin_amdgcn_readlane(src_l, jj);
            float w = __half2float(*(const __half*)(wp + (size_t)jj * 4));
            unsigned int xv = *(const unsigned int*)(xb + (((size_t)(unsigned)s) << 8) + laneoff);
            den += w;
            accx = fmaf(w, __uint_as_float(xv << 16), accx);
            accy = fmaf(w, __uint_as_float(xv & 0xffff0000u), accy);
        }
    }
    float inv = 1.0f / den;
    float2 bb = *(const float2*)(bias + lane * 2);
    float o0 = accx * inv + bb.x;
    float o1 = accy * inv + bb.y;
    o0 = o0 > 0.f ? o0 : exp2f(o0 * 1.442695041f) - 1.0f;   // ELU
    o1 = o1 > 0.f ? o1 : exp2f(o1 * 1.442695041f) - 1.0f;
    unsigned int packed = (unsigned)f2bf(o0) | ((unsigned)f2bf(o1) << 16);
    *(unsigned int*)(hvb + (size_t)node * 128 + lane * 2) = packed;
    float2 g2 = *(const float2*)(gw + lane * 2);
    float gp = o0 * g2.x + o1 * g2.y;
    #pragma unroll
    for (int m = 1; m < 64; m <<= 1) gp += __shfl_xor(gp, m);
    if (lane == 0) gexpv[node] = exp2f((gp + gb[0]) * 1.442695041f);
}

// ---------------------------------------------------------------- pool: block/graph (bf16 hv)
__global__ __launch_bounds__(1024) void pool_kernel(const unsigned short* __restrict__ hvb,
                                                    const float* __restrict__ gexpv,
                                                    const int* __restrict__ batch,
                                                    float* __restrict__ gout,
                                                    int voff) {
    int b = blockIdx.x;
    int g = threadIdx.x >> 7;
    int ch = threadIdx.x & 127;
    int l = 0, r = NN;
    while (l < r) { int m = (l + r) >> 1; if (batch[m] < b) l = m + 1; else r = m; }
    int s0 = l;
    r = NN;
    while (l < r) { int m = (l + r) >> 1; if (batch[m] < b + 1) l = m + 1; else r = m; }
    int s1 = l;
    float acc = 0.f, wsum = 0.f;
    for (int n = s0 + g; n < s1; n += 8) {
        float w = gexpv[n];
        wsum += w;
        acc = fmaf(w, bf2f(hvb[(size_t)n * 128 + ch]), acc);
    }
    __shared__ float sacc[8][128];
    __shared__ float sws[8];
    sacc[g][ch] = acc;
    if (ch == 0) sws[g] = wsum;
    __syncthreads();
    if (g == 0) {
        float a = 0.f, w = 0.f;
        #pragma unroll
        for (int i = 0; i < 8; i++) { a += sacc[i][ch]; w += sws[i]; }
        gout[b * 384 + voff + ch] = (s1 > s0) ? a / w : 0.f;
    }
}

// ---------------------------------------------------------------- classifier
__global__ __launch_bounds__(128) void clf_kernel(const float* __restrict__ gout,
                                                  const float* __restrict__ W1,
                                                  const float* __restrict__ b1,
                                                  const float* __restrict__ W2,
                                                  const float* __restrict__ b2,
                                                  float* __restrict__ out) {
    int b = blockIdx.x;
    int j = threadIdx.x;
    float acc = b1[j];
    for (int k = 0; k < 384; k++) acc = fmaf(gout[b * 384 + k], W1[k * 128 + j], acc);
    acc = acc > 0.f ? acc : 0.01f * acc;
    float p = acc * W2[j];
    #pragma unroll
    for (int m = 1; m < 64; m <<= 1) p += __shfl_xor(p, m);
    __shared__ float sh[2];
    if ((j & 63) == 0) sh[j >> 6] = p;
    __syncthreads();
    if (j == 0) out[b] = sh[0] + sh[1] + b2[0];
}

// ---------------------------------------------------------------- launch
extern "C" void kernel_launch(void* const* d_in, const int* in_sizes, int n_in,
                              void* d_out, int out_size, void* d_ws, size_t ws_size,
                              hipStream_t stream) {
    const float* x      = (const float*)d_in[0];
    const int*   ei[3]  = {(const int*)d_in[1], (const int*)d_in[2], (const int*)d_in[3]};
    const int*   batch  = (const int*)d_in[4];
    const float* ln_g   = (const float*)d_in[5];
    const float* ln_b   = (const float*)d_in[6];
    const float* proj_W = (const float*)d_in[7];
    const float* proj_b = (const float*)d_in[8];
    const float* Wv[3]  = {(const float*)d_in[9],  (const float*)d_in[13], (const float*)d_in[17]};
    const float* asv[3] = {(const float*)d_in[10], (const float*)d_in[14], (const float*)d_in[18]};
    const float* adv[3] = {(const float*)d_in[11], (const float*)d_in[15], (const float*)d_in[19]};
    const float* bv[3]  = {(const float*)d_in[12], (const float*)d_in[16], (const float*)d_in[20]};
    const float* gate_W = (const float*)d_in[21];
    const float* gate_b = (const float*)d_in[22];
    const float* clf_W1 = (const float*)d_in[23];
    const float* clf_b1 = (const float*)d_in[24];
    const float* clf_W2 = (const float*)d_in[25];
    const float* clf_b2 = (const float*)d_in[26];
    float* out = (float*)d_out;

    (void)in_sizes; (void)n_in; (void)out_size; (void)ws_size;

    // ---- workspace layout ----
    char* base = (char*)d_ws;
    size_t off = 0;
    auto nxt = [&](size_t bytes) { char* r = base + off; off += (bytes + 255) & ~(size_t)255; return r; };
    unsigned short* xn   = (unsigned short*)nxt((size_t)ROWS_PAD * 128 * 2);
    unsigned short* h0   = (unsigned short*)nxt((size_t)ROWS_PAD * 128 * 2);
    unsigned short* xh   = (unsigned short*)nxt((size_t)ROWS_PAD * 128 * 2);
    unsigned short* hvb  = (unsigned short*)nxt((size_t)NN * 128 * 2);
    unsigned short* WT   = (unsigned short*)nxt(4 * 16384 * 2);
    float* a_src  = (float*)nxt((size_t)ROWS_PAD * 4 * 4);
    float* a_dst  = (float*)nxt((size_t)ROWS_PAD * 4 * 4);
    float* gexpv  = (float*)nxt(NN * 4);
    float* gout   = (float*)nxt(BB * 384 * 4);
    int* deg3     = (int*)nxt(3 * NN * 4);
    int* start3   = (int*)nxt(3 * NN * 4);
    unsigned int* ebuf3 = (unsigned int*)nxt(((size_t)3 * EPV + 64) * 4);
    uint2* wbuf   = (uint2*)nxt(((size_t)EPV + 64) * 8);
    int* btot     = (int*)nxt(3 * NBUCK * 4);
    int* ebstart  = (int*)nxt(3 * (NBUCK + 1) * 4);
    int* bstart   = (int*)nxt(3 * (NBUCK + 1) * 4);
    int* blockHist= (int*)nxt((size_t)3 * PBLK * NBUCK * 4);
    int* blockOff = (int*)nxt((size_t)3 * PBLK * NBUCK * 4);
    unsigned int* pairbuf = (unsigned int*)nxt((size_t)3 * EE * 4);

    // 1. weight packs + layernorm
    pack_wt<<<dim3(64, 4), 256, 0, stream>>>(proj_W, Wv[0], Wv[1], Wv[2], WT);
    ln_kernel<<<25000, 256, 0, stream>>>(x, ln_g, ln_b, xn);
    // 2. CSR build (with self-loops folded in)
    csr_hist<<<3 * PBLK, 256, 0, stream>>>(ei[0], ei[1], ei[2], blockHist);
    csr_scan<<<3, 512, 0, stream>>>(blockHist, btot, ebstart, bstart);
    csr_boff<<<(3 * NBUCK + 255) / 256, 256, 0, stream>>>(blockHist, ebstart, blockOff);
    csr_scatter<<<3 * PBLK, 256, 0, stream>>>(ei[0], ei[1], ei[2], blockOff, pairbuf);
    csr_fine<<<3 * NBUCK, 256, 0, stream>>>(pairbuf, btot, ebstart, bstart, deg3, start3, ebuf3);
    // 3. h0 = leaky(xn @ proj_W + proj_b)
    gemm_mfma<1, 1, 0><<<782, 256, 0, stream>>>(xn, WT, proj_b, h0,
                                                nullptr, nullptr, nullptr, nullptr);
    // 4. views
    for (int v = 0; v < 3; v++) {
        gemm_mfma<0, 0, 1><<<782, 256, 0, stream>>>(h0, WT + (1 + v) * 16384, nullptr, xh,
                                                    asv[v], adv[v], a_src, a_dst);
        wcalc_kernel<<<(EPV + 255) / 256, 256, 0, stream>>>(ebuf3 + (size_t)v * EPV,
                                                            bstart + v * (NBUCK + 1),
                                                            a_src, a_dst, wbuf);
        aggregate_kernel<<<25000, 256, 0, stream>>>(xh, start3 + v * NN, deg3 + v * NN,
                                                    ebuf3 + (size_t)v * EPV,
                                                    (const unsigned short*)wbuf,
                                                    bv[v], gate_W, gate_b, hvb, gexpv);
        pool_kernel<<<256, 1024, 0, stream>>>(hvb, gexpv, batch, gout, v * 128);
    }
    // 5. classifier
    clf_kernel<<<256, 128, 0, stream>>>(gout, clf_W1, clf_b1, clf_W2, clf_b2, out);
}

// Round 5
// 776.336 us; speedup vs baseline: 2.3787x; 1.0111x over previous
//
#include <hip/hip_runtime.h>
#include <hip/hip_bf16.h>
#include <hip/hip_fp16.h>
#include <math.h>

#define NN 100000
#define EE 1600000
#define BB 256
#define DD 128
#define NBUCK 391          // ceil(NN/256) coarse buckets (dst>>8)
#define PBLK 384           // blocks per view in bucket pass
#define CH 4167            // edges per block (384*4167 >= EE)
#define TOTB (3 * PBLK)    // total bucket-pass blocks
#define ROWS_PAD 100096    // 782*128
#define EPV (EE + NN)      // entries per view incl self-loops

typedef short bf16x8 __attribute__((ext_vector_type(8)));
typedef float f32x4 __attribute__((ext_vector_type(4)));

__device__ __forceinline__ float bf2f(unsigned short u) {
    return __uint_as_float(((unsigned int)u) << 16);
}
__device__ __forceinline__ unsigned short f2bf(float f) {
    __hip_bfloat16 h = __float2bfloat16(f);   // RNE
    return *(unsigned short*)&h;
}
__device__ __forceinline__ unsigned short f2h(float f) {
    __half h = __float2half(f);               // RNE
    return *(unsigned short*)&h;
}

// ---------------------------------------------------------------- LayerNorm (bf16 out)
__global__ __launch_bounds__(256) void ln_kernel(const float* __restrict__ x,
                                                 const float* __restrict__ g,
                                                 const float* __restrict__ b,
                                                 unsigned short* __restrict__ xn) {
    int node = (blockIdx.x * 256 + threadIdx.x) >> 6;
    int lane = threadIdx.x & 63;
    if (node >= NN) return;
    float2 v = *(const float2*)(x + (size_t)node * 128 + lane * 2);
    float s = v.x + v.y;
    float sq = v.x * v.x + v.y * v.y;
    #pragma unroll
    for (int m = 1; m < 64; m <<= 1) { s += __shfl_xor(s, m); sq += __shfl_xor(sq, m); }
    float mu = s * (1.0f / 128.0f);
    float var = sq * (1.0f / 128.0f) - mu * mu;
    float rs = rsqrtf(var + 1e-5f);
    float2 gg = *(const float2*)(g + lane * 2);
    float2 bb = *(const float2*)(b + lane * 2);
    ushort2 o;
    o.x = f2bf((v.x - mu) * rs * gg.x + bb.x);
    o.y = f2bf((v.y - mu) * rs * gg.y + bb.y);
    *(ushort2*)(xn + (size_t)node * 128 + lane * 2) = o;
}

// ---------------------------------------------------------------- pack W^T to bf16 [n][k]
__global__ __launch_bounds__(256) void pack_wt(const float* __restrict__ W0,
                                               const float* __restrict__ W1,
                                               const float* __restrict__ W2,
                                               const float* __restrict__ W3,
                                               unsigned short* __restrict__ WT) {
    int which = blockIdx.y;
    const float* W = which == 0 ? W0 : which == 1 ? W1 : which == 2 ? W2 : W3;
    int i = blockIdx.x * 256 + threadIdx.x;   // 0..16383
    int n = i >> 7, k = i & 127;
    WT[which * 16384 + i] = f2bf(W[k * 128 + n]);
}

// ---------------------------------------------------------------- bf16 MFMA GEMM [N,128]x[128,128]
template <int ACT, int BIAS, int FUSE>
__global__ __launch_bounds__(256) void gemm_mfma(const unsigned short* __restrict__ A,
                                                 const unsigned short* __restrict__ WT,
                                                 const float* __restrict__ bias,
                                                 unsigned short* __restrict__ Out,
                                                 const float* __restrict__ asw,
                                                 const float* __restrict__ adw,
                                                 float* __restrict__ a_src,
                                                 float* __restrict__ a_dst) {
    int w = threadIdx.x >> 6, lane = threadIdx.x & 63;
    int ln = lane & 15, oct = lane >> 4;
    int row0 = blockIdx.x * 128 + w * 32;

    f32x4 acc[2][8];
    #pragma unroll
    for (int i = 0; i < 2; i++)
        #pragma unroll
        for (int j = 0; j < 8; j++) acc[i][j] = (f32x4){0.f, 0.f, 0.f, 0.f};

    const bf16x8* Ar0 = (const bf16x8*)(A + (size_t)(row0 + ln) * 128);
    const bf16x8* Ar1 = (const bf16x8*)(A + (size_t)(row0 + 16 + ln) * 128);
    const bf16x8* Wr  = (const bf16x8*)(WT + (size_t)ln * 128);

    #pragma unroll
    for (int kq = 0; kq < 4; kq++) {
        int koff = kq * 4 + oct;
        bf16x8 a0 = Ar0[koff];
        bf16x8 a1 = Ar1[koff];
        #pragma unroll
        for (int ct = 0; ct < 8; ct++) {
            bf16x8 bfr = Wr[ct * 16 * 16 + koff];
            acc[0][ct] = __builtin_amdgcn_mfma_f32_16x16x32_bf16(a0, bfr, acc[0][ct], 0, 0, 0);
            acc[1][ct] = __builtin_amdgcn_mfma_f32_16x16x32_bf16(a1, bfr, acc[1][ct], 0, 0, 0);
        }
    }

    float biasv[8], aswv[8], adwv[8];
    if (BIAS) {
        #pragma unroll
        for (int ct = 0; ct < 8; ct++) biasv[ct] = bias[ct * 16 + ln];
    }
    if (FUSE) {
        #pragma unroll
        for (int ct = 0; ct < 8; ct++) { aswv[ct] = asw[ct * 16 + ln]; adwv[ct] = adw[ct * 16 + ln]; }
    }

    #pragma unroll
    for (int rt = 0; rt < 2; rt++) {
        #pragma unroll
        for (int r = 0; r < 4; r++) {
            int row = row0 + rt * 16 + oct * 4 + r;
            float sh_[4] = {0.f, 0.f, 0.f, 0.f}, dh_[4] = {0.f, 0.f, 0.f, 0.f};
            #pragma unroll
            for (int ct = 0; ct < 8; ct++) {
                float v = acc[rt][ct][r];
                if (BIAS) v += biasv[ct];
                if (ACT) v = v > 0.f ? v : 0.01f * v;
                Out[(size_t)row * 128 + ct * 16 + ln] = f2bf(v);
                if (FUSE) {
                    sh_[ct >> 1] = fmaf(v, aswv[ct], sh_[ct >> 1]);
                    dh_[ct >> 1] = fmaf(v, adwv[ct], dh_[ct >> 1]);
                }
            }
            if (FUSE) {
                #pragma unroll
                for (int off = 1; off < 16; off <<= 1) {
                    #pragma unroll
                    for (int h = 0; h < 4; h++) {
                        sh_[h] += __shfl_xor(sh_[h], off);
                        dh_[h] += __shfl_xor(dh_[h], off);
                    }
                }
                if (ln == 0) {
                    *(float4*)(a_src + (size_t)row * 4) = make_float4(sh_[0], sh_[1], sh_[2], sh_[3]);
                    *(float4*)(a_dst + (size_t)row * 4) = make_float4(dh_[0], dh_[1], dh_[2], dh_[3]);
                }
            }
        }
    }
}

// ---------------------------------------------------------------- CSR: coarse histogram
// blockHistT layout: [bucket][TOTB]
__global__ __launch_bounds__(256) void csr_hist(const int* __restrict__ e0,
                                                const int* __restrict__ e1,
                                                const int* __restrict__ e2,
                                                int* __restrict__ blockHistT) {
    int v = blockIdx.x / PBLK, p = blockIdx.x % PBLK;
    const int* ei = v == 0 ? e0 : v == 1 ? e1 : e2;
    __shared__ int h[NBUCK];
    for (int i = threadIdx.x; i < NBUCK; i += 256) h[i] = 0;
    __syncthreads();
    int ea = p * CH, ebnd = min(EE, ea + CH);
    int e = ea + threadIdx.x;
    for (; e + 768 < ebnd; e += 1024) {
        int d0 = ei[EE + e], d1 = ei[EE + e + 256];
        int d2 = ei[EE + e + 512], d3 = ei[EE + e + 768];
        atomicAdd(&h[((unsigned)d0) >> 8], 1);
        atomicAdd(&h[((unsigned)d1) >> 8], 1);
        atomicAdd(&h[((unsigned)d2) >> 8], 1);
        atomicAdd(&h[((unsigned)d3) >> 8], 1);
    }
    for (; e < ebnd; e += 256) atomicAdd(&h[((unsigned)ei[EE + e]) >> 8], 1);
    __syncthreads();
    for (int i = threadIdx.x; i < NBUCK; i += 256) blockHistT[i * TOTB + blockIdx.x] = h[i];
}

// ---------------------------------------------------------------- CSR: totals + starts (per view)
__global__ __launch_bounds__(512) void csr_scan(const int* __restrict__ blockHistT,
                                                int* __restrict__ btot,
                                                int* __restrict__ ebstart,
                                                int* __restrict__ bstart) {
    int v = blockIdx.x, t = threadIdx.x;
    __shared__ int se[512], ss[512];
    int tot_e = 0;
    if (t < NBUCK) {
        const int* row = blockHistT + (size_t)t * TOTB + v * PBLK;
        for (int p = 0; p < PBLK; p++) tot_e += row[p];
    }
    int nval = (t < NBUCK) ? min(256, NN - t * 256) : 0;
    int tot_s = tot_e + nval;
    se[t] = tot_e; ss[t] = tot_s;
    __syncthreads();
    for (int s = 1; s < 512; s <<= 1) {
        int ae = (t >= s) ? se[t - s] : 0;
        int as_ = (t >= s) ? ss[t - s] : 0;
        __syncthreads();
        se[t] += ae; ss[t] += as_;
        __syncthreads();
    }
    if (t < NBUCK) {
        btot[v * NBUCK + t] = tot_e;
        ebstart[v * (NBUCK + 1) + t] = se[t] - tot_e;
        bstart[v * (NBUCK + 1) + t] = ss[t] - tot_s;
    }
    if (t == NBUCK - 1) {
        ebstart[v * (NBUCK + 1) + NBUCK] = se[t];
        bstart[v * (NBUCK + 1) + NBUCK] = ss[t];
    }
}

// ---------------------------------------------------------------- CSR: per-block bucket offsets
__global__ __launch_bounds__(256) void csr_boff(const int* __restrict__ blockHistT,
                                                const int* __restrict__ ebstart,
                                                int* __restrict__ blockOffT) {
    int i = blockIdx.x * 256 + threadIdx.x;
    if (i >= 3 * NBUCK) return;
    int v = i / NBUCK, b = i - v * NBUCK;
    int run = ebstart[v * (NBUCK + 1) + b];
    const int* hrow = blockHistT + (size_t)b * TOTB + v * PBLK;
    int* orow = blockOffT + (size_t)b * TOTB + v * PBLK;
    for (int p = 0; p < PBLK; p++) {
        orow[p] = run;
        run += hrow[p];
    }
}

// ---------------------------------------------------------------- CSR: coarse scatter (packed)
__global__ __launch_bounds__(256) void csr_scatter(const int* __restrict__ e0,
                                                   const int* __restrict__ e1,
                                                   const int* __restrict__ e2,
                                                   const int* __restrict__ blockOffT,
                                                   unsigned int* __restrict__ pairbuf) {
    int v = blockIdx.x / PBLK, p = blockIdx.x % PBLK;
    const int* ei = v == 0 ? e0 : v == 1 ? e1 : e2;
    __shared__ int cur[NBUCK];
    for (int i = threadIdx.x; i < NBUCK; i += 256) cur[i] = blockOffT[(size_t)i * TOTB + blockIdx.x];
    __syncthreads();
    int ea = p * CH, ebnd = min(EE, ea + CH);
    unsigned int* pb = pairbuf + (size_t)v * EE;
    int e = ea + threadIdx.x;
    for (; e + 768 < ebnd; e += 1024) {
        unsigned s0 = (unsigned)ei[e],       d0 = (unsigned)ei[EE + e];
        unsigned s1 = (unsigned)ei[e + 256], d1 = (unsigned)ei[EE + e + 256];
        unsigned s2 = (unsigned)ei[e + 512], d2 = (unsigned)ei[EE + e + 512];
        unsigned s3 = (unsigned)ei[e + 768], d3 = (unsigned)ei[EE + e + 768];
        int p0 = atomicAdd(&cur[d0 >> 8], 1);
        int p1 = atomicAdd(&cur[d1 >> 8], 1);
        int p2 = atomicAdd(&cur[d2 >> 8], 1);
        int p3 = atomicAdd(&cur[d3 >> 8], 1);
        pb[p0] = (s0 << 8) | (d0 & 255u);
        pb[p1] = (s1 << 8) | (d1 & 255u);
        pb[p2] = (s2 << 8) | (d2 & 255u);
        pb[p3] = (s3 << 8) | (d3 & 255u);
    }
    for (; e < ebnd; e += 256) {
        unsigned s = (unsigned)ei[e], d = (unsigned)ei[EE + e];
        int pos = atomicAdd(&cur[d >> 8], 1);
        pb[pos] = (s << 8) | (d & 255u);
    }
}

// ---------------------------------------------------------------- CSR: fine sort + self-loops
__global__ __launch_bounds__(256) void csr_fine(const unsigned int* __restrict__ pairbuf,
                                                const int* __restrict__ btot,
                                                const int* __restrict__ ebstart,
                                                const int* __restrict__ bstart,
                                                int* __restrict__ deg3,
                                                int* __restrict__ start3,
                                                unsigned int* __restrict__ ebuf3) {
    int v = blockIdx.x / NBUCK, b = blockIdx.x - v * NBUCK;
    int cnt   = btot[v * NBUCK + b];
    int pbase = ebstart[v * (NBUCK + 1) + b];
    int obase = bstart[v * (NBUCK + 1) + b];
    const unsigned int* pb = pairbuf + (size_t)v * EE + pbase;
    unsigned int* eb = ebuf3 + (size_t)v * EPV + obase;
    __shared__ int hist[256], scan[256], cur[256];
    int t = threadIdx.x;
    int node = b * 256 + t;
    int valid = (node < NN) ? 1 : 0;
    hist[t] = valid;
    __syncthreads();
    {
        int i = t;
        for (; i + 768 < cnt; i += 1024) {
            unsigned v0 = pb[i], v1 = pb[i + 256], v2 = pb[i + 512], v3 = pb[i + 768];
            atomicAdd(&hist[v0 & 255u], 1);
            atomicAdd(&hist[v1 & 255u], 1);
            atomicAdd(&hist[v2 & 255u], 1);
            atomicAdd(&hist[v3 & 255u], 1);
        }
        for (; i < cnt; i += 256) atomicAdd(&hist[pb[i] & 255u], 1);
    }
    __syncthreads();
    scan[t] = hist[t];
    __syncthreads();
    for (int s = 1; s < 256; s <<= 1) {
        int u = (t >= s) ? scan[t - s] : 0;
        __syncthreads();
        scan[t] += u;
        __syncthreads();
    }
    int excl = scan[t] - hist[t];
    cur[t] = excl + valid;
    if (valid) eb[excl] = (((unsigned)node) << 8) | ((unsigned)node & 255u);   // self-loop first
    __syncthreads();
    {
        int i = t;
        for (; i + 768 < cnt; i += 1024) {
            unsigned v0 = pb[i], v1 = pb[i + 256], v2 = pb[i + 512], v3 = pb[i + 768];
            int p0 = atomicAdd(&cur[v0 & 255u], 1);
            int p1 = atomicAdd(&cur[v1 & 255u], 1);
            int p2 = atomicAdd(&cur[v2 & 255u], 1);
            int p3 = atomicAdd(&cur[v3 & 255u], 1);
            eb[p0] = v0; eb[p1] = v1; eb[p2] = v2; eb[p3] = v3;
        }
        for (; i < cnt; i += 256) {
            unsigned int val = pb[i];
            int pos = atomicAdd(&cur[val & 255u], 1);
            eb[pos] = val;
        }
    }
    if (valid) {
        deg3[v * NN + node] = hist[t];
        start3[v * NN + node] = obase + excl;
    }
}

// ---------------------------------------------------------------- per-edge softmax weights (fp16)
// one bucket per blockIdx.x; blockIdx.y strides within bucket — no binary search
__global__ __launch_bounds__(256) void wcalc_kernel(const unsigned int* __restrict__ ebuf,
                                                    const int* __restrict__ bstart,
                                                    const float* __restrict__ a_src,
                                                    const float* __restrict__ a_dst,
                                                    uint2* __restrict__ wbuf) {
    int b = blockIdx.x;
    int lo = bstart[b], hi = bstart[b + 1];
    int dbase = b * 256;
    for (int e = lo + blockIdx.y * 256 + threadIdx.x; e < hi; e += 1024) {
        unsigned int val = ebuf[e];
        int dst = dbase + (int)(val & 255u);
        int src = (int)(val >> 8);
        float4 as4 = *(const float4*)(a_src + (size_t)src * 4);
        float4 ad4 = *(const float4*)(a_dst + (size_t)dst * 4);
        float tv[4] = {as4.x + ad4.x, as4.y + ad4.y, as4.z + ad4.z, as4.w + ad4.w};
        unsigned short hw[4];
        #pragma unroll
        for (int h = 0; h < 4; h++) {
            float tt = tv[h];
            tt = fmaxf(tt, 0.f) + 0.2f * fminf(tt, 0.f);          // leaky 0.2
            hw[h] = f2h(exp2f(tt * 1.442695041f));
        }
        wbuf[e] = make_uint2((unsigned)hw[0] | ((unsigned)hw[1] << 16),
                             (unsigned)hw[2] | ((unsigned)hw[3] << 16));
    }
}

// ---------------------------------------------------------------- GAT aggregate (wave/dst)
__global__ __launch_bounds__(256) void aggregate_kernel(const unsigned short* __restrict__ xh,
                                                        const int* __restrict__ start,
                                                        const int* __restrict__ deg,
                                                        const unsigned int* __restrict__ ebuf,
                                                        const unsigned short* __restrict__ wbuf,
                                                        const float* __restrict__ bias,
                                                        const float* __restrict__ gw,
                                                        const float* __restrict__ gb,
                                                        unsigned short* __restrict__ hvb,
                                                        float* __restrict__ gexpv) {
    int node = (blockIdx.x * 256 + threadIdx.x) >> 6;
    int lane = threadIdx.x & 63;
    if (node >= NN) return;
    int h = lane >> 4;
    int st = start[node];
    int cnt = deg[node];
    const char* xb = (const char*)xh;
    int laneoff = lane * 4;                 // byte offset within 256B row

    float accx = 0.f, accy = 0.f, den = 0.f;
    for (int j0 = 0; j0 < cnt; j0 += 64) {
        int nj = min(64, cnt - j0);
        int src_l = (lane < nj) ? (int)(ebuf[st + j0 + lane] >> 8) : 0;
        const unsigned short* wp = wbuf + (size_t)(st + j0) * 4 + h;
        int jj = 0;
        for (; jj + 4 <= nj; jj += 4) {
            int s0 = __builtin_amdgcn_readlane(src_l, jj);
            int s1 = __builtin_amdgcn_readlane(src_l, jj + 1);
            int s2 = __builtin_amdgcn_readlane(src_l, jj + 2);
            int s3 = __builtin_amdgcn_readlane(src_l, jj + 3);
            float w0 = __half2float(*(const __half*)(wp + (size_t)(jj + 0) * 4));
            float w1 = __half2float(*(const __half*)(wp + (size_t)(jj + 1) * 4));
            float w2 = __half2float(*(const __half*)(wp + (size_t)(jj + 2) * 4));
            float w3 = __half2float(*(const __half*)(wp + (size_t)(jj + 3) * 4));
            unsigned int x0 = *(const unsigned int*)(xb + (((size_t)(unsigned)s0) << 8) + laneoff);
            unsigned int x1 = *(const unsigned int*)(xb + (((size_t)(unsigned)s1) << 8) + laneoff);
            unsigned int x2 = *(const unsigned int*)(xb + (((size_t)(unsigned)s2) << 8) + laneoff);
            unsigned int x3 = *(const unsigned int*)(xb + (((size_t)(unsigned)s3) << 8) + laneoff);
            den += (w0 + w1) + (w2 + w3);
            accx = fmaf(w0, __uint_as_float(x0 << 16), accx);
            accy = fmaf(w0, __uint_as_float(x0 & 0xffff0000u), accy);
            accx = fmaf(w1, __uint_as_float(x1 << 16), accx);
            accy = fmaf(w1, __uint_as_float(x1 & 0xffff0000u), accy);
            accx = fmaf(w2, __uint_as_float(x2 << 16), accx);
            accy = fmaf(w2, __uint_as_float(x2 & 0xffff0000u), accy);
            accx = fmaf(w3, __uint_as_float(x3 << 16), accx);
            accy = fmaf(w3, __uint_as_float(x3 & 0xffff0000u), accy);
        }
        for (; jj < nj; jj++) {
            int s = __builtin_amdgcn_readlane(src_l, jj);
            float w = __half2float(*(const __half*)(wp + (size_t)jj * 4));
            unsigned int xv = *(const unsigned int*)(xb + (((size_t)(unsigned)s) << 8) + laneoff);
            den += w;
            accx = fmaf(w, __uint_as_float(xv << 16), accx);
            accy = fmaf(w, __uint_as_float(xv & 0xffff0000u), accy);
        }
    }
    float inv = 1.0f / den;
    float2 bb = *(const float2*)(bias + lane * 2);
    float o0 = accx * inv + bb.x;
    float o1 = accy * inv + bb.y;
    o0 = o0 > 0.f ? o0 : exp2f(o0 * 1.442695041f) - 1.0f;   // ELU
    o1 = o1 > 0.f ? o1 : exp2f(o1 * 1.442695041f) - 1.0f;
    unsigned int packed = (unsigned)f2bf(o0) | ((unsigned)f2bf(o1) << 16);
    *(unsigned int*)(hvb + (size_t)node * 128 + lane * 2) = packed;
    float2 g2 = *(const float2*)(gw + lane * 2);
    float gp = o0 * g2.x + o1 * g2.y;
    #pragma unroll
    for (int m = 1; m < 64; m <<= 1) gp += __shfl_xor(gp, m);
    if (lane == 0) gexpv[node] = exp2f((gp + gb[0]) * 1.442695041f);
}

// ---------------------------------------------------------------- pool: block/graph (bf16 hv)
__global__ __launch_bounds__(1024) void pool_kernel(const unsigned short* __restrict__ hvb,
                                                    const float* __restrict__ gexpv,
                                                    const int* __restrict__ batch,
                                                    float* __restrict__ gout,
                                                    int voff) {
    int b = blockIdx.x;
    int g = threadIdx.x >> 7;
    int ch = threadIdx.x & 127;
    int l = 0, r = NN;
    while (l < r) { int m = (l + r) >> 1; if (batch[m] < b) l = m + 1; else r = m; }
    int s0 = l;
    r = NN;
    while (l < r) { int m = (l + r) >> 1; if (batch[m] < b + 1) l = m + 1; else r = m; }
    int s1 = l;
    float acc = 0.f, wsum = 0.f;
    for (int n = s0 + g; n < s1; n += 8) {
        float w = gexpv[n];
        wsum += w;
        acc = fmaf(w, bf2f(hvb[(size_t)n * 128 + ch]), acc);
    }
    __shared__ float sacc[8][128];
    __shared__ float sws[8];
    sacc[g][ch] = acc;
    if (ch == 0) sws[g] = wsum;
    __syncthreads();
    if (g == 0) {
        float a = 0.f, w = 0.f;
        #pragma unroll
        for (int i = 0; i < 8; i++) { a += sacc[i][ch]; w += sws[i]; }
        gout[b * 384 + voff + ch] = (s1 > s0) ? a / w : 0.f;
    }
}

// ---------------------------------------------------------------- classifier
__global__ __launch_bounds__(128) void clf_kernel(const float* __restrict__ gout,
                                                  const float* __restrict__ W1,
                                                  const float* __restrict__ b1,
                                                  const float* __restrict__ W2,
                                                  const float* __restrict__ b2,
                                                  float* __restrict__ out) {
    int b = blockIdx.x;
    int j = threadIdx.x;
    float acc = b1[j];
    for (int k = 0; k < 384; k++) acc = fmaf(gout[b * 384 + k], W1[k * 128 + j], acc);
    acc = acc > 0.f ? acc : 0.01f * acc;
    float p = acc * W2[j];
    #pragma unroll
    for (int m = 1; m < 64; m <<= 1) p += __shfl_xor(p, m);
    __shared__ float sh[2];
    if ((j & 63) == 0) sh[j >> 6] = p;
    __syncthreads();
    if (j == 0) out[b] = sh[0] + sh[1] + b2[0];
}

// ---------------------------------------------------------------- launch
extern "C" void kernel_launch(void* const* d_in, const int* in_sizes, int n_in,
                              void* d_out, int out_size, void* d_ws, size_t ws_size,
                              hipStream_t stream) {
    const float* x      = (const float*)d_in[0];
    const int*   ei[3]  = {(const int*)d_in[1], (const int*)d_in[2], (const int*)d_in[3]};
    const int*   batch  = (const int*)d_in[4];
    const float* ln_g   = (const float*)d_in[5];
    const float* ln_b   = (const float*)d_in[6];
    const float* proj_W = (const float*)d_in[7];
    const float* proj_b = (const float*)d_in[8];
    const float* Wv[3]  = {(const float*)d_in[9],  (const float*)d_in[13], (const float*)d_in[17]};
    const float* asv[3] = {(const float*)d_in[10], (const float*)d_in[14], (const float*)d_in[18]};
    const float* adv[3] = {(const float*)d_in[11], (const float*)d_in[15], (const float*)d_in[19]};
    const float* bv[3]  = {(const float*)d_in[12], (const float*)d_in[16], (const float*)d_in[20]};
    const float* gate_W = (const float*)d_in[21];
    const float* gate_b = (const float*)d_in[22];
    const float* clf_W1 = (const float*)d_in[23];
    const float* clf_b1 = (const float*)d_in[24];
    const float* clf_W2 = (const float*)d_in[25];
    const float* clf_b2 = (const float*)d_in[26];
    float* out = (float*)d_out;

    (void)in_sizes; (void)n_in; (void)out_size; (void)ws_size;

    // ---- workspace layout ----
    char* base = (char*)d_ws;
    size_t off = 0;
    auto nxt = [&](size_t bytes) { char* r = base + off; off += (bytes + 255) & ~(size_t)255; return r; };
    unsigned short* xn   = (unsigned short*)nxt((size_t)ROWS_PAD * 128 * 2);
    unsigned short* h0   = (unsigned short*)nxt((size_t)ROWS_PAD * 128 * 2);
    unsigned short* xh   = (unsigned short*)nxt((size_t)ROWS_PAD * 128 * 2);
    unsigned short* hvb  = (unsigned short*)nxt((size_t)NN * 128 * 2);
    unsigned short* WT   = (unsigned short*)nxt(4 * 16384 * 2);
    float* a_src  = (float*)nxt((size_t)ROWS_PAD * 4 * 4);
    float* a_dst  = (float*)nxt((size_t)ROWS_PAD * 4 * 4);
    float* gexpv  = (float*)nxt(NN * 4);
    float* gout   = (float*)nxt(BB * 384 * 4);
    int* deg3     = (int*)nxt(3 * NN * 4);
    int* start3   = (int*)nxt(3 * NN * 4);
    unsigned int* ebuf3 = (unsigned int*)nxt(((size_t)3 * EPV + 64) * 4);
    uint2* wbuf   = (uint2*)nxt(((size_t)EPV + 64) * 8);
    int* btot     = (int*)nxt(3 * NBUCK * 4);
    int* ebstart  = (int*)nxt(3 * (NBUCK + 1) * 4);
    int* bstart   = (int*)nxt(3 * (NBUCK + 1) * 4);
    int* blockHistT = (int*)nxt((size_t)NBUCK * TOTB * 4);
    int* blockOffT  = (int*)nxt((size_t)NBUCK * TOTB * 4);
    unsigned int* pairbuf = (unsigned int*)nxt((size_t)3 * EE * 4);

    // 1. weight packs + layernorm
    pack_wt<<<dim3(64, 4), 256, 0, stream>>>(proj_W, Wv[0], Wv[1], Wv[2], WT);
    ln_kernel<<<25000, 256, 0, stream>>>(x, ln_g, ln_b, xn);
    // 2. CSR build (with self-loops folded in)
    csr_hist<<<TOTB, 256, 0, stream>>>(ei[0], ei[1], ei[2], blockHistT);
    csr_scan<<<3, 512, 0, stream>>>(blockHistT, btot, ebstart, bstart);
    csr_boff<<<(3 * NBUCK + 255) / 256, 256, 0, stream>>>(blockHistT, ebstart, blockOffT);
    csr_scatter<<<TOTB, 256, 0, stream>>>(ei[0], ei[1], ei[2], blockOffT, pairbuf);
    csr_fine<<<3 * NBUCK, 256, 0, stream>>>(pairbuf, btot, ebstart, bstart, deg3, start3, ebuf3);
    // 3. h0 = leaky(xn @ proj_W + proj_b)
    gemm_mfma<1, 1, 0><<<782, 256, 0, stream>>>(xn, WT, proj_b, h0,
                                                nullptr, nullptr, nullptr, nullptr);
    // 4. views
    for (int v = 0; v < 3; v++) {
        gemm_mfma<0, 0, 1><<<782, 256, 0, stream>>>(h0, WT + (1 + v) * 16384, nullptr, xh,
                                                    asv[v], adv[v], a_src, a_dst);
        wcalc_kernel<<<dim3(NBUCK, 4), 256, 0, stream>>>(ebuf3 + (size_t)v * EPV,
                                                         bstart + v * (NBUCK + 1),
                                                         a_src, a_dst, wbuf);
        aggregate_kernel<<<25000, 256, 0, stream>>>(xh, start3 + v * NN, deg3 + v * NN,
                                                    ebuf3 + (size_t)v * EPV,
                                                    (const unsigned short*)wbuf,
                                                    bv[v], gate_W, gate_b, hvb, gexpv);
        pool_kernel<<<256, 1024, 0, stream>>>(hvb, gexpv, batch, gout, v * 128);
    }
    // 5. classifier
    clf_kernel<<<256, 128, 0, stream>>>(gout, clf_W1, clf_b1, clf_W2, clf_b2, out);
}

// Round 6
// 710.194 us; speedup vs baseline: 2.6002x; 1.0931x over previous
//
#include <hip/hip_runtime.h>
#include <hip/hip_bf16.h>
#include <hip/hip_fp16.h>
#include <math.h>

#define NN 100000
#define EE 1600000
#define BB 256
#define DD 128
#define NBUCK 391          // ceil(NN/256) coarse buckets (dst>>8)
#define PBLK 384           // blocks per view in bucket pass
#define CH 4167            // edges per block (384*4167 >= EE)
#define TOTB (3 * PBLK)    // total bucket-pass blocks
#define ROWS_PAD 100096    // 782*128
#define EPV (EE + NN)      // entries per view incl self-loops

typedef short bf16x8 __attribute__((ext_vector_type(8)));
typedef float f32x4 __attribute__((ext_vector_type(4)));

__device__ __forceinline__ float bf2f(unsigned short u) {
    return __uint_as_float(((unsigned int)u) << 16);
}
__device__ __forceinline__ unsigned short f2bf(float f) {
    __hip_bfloat16 h = __float2bfloat16(f);   // RNE
    return *(unsigned short*)&h;
}
__device__ __forceinline__ unsigned short f2h(float f) {
    __half h = __float2half(f);               // RNE
    return *(unsigned short*)&h;
}
__device__ __forceinline__ float h2f(unsigned short u) {
    __half h = *(__half*)&u;
    return __half2float(h);
}

// ---------------------------------------------------------------- pack W^T to bf16 [n][k]
// which==0 (proj): fold ln_g -> bf16(g[k]*W[k,n])
__global__ __launch_bounds__(256) void pack_wt(const float* __restrict__ W0,
                                               const float* __restrict__ W1,
                                               const float* __restrict__ W2,
                                               const float* __restrict__ W3,
                                               const float* __restrict__ ln_g,
                                               unsigned short* __restrict__ WT) {
    int which = blockIdx.y;
    const float* W = which == 0 ? W0 : which == 1 ? W1 : which == 2 ? W2 : W3;
    int i = blockIdx.x * 256 + threadIdx.x;   // 0..16383
    int n = i >> 7, k = i & 127;
    float v = W[k * 128 + n];
    if (which == 0) v *= ln_g[k];
    WT[which * 16384 + i] = f2bf(v);
}

// ---------------------------------------------------------------- LN affine constants
// c12[n] = sum_k g[k]*W[k,n];  c12[128+n] = sum_k b[k]*W[k,n]
__global__ __launch_bounds__(128) void ln_consts(const float* __restrict__ W,
                                                 const float* __restrict__ g,
                                                 const float* __restrict__ b,
                                                 float* __restrict__ c12) {
    int n = threadIdx.x;
    float c1 = 0.f, c2 = 0.f;
    for (int k = 0; k < 128; k++) {
        float w = W[k * 128 + n];
        c1 = fmaf(g[k], w, c1);
        c2 = fmaf(b[k], w, c2);
    }
    c12[n] = c1;
    c12[128 + n] = c2;
}

// ---------------------------------------------------------------- proj GEMM with fused LayerNorm
// h0 = leaky( rs*(bf16(x) @ bf16(g*W)) - rs*mu*c1[n] + c2[n] + pb[n] )
__global__ __launch_bounds__(256) void gemm_proj(const float* __restrict__ X,
                                                 const unsigned short* __restrict__ WT,
                                                 const float* __restrict__ c12,
                                                 const float* __restrict__ pb,
                                                 unsigned short* __restrict__ Out) {
    int w = threadIdx.x >> 6, lane = threadIdx.x & 63;
    int ln = lane & 15, oct = lane >> 4;
    int row0 = blockIdx.x * 128 + w * 32;

    f32x4 acc[2][8];
    #pragma unroll
    for (int i = 0; i < 2; i++)
        #pragma unroll
        for (int j = 0; j < 8; j++) acc[i][j] = (f32x4){0.f, 0.f, 0.f, 0.f};

    const float* X0 = X + (size_t)(row0 + ln) * 128;
    const float* X1 = X + (size_t)(row0 + 16 + ln) * 128;
    const bf16x8* Wr = (const bf16x8*)(WT + (size_t)ln * 128);

    float s0 = 0.f, q0 = 0.f, s1 = 0.f, q1 = 0.f;
    #pragma unroll
    for (int kq = 0; kq < 4; kq++) {
        int koff = kq * 4 + oct;              // 8-float chunk index
        float4 xa = *(const float4*)(X0 + koff * 8);
        float4 xb = *(const float4*)(X0 + koff * 8 + 4);
        float4 ya = *(const float4*)(X1 + koff * 8);
        float4 yb = *(const float4*)(X1 + koff * 8 + 4);
        s0 += (xa.x + xa.y) + (xa.z + xa.w) + (xb.x + xb.y) + (xb.z + xb.w);
        q0 += xa.x * xa.x + xa.y * xa.y + xa.z * xa.z + xa.w * xa.w
            + xb.x * xb.x + xb.y * xb.y + xb.z * xb.z + xb.w * xb.w;
        s1 += (ya.x + ya.y) + (ya.z + ya.w) + (yb.x + yb.y) + (yb.z + yb.w);
        q1 += ya.x * ya.x + ya.y * ya.y + ya.z * ya.z + ya.w * ya.w
            + yb.x * yb.x + yb.y * yb.y + yb.z * yb.z + yb.w * yb.w;
        bf16x8 a0, a1;
        a0[0] = (short)f2bf(xa.x); a0[1] = (short)f2bf(xa.y); a0[2] = (short)f2bf(xa.z); a0[3] = (short)f2bf(xa.w);
        a0[4] = (short)f2bf(xb.x); a0[5] = (short)f2bf(xb.y); a0[6] = (short)f2bf(xb.z); a0[7] = (short)f2bf(xb.w);
        a1[0] = (short)f2bf(ya.x); a1[1] = (short)f2bf(ya.y); a1[2] = (short)f2bf(ya.z); a1[3] = (short)f2bf(ya.w);
        a1[4] = (short)f2bf(yb.x); a1[5] = (short)f2bf(yb.y); a1[6] = (short)f2bf(yb.z); a1[7] = (short)f2bf(yb.w);
        #pragma unroll
        for (int ct = 0; ct < 8; ct++) {
            bf16x8 bfr = Wr[ct * 16 * 16 + koff];
            acc[0][ct] = __builtin_amdgcn_mfma_f32_16x16x32_bf16(a0, bfr, acc[0][ct], 0, 0, 0);
            acc[1][ct] = __builtin_amdgcn_mfma_f32_16x16x32_bf16(a1, bfr, acc[1][ct], 0, 0, 0);
        }
    }
    // per-row LN stats: reduce across the 4 oct-lanes holding the same row
    #pragma unroll
    for (int m = 16; m < 64; m <<= 1) {
        s0 += __shfl_xor(s0, m); q0 += __shfl_xor(q0, m);
        s1 += __shfl_xor(s1, m); q1 += __shfl_xor(q1, m);
    }
    float mu0 = s0 * (1.0f / 128.0f);
    float rs0 = rsqrtf(q0 * (1.0f / 128.0f) - mu0 * mu0 + 1e-5f);
    float mu1 = s1 * (1.0f / 128.0f);
    float rs1 = rsqrtf(q1 * (1.0f / 128.0f) - mu1 * mu1 + 1e-5f);

    float c1v[8], c2v[8], pbv[8];
    #pragma unroll
    for (int ct = 0; ct < 8; ct++) {
        c1v[ct] = c12[ct * 16 + ln];
        c2v[ct] = c12[128 + ct * 16 + ln];
        pbv[ct] = pb[ct * 16 + ln];
    }

    #pragma unroll
    for (int rt = 0; rt < 2; rt++) {
        #pragma unroll
        for (int r = 0; r < 4; r++) {
            int src = oct * 4 + r;            // lane (oct=0, ln=src) holds this row's stats
            float rs_r = __shfl(rt ? rs1 : rs0, src);
            float mu_r = __shfl(rt ? mu1 : mu0, src);
            int row = row0 + rt * 16 + oct * 4 + r;
            #pragma unroll
            for (int ct = 0; ct < 8; ct++) {
                float v = rs_r * acc[rt][ct][r] - rs_r * mu_r * c1v[ct] + c2v[ct] + pbv[ct];
                v = v > 0.f ? v : 0.01f * v;
                Out[(size_t)row * 128 + ct * 16 + ln] = f2bf(v);
            }
        }
    }
}

// ---------------------------------------------------------------- view GEMM (bf16 in/out, fused att)
__global__ __launch_bounds__(256) void gemm_view(const unsigned short* __restrict__ A,
                                                 const unsigned short* __restrict__ WT,
                                                 unsigned short* __restrict__ Out,
                                                 const float* __restrict__ asw,
                                                 const float* __restrict__ adw,
                                                 float* __restrict__ a_src,
                                                 float* __restrict__ a_dst) {
    int w = threadIdx.x >> 6, lane = threadIdx.x & 63;
    int ln = lane & 15, oct = lane >> 4;
    int row0 = blockIdx.x * 128 + w * 32;

    f32x4 acc[2][8];
    #pragma unroll
    for (int i = 0; i < 2; i++)
        #pragma unroll
        for (int j = 0; j < 8; j++) acc[i][j] = (f32x4){0.f, 0.f, 0.f, 0.f};

    const bf16x8* Ar0 = (const bf16x8*)(A + (size_t)(row0 + ln) * 128);
    const bf16x8* Ar1 = (const bf16x8*)(A + (size_t)(row0 + 16 + ln) * 128);
    const bf16x8* Wr  = (const bf16x8*)(WT + (size_t)ln * 128);

    #pragma unroll
    for (int kq = 0; kq < 4; kq++) {
        int koff = kq * 4 + oct;
        bf16x8 a0 = Ar0[koff];
        bf16x8 a1 = Ar1[koff];
        #pragma unroll
        for (int ct = 0; ct < 8; ct++) {
            bf16x8 bfr = Wr[ct * 16 * 16 + koff];
            acc[0][ct] = __builtin_amdgcn_mfma_f32_16x16x32_bf16(a0, bfr, acc[0][ct], 0, 0, 0);
            acc[1][ct] = __builtin_amdgcn_mfma_f32_16x16x32_bf16(a1, bfr, acc[1][ct], 0, 0, 0);
        }
    }

    float aswv[8], adwv[8];
    #pragma unroll
    for (int ct = 0; ct < 8; ct++) { aswv[ct] = asw[ct * 16 + ln]; adwv[ct] = adw[ct * 16 + ln]; }

    #pragma unroll
    for (int rt = 0; rt < 2; rt++) {
        #pragma unroll
        for (int r = 0; r < 4; r++) {
            int row = row0 + rt * 16 + oct * 4 + r;
            float sh_[4] = {0.f, 0.f, 0.f, 0.f}, dh_[4] = {0.f, 0.f, 0.f, 0.f};
            #pragma unroll
            for (int ct = 0; ct < 8; ct++) {
                float v = acc[rt][ct][r];
                Out[(size_t)row * 128 + ct * 16 + ln] = f2bf(v);
                sh_[ct >> 1] = fmaf(v, aswv[ct], sh_[ct >> 1]);
                dh_[ct >> 1] = fmaf(v, adwv[ct], dh_[ct >> 1]);
            }
            #pragma unroll
            for (int off = 1; off < 16; off <<= 1) {
                #pragma unroll
                for (int h = 0; h < 4; h++) {
                    sh_[h] += __shfl_xor(sh_[h], off);
                    dh_[h] += __shfl_xor(dh_[h], off);
                }
            }
            if (ln == 0) {
                *(float4*)(a_src + (size_t)row * 4) = make_float4(sh_[0], sh_[1], sh_[2], sh_[3]);
                *(float4*)(a_dst + (size_t)row * 4) = make_float4(dh_[0], dh_[1], dh_[2], dh_[3]);
            }
        }
    }
}

// ---------------------------------------------------------------- CSR: coarse histogram ([bucket][TOTB])
__global__ __launch_bounds__(256) void csr_hist(const int* __restrict__ e0,
                                                const int* __restrict__ e1,
                                                const int* __restrict__ e2,
                                                int* __restrict__ blockHistT) {
    int v = blockIdx.x / PBLK, p = blockIdx.x % PBLK;
    const int* ei = v == 0 ? e0 : v == 1 ? e1 : e2;
    __shared__ int h[NBUCK];
    for (int i = threadIdx.x; i < NBUCK; i += 256) h[i] = 0;
    __syncthreads();
    int ea = p * CH, ebnd = min(EE, ea + CH);
    int e = ea + threadIdx.x;
    for (; e + 768 < ebnd; e += 1024) {
        int d0 = ei[EE + e], d1 = ei[EE + e + 256];
        int d2 = ei[EE + e + 512], d3 = ei[EE + e + 768];
        atomicAdd(&h[((unsigned)d0) >> 8], 1);
        atomicAdd(&h[((unsigned)d1) >> 8], 1);
        atomicAdd(&h[((unsigned)d2) >> 8], 1);
        atomicAdd(&h[((unsigned)d3) >> 8], 1);
    }
    for (; e < ebnd; e += 256) atomicAdd(&h[((unsigned)ei[EE + e]) >> 8], 1);
    __syncthreads();
    for (int i = threadIdx.x; i < NBUCK; i += 256) blockHistT[i * TOTB + blockIdx.x] = h[i];
}

// ---------------------------------------------------------------- CSR: per-bucket totals (wave/bucket)
__global__ __launch_bounds__(256) void csr_bsum(const int* __restrict__ blockHistT,
                                                int* __restrict__ btot) {
    int wid = (blockIdx.x * 256 + threadIdx.x) >> 6;
    int lane = threadIdx.x & 63;
    if (wid >= 3 * NBUCK) return;
    int v = wid / NBUCK, b = wid - v * NBUCK;
    const int* row = blockHistT + (size_t)b * TOTB + v * PBLK;
    int s = 0;
    #pragma unroll
    for (int j = 0; j < 6; j++) s += row[lane * 6 + j];
    #pragma unroll
    for (int m = 1; m < 64; m <<= 1) s += __shfl_xor(s, m);
    if (lane == 0) btot[wid] = s;
}

// ---------------------------------------------------------------- CSR: bucket starts (scan over btot)
__global__ __launch_bounds__(512) void csr_scan(const int* __restrict__ btot,
                                                int* __restrict__ ebstart,
                                                int* __restrict__ bstart) {
    int v = blockIdx.x, t = threadIdx.x;
    __shared__ int se[512], ss[512];
    int tot_e = (t < NBUCK) ? btot[v * NBUCK + t] : 0;
    int nval = (t < NBUCK) ? min(256, NN - t * 256) : 0;
    int tot_s = tot_e + nval;
    se[t] = tot_e; ss[t] = tot_s;
    __syncthreads();
    for (int s = 1; s < 512; s <<= 1) {
        int ae = (t >= s) ? se[t - s] : 0;
        int as_ = (t >= s) ? ss[t - s] : 0;
        __syncthreads();
        se[t] += ae; ss[t] += as_;
        __syncthreads();
    }
    if (t < NBUCK) {
        ebstart[v * (NBUCK + 1) + t] = se[t] - tot_e;
        bstart[v * (NBUCK + 1) + t] = ss[t] - tot_s;
    }
    if (t == NBUCK - 1) {
        ebstart[v * (NBUCK + 1) + NBUCK] = se[t];
        bstart[v * (NBUCK + 1) + NBUCK] = ss[t];
    }
}

// ---------------------------------------------------------------- CSR: per-block offsets (wave-scan/bucket)
__global__ __launch_bounds__(256) void csr_boff(const int* __restrict__ blockHistT,
                                                const int* __restrict__ ebstart,
                                                int* __restrict__ blockOffT) {
    int wid = (blockIdx.x * 256 + threadIdx.x) >> 6;
    int lane = threadIdx.x & 63;
    if (wid >= 3 * NBUCK) return;
    int v = wid / NBUCK, b = wid - v * NBUCK;
    const int* row = blockHistT + (size_t)b * TOTB + v * PBLK;
    int* orow = blockOffT + (size_t)b * TOTB + v * PBLK;
    int vals[6], lexcl[6];
    int ls = 0;
    #pragma unroll
    for (int j = 0; j < 6; j++) vals[j] = row[lane * 6 + j];
    #pragma unroll
    for (int j = 0; j < 6; j++) { lexcl[j] = ls; ls += vals[j]; }
    int incl = ls;
    #pragma unroll
    for (int m = 1; m < 64; m <<= 1) {
        int t = __shfl_up(incl, m);
        if (lane >= m) incl += t;
    }
    int wexcl = incl - ls;
    int base = ebstart[v * (NBUCK + 1) + b];
    #pragma unroll
    for (int j = 0; j < 6; j++) orow[lane * 6 + j] = base + wexcl + lexcl[j];
}

// ---------------------------------------------------------------- CSR: coarse scatter (packed)
__global__ __launch_bounds__(256) void csr_scatter(const int* __restrict__ e0,
                                                   const int* __restrict__ e1,
                                                   const int* __restrict__ e2,
                                                   const int* __restrict__ blockOffT,
                                                   unsigned int* __restrict__ pairbuf) {
    int v = blockIdx.x / PBLK, p = blockIdx.x % PBLK;
    const int* ei = v == 0 ? e0 : v == 1 ? e1 : e2;
    __shared__ int cur[NBUCK];
    for (int i = threadIdx.x; i < NBUCK; i += 256) cur[i] = blockOffT[(size_t)i * TOTB + blockIdx.x];
    __syncthreads();
    int ea = p * CH, ebnd = min(EE, ea + CH);
    unsigned int* pb = pairbuf + (size_t)v * EE;
    int e = ea + threadIdx.x;
    for (; e + 768 < ebnd; e += 1024) {
        unsigned s0 = (unsigned)ei[e],       d0 = (unsigned)ei[EE + e];
        unsigned s1 = (unsigned)ei[e + 256], d1 = (unsigned)ei[EE + e + 256];
        unsigned s2 = (unsigned)ei[e + 512], d2 = (unsigned)ei[EE + e + 512];
        unsigned s3 = (unsigned)ei[e + 768], d3 = (unsigned)ei[EE + e + 768];
        int p0 = atomicAdd(&cur[d0 >> 8], 1);
        int p1 = atomicAdd(&cur[d1 >> 8], 1);
        int p2 = atomicAdd(&cur[d2 >> 8], 1);
        int p3 = atomicAdd(&cur[d3 >> 8], 1);
        pb[p0] = (s0 << 8) | (d0 & 255u);
        pb[p1] = (s1 << 8) | (d1 & 255u);
        pb[p2] = (s2 << 8) | (d2 & 255u);
        pb[p3] = (s3 << 8) | (d3 & 255u);
    }
    for (; e < ebnd; e += 256) {
        unsigned s = (unsigned)ei[e], d = (unsigned)ei[EE + e];
        int pos = atomicAdd(&cur[d >> 8], 1);
        pb[pos] = (s << 8) | (d & 255u);
    }
}

// ---------------------------------------------------------------- CSR: fine sort + self-loops
__global__ __launch_bounds__(256) void csr_fine(const unsigned int* __restrict__ pairbuf,
                                                const int* __restrict__ btot,
                                                const int* __restrict__ ebstart,
                                                const int* __restrict__ bstart,
                                                int* __restrict__ deg3,
                                                int* __restrict__ start3,
                                                unsigned int* __restrict__ ebuf3) {
    int v = blockIdx.x / NBUCK, b = blockIdx.x - v * NBUCK;
    int cnt   = btot[v * NBUCK + b];
    int pbase = ebstart[v * (NBUCK + 1) + b];
    int obase = bstart[v * (NBUCK + 1) + b];
    const unsigned int* pb = pairbuf + (size_t)v * EE + pbase;
    unsigned int* eb = ebuf3 + (size_t)v * EPV + obase;
    __shared__ int hist[256], scan[256], cur[256];
    int t = threadIdx.x;
    int node = b * 256 + t;
    int valid = (node < NN) ? 1 : 0;
    hist[t] = valid;
    __syncthreads();
    {
        int i = t;
        for (; i + 768 < cnt; i += 1024) {
            unsigned v0 = pb[i], v1 = pb[i + 256], v2 = pb[i + 512], v3 = pb[i + 768];
            atomicAdd(&hist[v0 & 255u], 1);
            atomicAdd(&hist[v1 & 255u], 1);
            atomicAdd(&hist[v2 & 255u], 1);
            atomicAdd(&hist[v3 & 255u], 1);
        }
        for (; i < cnt; i += 256) atomicAdd(&hist[pb[i] & 255u], 1);
    }
    __syncthreads();
    scan[t] = hist[t];
    __syncthreads();
    for (int s = 1; s < 256; s <<= 1) {
        int u = (t >= s) ? scan[t - s] : 0;
        __syncthreads();
        scan[t] += u;
        __syncthreads();
    }
    int excl = scan[t] - hist[t];
    cur[t] = excl + valid;
    if (valid) eb[excl] = (((unsigned)node) << 8) | ((unsigned)node & 255u);   // self-loop first
    __syncthreads();
    {
        int i = t;
        for (; i + 768 < cnt; i += 1024) {
            unsigned v0 = pb[i], v1 = pb[i + 256], v2 = pb[i + 512], v3 = pb[i + 768];
            int p0 = atomicAdd(&cur[v0 & 255u], 1);
            int p1 = atomicAdd(&cur[v1 & 255u], 1);
            int p2 = atomicAdd(&cur[v2 & 255u], 1);
            int p3 = atomicAdd(&cur[v3 & 255u], 1);
            eb[p0] = v0; eb[p1] = v1; eb[p2] = v2; eb[p3] = v3;
        }
        for (; i < cnt; i += 256) {
            unsigned int val = pb[i];
            int pos = atomicAdd(&cur[val & 255u], 1);
            eb[pos] = val;
        }
    }
    if (valid) {
        deg3[v * NN + node] = hist[t];
        start3[v * NN + node] = obase + excl;
    }
}

// ---------------------------------------------------------------- GAT aggregate (wave/dst, inline weights)
__global__ __launch_bounds__(256) void aggregate_kernel(const unsigned short* __restrict__ xh,
                                                        const int* __restrict__ start,
                                                        const int* __restrict__ deg,
                                                        const unsigned int* __restrict__ ebuf,
                                                        const float* __restrict__ a_src,
                                                        const float* __restrict__ a_dst,
                                                        const float* __restrict__ bias,
                                                        const float* __restrict__ gw,
                                                        const float* __restrict__ gb,
                                                        unsigned short* __restrict__ hvb,
                                                        float* __restrict__ gexpv) {
    int node = (blockIdx.x * 256 + threadIdx.x) >> 6;
    int lane = threadIdx.x & 63;
    if (node >= NN) return;
    int h = lane >> 4;
    int st = start[node];
    int cnt = deg[node];
    const char* xb = (const char*)xh;
    int laneoff = lane * 4;                 // byte offset within 256B row
    float4 ad4 = *(const float4*)(a_dst + (size_t)node * 4);

    float accx = 0.f, accy = 0.f, den = 0.f;
    for (int j0 = 0; j0 < cnt; j0 += 64) {
        int nj = min(64, cnt - j0);
        int src_l = 0;
        unsigned u01 = 0, u23 = 0;
        if (lane < nj) {
            src_l = (int)(ebuf[st + j0 + lane] >> 8);
            float4 as4 = *(const float4*)(a_src + (size_t)src_l * 4);
            float t0 = as4.x + ad4.x, t1 = as4.y + ad4.y;
            float t2 = as4.z + ad4.z, t3 = as4.w + ad4.w;
            t0 = fmaxf(t0, 0.f) + 0.2f * fminf(t0, 0.f);
            t1 = fmaxf(t1, 0.f) + 0.2f * fminf(t1, 0.f);
            t2 = fmaxf(t2, 0.f) + 0.2f * fminf(t2, 0.f);
            t3 = fmaxf(t3, 0.f) + 0.2f * fminf(t3, 0.f);
            u01 = (unsigned)f2h(exp2f(t0 * 1.442695041f)) |
                  ((unsigned)f2h(exp2f(t1 * 1.442695041f)) << 16);
            u23 = (unsigned)f2h(exp2f(t2 * 1.442695041f)) |
                  ((unsigned)f2h(exp2f(t3 * 1.442695041f)) << 16);
        }
        int jj = 0;
        for (; jj + 4 <= nj; jj += 4) {
            int s0 = __builtin_amdgcn_readlane(src_l, jj);
            int s1 = __builtin_amdgcn_readlane(src_l, jj + 1);
            int s2 = __builtin_amdgcn_readlane(src_l, jj + 2);
            int s3 = __builtin_amdgcn_readlane(src_l, jj + 3);
            unsigned pa0 = (unsigned)__builtin_amdgcn_readlane((int)u01, jj);
            unsigned pb0 = (unsigned)__builtin_amdgcn_readlane((int)u23, jj);
            unsigned pa1 = (unsigned)__builtin_amdgcn_readlane((int)u01, jj + 1);
            unsigned pb1 = (unsigned)__builtin_amdgcn_readlane((int)u23, jj + 1);
            unsigned pa2 = (unsigned)__builtin_amdgcn_readlane((int)u01, jj + 2);
            unsigned pb2 = (unsigned)__builtin_amdgcn_readlane((int)u23, jj + 2);
            unsigned pa3 = (unsigned)__builtin_amdgcn_readlane((int)u01, jj + 3);
            unsigned pb3 = (unsigned)__builtin_amdgcn_readlane((int)u23, jj + 3);
            unsigned k0 = (h < 2) ? pa0 : pb0;
            unsigned k1 = (h < 2) ? pa1 : pb1;
            unsigned k2 = (h < 2) ? pa2 : pb2;
            unsigned k3 = (h < 2) ? pa3 : pb3;
            float w0 = h2f((unsigned short)((h & 1) ? (k0 >> 16) : (k0 & 0xffffu)));
            float w1 = h2f((unsigned short)((h & 1) ? (k1 >> 16) : (k1 & 0xffffu)));
            float w2 = h2f((unsigned short)((h & 1) ? (k2 >> 16) : (k2 & 0xffffu)));
            float w3 = h2f((unsigned short)((h & 1) ? (k3 >> 16) : (k3 & 0xffffu)));
            unsigned int x0 = *(const unsigned int*)(xb + (((size_t)(unsigned)s0) << 8) + laneoff);
            unsigned int x1 = *(const unsigned int*)(xb + (((size_t)(unsigned)s1) << 8) + laneoff);
            unsigned int x2 = *(const unsigned int*)(xb + (((size_t)(unsigned)s2) << 8) + laneoff);
            unsigned int x3 = *(const unsigned int*)(xb + (((size_t)(unsigned)s3) << 8) + laneoff);
            den += (w0 + w1) + (w2 + w3);
            accx = fmaf(w0, __uint_as_float(x0 << 16), accx);
            accy = fmaf(w0, __uint_as_float(x0 & 0xffff0000u), accy);
            accx = fmaf(w1, __uint_as_float(x1 << 16), accx);
            accy = fmaf(w1, __uint_as_float(x1 & 0xffff0000u), accy);
            accx = fmaf(w2, __uint_as_float(x2 << 16), accx);
            accy = fmaf(w2, __uint_as_float(x2 & 0xffff0000u), accy);
            accx = fmaf(w3, __uint_as_float(x3 << 16), accx);
            accy = fmaf(w3, __uint_as_float(x3 & 0xffff0000u), accy);
        }
        for (; jj < nj; jj++) {
            int s = __builtin_amdgcn_readlane(src_l, jj);
            unsigned pa = (unsigned)__builtin_amdgcn_readlane((int)u01, jj);
            unsigned pbk = (unsigned)__builtin_amdgcn_readlane((int)u23, jj);
            unsigned k = (h < 2) ? pa : pbk;
            float w = h2f((unsigned short)((h & 1) ? (k >> 16) : (k & 0xffffu)));
            unsigned int xv = *(const unsigned int*)(xb + (((size_t)(unsigned)s) << 8) + laneoff);
            den += w;
            accx = fmaf(w, __uint_as_float(xv << 16), accx);
            accy = fmaf(w, __uint_as_float(xv & 0xffff0000u), accy);
        }
    }
    float inv = 1.0f / den;
    float2 bb = *(const float2*)(bias + lane * 2);
    float o0 = accx * inv + bb.x;
    float o1 = accy * inv + bb.y;
    o0 = o0 > 0.f ? o0 : exp2f(o0 * 1.442695041f) - 1.0f;   // ELU
    o1 = o1 > 0.f ? o1 : exp2f(o1 * 1.442695041f) - 1.0f;
    unsigned int packed = (unsigned)f2bf(o0) | ((unsigned)f2bf(o1) << 16);
    *(unsigned int*)(hvb + (size_t)node * 128 + lane * 2) = packed;
    float2 g2 = *(const float2*)(gw + lane * 2);
    float gp = o0 * g2.x + o1 * g2.y;
    #pragma unroll
    for (int m = 1; m < 64; m <<= 1) gp += __shfl_xor(gp, m);
    if (lane == 0) gexpv[node] = exp2f((gp + gb[0]) * 1.442695041f);
}

// ---------------------------------------------------------------- pool: block/graph (bf16 hv)
__global__ __launch_bounds__(1024) void pool_kernel(const unsigned short* __restrict__ hvb,
                                                    const float* __restrict__ gexpv,
                                                    const int* __restrict__ batch,
                                                    float* __restrict__ gout,
                                                    int voff) {
    int b = blockIdx.x;
    int g = threadIdx.x >> 7;
    int ch = threadIdx.x & 127;
    int l = 0, r = NN;
    while (l < r) { int m = (l + r) >> 1; if (batch[m] < b) l = m + 1; else r = m; }
    int s0 = l;
    r = NN;
    while (l < r) { int m = (l + r) >> 1; if (batch[m] < b + 1) l = m + 1; else r = m; }
    int s1 = l;
    float acc = 0.f, wsum = 0.f;
    for (int n = s0 + g; n < s1; n += 8) {
        float w = gexpv[n];
        wsum += w;
        acc = fmaf(w, bf2f(hvb[(size_t)n * 128 + ch]), acc);
    }
    __shared__ float sacc[8][128];
    __shared__ float sws[8];
    sacc[g][ch] = acc;
    if (ch == 0) sws[g] = wsum;
    __syncthreads();
    if (g == 0) {
        float a = 0.f, w = 0.f;
        #pragma unroll
        for (int i = 0; i < 8; i++) { a += sacc[i][ch]; w += sws[i]; }
        gout[b * 384 + voff + ch] = (s1 > s0) ? a / w : 0.f;
    }
}

// ---------------------------------------------------------------- classifier
__global__ __launch_bounds__(128) void clf_kernel(const float* __restrict__ gout,
                                                  const float* __restrict__ W1,
                                                  const float* __restrict__ b1,
                                                  const float* __restrict__ W2,
                                                  const float* __restrict__ b2,
                                                  float* __restrict__ out) {
    int b = blockIdx.x;
    int j = threadIdx.x;
    float acc = b1[j];
    for (int k = 0; k < 384; k++) acc = fmaf(gout[b * 384 + k], W1[k * 128 + j], acc);
    acc = acc > 0.f ? acc : 0.01f * acc;
    float p = acc * W2[j];
    #pragma unroll
    for (int m = 1; m < 64; m <<= 1) p += __shfl_xor(p, m);
    __shared__ float sh[2];
    if ((j & 63) == 0) sh[j >> 6] = p;
    __syncthreads();
    if (j == 0) out[b] = sh[0] + sh[1] + b2[0];
}

// ---------------------------------------------------------------- launch
extern "C" void kernel_launch(void* const* d_in, const int* in_sizes, int n_in,
                              void* d_out, int out_size, void* d_ws, size_t ws_size,
                              hipStream_t stream) {
    const float* x      = (const float*)d_in[0];
    const int*   ei[3]  = {(const int*)d_in[1], (const int*)d_in[2], (const int*)d_in[3]};
    const int*   batch  = (const int*)d_in[4];
    const float* ln_g   = (const float*)d_in[5];
    const float* ln_b   = (const float*)d_in[6];
    const float* proj_W = (const float*)d_in[7];
    const float* proj_b = (const float*)d_in[8];
    const float* Wv[3]  = {(const float*)d_in[9],  (const float*)d_in[13], (const float*)d_in[17]};
    const float* asv[3] = {(const float*)d_in[10], (const float*)d_in[14], (const float*)d_in[18]};
    const float* adv[3] = {(const float*)d_in[11], (const float*)d_in[15], (const float*)d_in[19]};
    const float* bv[3]  = {(const float*)d_in[12], (const float*)d_in[16], (const float*)d_in[20]};
    const float* gate_W = (const float*)d_in[21];
    const float* gate_b = (const float*)d_in[22];
    const float* clf_W1 = (const float*)d_in[23];
    const float* clf_b1 = (const float*)d_in[24];
    const float* clf_W2 = (const float*)d_in[25];
    const float* clf_b2 = (const float*)d_in[26];
    float* out = (float*)d_out;

    (void)in_sizes; (void)n_in; (void)out_size; (void)ws_size;

    // ---- workspace layout ----
    char* base = (char*)d_ws;
    size_t off = 0;
    auto nxt = [&](size_t bytes) { char* r = base + off; off += (bytes + 255) & ~(size_t)255; return r; };
    unsigned short* h0   = (unsigned short*)nxt((size_t)ROWS_PAD * 128 * 2);
    unsigned short* xh   = (unsigned short*)nxt((size_t)ROWS_PAD * 128 * 2);
    unsigned short* hvb  = (unsigned short*)nxt((size_t)NN * 128 * 2);
    unsigned short* WT   = (unsigned short*)nxt(4 * 16384 * 2);
    float* c12    = (float*)nxt(256 * 4);
    float* a_src  = (float*)nxt((size_t)ROWS_PAD * 4 * 4);
    float* a_dst  = (float*)nxt((size_t)ROWS_PAD * 4 * 4);
    float* gexpv  = (float*)nxt(NN * 4);
    float* gout   = (float*)nxt(BB * 384 * 4);
    int* deg3     = (int*)nxt(3 * NN * 4);
    int* start3   = (int*)nxt(3 * NN * 4);
    unsigned int* ebuf3 = (unsigned int*)nxt(((size_t)3 * EPV + 64) * 4);
    int* btot     = (int*)nxt(3 * NBUCK * 4);
    int* ebstart  = (int*)nxt(3 * (NBUCK + 1) * 4);
    int* bstart   = (int*)nxt(3 * (NBUCK + 1) * 4);
    int* blockHistT = (int*)nxt((size_t)NBUCK * TOTB * 4);
    int* blockOffT  = (int*)nxt((size_t)NBUCK * TOTB * 4);
    unsigned int* pairbuf = (unsigned int*)nxt((size_t)3 * EE * 4);

    // 1. weight packs + LN affine constants
    pack_wt<<<dim3(64, 4), 256, 0, stream>>>(proj_W, Wv[0], Wv[1], Wv[2], ln_g, WT);
    ln_consts<<<1, 128, 0, stream>>>(proj_W, ln_g, ln_b, c12);
    // 2. CSR build (with self-loops folded in)
    csr_hist<<<TOTB, 256, 0, stream>>>(ei[0], ei[1], ei[2], blockHistT);
    csr_bsum<<<(3 * NBUCK + 3) / 4, 256, 0, stream>>>(blockHistT, btot);
    csr_scan<<<3, 512, 0, stream>>>(btot, ebstart, bstart);
    csr_boff<<<(3 * NBUCK + 3) / 4, 256, 0, stream>>>(blockHistT, ebstart, blockOffT);
    csr_scatter<<<TOTB, 256, 0, stream>>>(ei[0], ei[1], ei[2], blockOffT, pairbuf);
    csr_fine<<<3 * NBUCK, 256, 0, stream>>>(pairbuf, btot, ebstart, bstart, deg3, start3, ebuf3);
    // 3. h0 = leaky(LN(x) @ proj_W + proj_b)  — LN fused into GEMM
    gemm_proj<<<782, 256, 0, stream>>>(x, WT, c12, proj_b, h0);
    // 4. views
    for (int v = 0; v < 3; v++) {
        gemm_view<<<782, 256, 0, stream>>>(h0, WT + (1 + v) * 16384, xh,
                                           asv[v], adv[v], a_src, a_dst);
        aggregate_kernel<<<25000, 256, 0, stream>>>(xh, start3 + v * NN, deg3 + v * NN,
                                                    ebuf3 + (size_t)v * EPV,
                                                    a_src, a_dst,
                                                    bv[v], gate_W, gate_b, hvb, gexpv);
        pool_kernel<<<256, 1024, 0, stream>>>(hvb, gexpv, batch, gout, v * 128);
    }
    // 5. classifier
    clf_kernel<<<256, 128, 0, stream>>>(gout, clf_W1, clf_b1, clf_W2, clf_b2, out);
}

// Round 9
// 696.132 us; speedup vs baseline: 2.6527x; 1.0202x over previous
//
#include <hip/hip_runtime.h>
#include <hip/hip_bf16.h>
#include <hip/hip_fp16.h>
#include <math.h>

#define NN 100000
#define EE 1600000
#define BB 256
#define NBUCK 391          // ceil(NN/256) coarse buckets (dst>>8)
#define PBLK 384           // blocks per view in bucket pass
#define CH 4167            // edges per block (384*4167 >= EE)
#define TOTB (3 * PBLK)    // total bucket-pass blocks
#define ROWS_PAD 100096    // 782*128
#define EPV (EE + NN)      // entries per view incl self-loops
#define LOG2E 1.442695041f

typedef short bf16x8 __attribute__((ext_vector_type(8)));
typedef float f32x4 __attribute__((ext_vector_type(4)));

__device__ __forceinline__ unsigned short f2bf(float f) {
    __hip_bfloat16 h = __float2bfloat16(f);   // RNE
    return *(unsigned short*)&h;
}
__device__ __forceinline__ unsigned short f2h(float f) {
    __half h = __float2half(f);               // RNE
    return *(unsigned short*)&h;
}
__device__ __forceinline__ float h2f(unsigned short u) {
    __half h = *(__half*)&u;
    return __half2float(h);
}

// ---------------------------------------------------------------- pack W^T to bf16 [n][k]
// which==0 (proj): fold ln_g -> bf16(g[k]*W[k,n])
__global__ __launch_bounds__(256) void pack_wt(const float* __restrict__ W0,
                                               const float* __restrict__ W1,
                                               const float* __restrict__ W2,
                                               const float* __restrict__ W3,
                                               const float* __restrict__ ln_g,
                                               unsigned short* __restrict__ WT) {
    int which = blockIdx.y;
    const float* W = which == 0 ? W0 : which == 1 ? W1 : which == 2 ? W2 : W3;
    int i = blockIdx.x * 256 + threadIdx.x;   // 0..16383
    int n = i >> 7, k = i & 127;
    float v = W[k * 128 + n];
    if (which == 0) v *= ln_g[k];
    WT[which * 16384 + i] = f2bf(v);
}

// ---------------------------------------------------------------- LN affine constants
__global__ __launch_bounds__(128) void ln_consts(const float* __restrict__ W,
                                                 const float* __restrict__ g,
                                                 const float* __restrict__ b,
                                                 float* __restrict__ c12) {
    int n = threadIdx.x;
    float c1 = 0.f, c2 = 0.f;
    for (int k = 0; k < 128; k++) {
        float w = W[k * 128 + n];
        c1 = fmaf(g[k], w, c1);
        c2 = fmaf(b[k], w, c2);
    }
    c12[n] = c1;
    c12[128 + n] = c2;
}

// ================================================================ device bodies

// ---- coarse histogram body (blockHistT layout [bucket][TOTB])
__device__ __forceinline__ void hist_body(int bid, int tid,
                                          const int* __restrict__ e0,
                                          const int* __restrict__ e1,
                                          const int* __restrict__ e2,
                                          int* __restrict__ blockHistT) {
    int v = bid / PBLK, p = bid % PBLK;
    const int* ei = v == 0 ? e0 : v == 1 ? e1 : e2;
    __shared__ int h[NBUCK];
    for (int i = tid; i < NBUCK; i += 256) h[i] = 0;
    __syncthreads();
    int ea = p * CH, ebnd = min(EE, ea + CH);
    int e = ea + tid;
    for (; e + 768 < ebnd; e += 1024) {
        int d0 = ei[EE + e], d1 = ei[EE + e + 256];
        int d2 = ei[EE + e + 512], d3 = ei[EE + e + 768];
        atomicAdd(&h[((unsigned)d0) >> 8], 1);
        atomicAdd(&h[((unsigned)d1) >> 8], 1);
        atomicAdd(&h[((unsigned)d2) >> 8], 1);
        atomicAdd(&h[((unsigned)d3) >> 8], 1);
    }
    for (; e < ebnd; e += 256) atomicAdd(&h[((unsigned)ei[EE + e]) >> 8], 1);
    __syncthreads();
    for (int i = tid; i < NBUCK; i += 256) blockHistT[i * TOTB + bid] = h[i];
}

// ---- proj GEMM body (fused LayerNorm), writes h0 bf16
__device__ __forceinline__ void proj_body(int nb, int tid,
                                          const float* __restrict__ X,
                                          const unsigned short* __restrict__ WT,
                                          const float* __restrict__ c12,
                                          const float* __restrict__ pb,
                                          unsigned short* __restrict__ Out) {
    int w = tid >> 6, lane = tid & 63;
    int ln = lane & 15, oct = lane >> 4;
    int row0 = nb * 128 + w * 32;

    f32x4 acc[2][8];
    #pragma unroll
    for (int i = 0; i < 2; i++)
        #pragma unroll
        for (int j = 0; j < 8; j++) acc[i][j] = (f32x4){0.f, 0.f, 0.f, 0.f};

    const float* X0 = X + (size_t)min(row0 + ln, NN - 1) * 128;
    const float* X1 = X + (size_t)min(row0 + 16 + ln, NN - 1) * 128;
    const bf16x8* Wr = (const bf16x8*)(WT + (size_t)ln * 128);

    float s0 = 0.f, q0 = 0.f, s1 = 0.f, q1 = 0.f;
    #pragma unroll
    for (int kq = 0; kq < 4; kq++) {
        int koff = kq * 4 + oct;
        float4 xa = *(const float4*)(X0 + koff * 8);
        float4 xb = *(const float4*)(X0 + koff * 8 + 4);
        float4 ya = *(const float4*)(X1 + koff * 8);
        float4 yb = *(const float4*)(X1 + koff * 8 + 4);
        s0 += (xa.x + xa.y) + (xa.z + xa.w) + (xb.x + xb.y) + (xb.z + xb.w);
        q0 += xa.x * xa.x + xa.y * xa.y + xa.z * xa.z + xa.w * xa.w
            + xb.x * xb.x + xb.y * xb.y + xb.z * xb.z + xb.w * xb.w;
        s1 += (ya.x + ya.y) + (ya.z + ya.w) + (yb.x + yb.y) + (yb.z + yb.w);
        q1 += ya.x * ya.x + ya.y * ya.y + ya.z * ya.z + ya.w * ya.w
            + yb.x * yb.x + yb.y * yb.y + yb.z * yb.z + yb.w * yb.w;
        bf16x8 a0, a1;
        a0[0] = (short)f2bf(xa.x); a0[1] = (short)f2bf(xa.y); a0[2] = (short)f2bf(xa.z); a0[3] = (short)f2bf(xa.w);
        a0[4] = (short)f2bf(xb.x); a0[5] = (short)f2bf(xb.y); a0[6] = (short)f2bf(xb.z); a0[7] = (short)f2bf(xb.w);
        a1[0] = (short)f2bf(ya.x); a1[1] = (short)f2bf(ya.y); a1[2] = (short)f2bf(ya.z); a1[3] = (short)f2bf(ya.w);
        a1[4] = (short)f2bf(yb.x); a1[5] = (short)f2bf(yb.y); a1[6] = (short)f2bf(yb.z); a1[7] = (short)f2bf(yb.w);
        #pragma unroll
        for (int ct = 0; ct < 8; ct++) {
            bf16x8 bfr = Wr[ct * 16 * 16 + koff];
            acc[0][ct] = __builtin_amdgcn_mfma_f32_16x16x32_bf16(a0, bfr, acc[0][ct], 0, 0, 0);
            acc[1][ct] = __builtin_amdgcn_mfma_f32_16x16x32_bf16(a1, bfr, acc[1][ct], 0, 0, 0);
        }
    }
    #pragma unroll
    for (int m = 16; m < 64; m <<= 1) {
        s0 += __shfl_xor(s0, m); q0 += __shfl_xor(q0, m);
        s1 += __shfl_xor(s1, m); q1 += __shfl_xor(q1, m);
    }
    float mu0 = s0 * (1.0f / 128.0f);
    float rs0 = rsqrtf(q0 * (1.0f / 128.0f) - mu0 * mu0 + 1e-5f);
    float mu1 = s1 * (1.0f / 128.0f);
    float rs1 = rsqrtf(q1 * (1.0f / 128.0f) - mu1 * mu1 + 1e-5f);

    float c1v[8], c2v[8], pbv[8];
    #pragma unroll
    for (int ct = 0; ct < 8; ct++) {
        c1v[ct] = c12[ct * 16 + ln];
        c2v[ct] = c12[128 + ct * 16 + ln];
        pbv[ct] = pb[ct * 16 + ln];
    }
    #pragma unroll
    for (int rt = 0; rt < 2; rt++) {
        #pragma unroll
        for (int r = 0; r < 4; r++) {
            int src = oct * 4 + r;
            float rs_r = __shfl(rt ? rs1 : rs0, src);
            float mu_r = __shfl(rt ? mu1 : mu0, src);
            int row = row0 + rt * 16 + oct * 4 + r;
            #pragma unroll
            for (int ct = 0; ct < 8; ct++) {
                float v = rs_r * acc[rt][ct][r] - rs_r * mu_r * c1v[ct] + c2v[ct] + pbv[ct];
                v = v > 0.f ? v : 0.01f * v;
                Out[(size_t)row * 128 + ct * 16 + ln] = f2bf(v);
            }
        }
    }
}

// ---- coarse scatter body
__device__ __forceinline__ void scatter_body(int bid, int tid,
                                             const int* __restrict__ e0,
                                             const int* __restrict__ e1,
                                             const int* __restrict__ e2,
                                             const int* __restrict__ blockOffT,
                                             unsigned int* __restrict__ pairbuf) {
    int v = bid / PBLK, p = bid % PBLK;
    const int* ei = v == 0 ? e0 : v == 1 ? e1 : e2;
    __shared__ int cur[NBUCK];
    for (int i = tid; i < NBUCK; i += 256) cur[i] = blockOffT[(size_t)i * TOTB + bid];
    __syncthreads();
    int ea = p * CH, ebnd = min(EE, ea + CH);
    unsigned int* pbuf = pairbuf + (size_t)v * EE;
    int e = ea + tid;
    for (; e + 768 < ebnd; e += 1024) {
        unsigned s0 = (unsigned)ei[e],       d0 = (unsigned)ei[EE + e];
        unsigned s1 = (unsigned)ei[e + 256], d1 = (unsigned)ei[EE + e + 256];
        unsigned s2 = (unsigned)ei[e + 512], d2 = (unsigned)ei[EE + e + 512];
        unsigned s3 = (unsigned)ei[e + 768], d3 = (unsigned)ei[EE + e + 768];
        int p0 = atomicAdd(&cur[d0 >> 8], 1);
        int p1 = atomicAdd(&cur[d1 >> 8], 1);
        int p2 = atomicAdd(&cur[d2 >> 8], 1);
        int p3 = atomicAdd(&cur[d3 >> 8], 1);
        pbuf[p0] = (s0 << 8) | (d0 & 255u);
        pbuf[p1] = (s1 << 8) | (d1 & 255u);
        pbuf[p2] = (s2 << 8) | (d2 & 255u);
        pbuf[p3] = (s3 << 8) | (d3 & 255u);
    }
    for (; e < ebnd; e += 256) {
        unsigned s = (unsigned)ei[e], d = (unsigned)ei[EE + e];
        int pos = atomicAdd(&cur[d >> 8], 1);
        pbuf[pos] = (s << 8) | (d & 255u);
    }
}

// ---- view GEMM body (bf16 A in, fp16 xh out, fused att reduction)
__device__ __forceinline__ void view_body(int nb, int tid,
                                          const unsigned short* __restrict__ h0,
                                          const unsigned short* __restrict__ WTv,
                                          const float* __restrict__ asw,
                                          const float* __restrict__ adw,
                                          unsigned short* __restrict__ Out,
                                          float* __restrict__ a_src,
                                          float* __restrict__ a_dst) {
    int w = tid >> 6, lane = tid & 63;
    int ln = lane & 15, oct = lane >> 4;
    int row0 = nb * 128 + w * 32;

    f32x4 acc[2][8];
    #pragma unroll
    for (int i = 0; i < 2; i++)
        #pragma unroll
        for (int j = 0; j < 8; j++) acc[i][j] = (f32x4){0.f, 0.f, 0.f, 0.f};

    const bf16x8* Ar0 = (const bf16x8*)(h0 + (size_t)(row0 + ln) * 128);
    const bf16x8* Ar1 = (const bf16x8*)(h0 + (size_t)(row0 + 16 + ln) * 128);
    const bf16x8* Wr  = (const bf16x8*)(WTv + (size_t)ln * 128);

    #pragma unroll
    for (int kq = 0; kq < 4; kq++) {
        int koff = kq * 4 + oct;
        bf16x8 a0 = Ar0[koff];
        bf16x8 a1 = Ar1[koff];
        #pragma unroll
        for (int ct = 0; ct < 8; ct++) {
            bf16x8 bfr = Wr[ct * 16 * 16 + koff];
            acc[0][ct] = __builtin_amdgcn_mfma_f32_16x16x32_bf16(a0, bfr, acc[0][ct], 0, 0, 0);
            acc[1][ct] = __builtin_amdgcn_mfma_f32_16x16x32_bf16(a1, bfr, acc[1][ct], 0, 0, 0);
        }
    }
    float aswv[8], adwv[8];
    #pragma unroll
    for (int ct = 0; ct < 8; ct++) { aswv[ct] = asw[ct * 16 + ln]; adwv[ct] = adw[ct * 16 + ln]; }

    #pragma unroll
    for (int rt = 0; rt < 2; rt++) {
        #pragma unroll
        for (int r = 0; r < 4; r++) {
            int row = row0 + rt * 16 + oct * 4 + r;
            float sh_[4] = {0.f, 0.f, 0.f, 0.f}, dh_[4] = {0.f, 0.f, 0.f, 0.f};
            #pragma unroll
            for (int ct = 0; ct < 8; ct++) {
                float vv = acc[rt][ct][r];
                Out[(size_t)row * 128 + ct * 16 + ln] = f2h(vv);
                sh_[ct >> 1] = fmaf(vv, aswv[ct], sh_[ct >> 1]);
                dh_[ct >> 1] = fmaf(vv, adwv[ct], dh_[ct >> 1]);
            }
            #pragma unroll
            for (int off = 1; off < 16; off <<= 1) {
                #pragma unroll
                for (int h = 0; h < 4; h++) {
                    sh_[h] += __shfl_xor(sh_[h], off);
                    dh_[h] += __shfl_xor(dh_[h], off);
                }
            }
            if (ln == 0) {
                *(float4*)(a_src + (size_t)row * 4) = make_float4(sh_[0], sh_[1], sh_[2], sh_[3]);
                *(float4*)(a_dst + (size_t)row * 4) = make_float4(dh_[0], dh_[1], dh_[2], dh_[3]);
            }
        }
    }
}

// ================================================================ fat/merged kernels (simple concatenation)
__global__ __launch_bounds__(256) void fat_hist_proj(const int* e0, const int* e1, const int* e2,
                                                     int* blockHistT,
                                                     const float* X, const unsigned short* WT,
                                                     const float* c12, const float* pb,
                                                     unsigned short* h0) {
    if (blockIdx.x < TOTB) hist_body(blockIdx.x, threadIdx.x, e0, e1, e2, blockHistT);
    else proj_body(blockIdx.x - TOTB, threadIdx.x, X, WT, c12, pb, h0);
}

__global__ __launch_bounds__(256) void fat_scatter_view(const int* e0, const int* e1, const int* e2,
                                                        const int* blockOffT, unsigned int* pairbuf,
                                                        const unsigned short* h0, const unsigned short* WT,
                                                        const float* as0, const float* ad0,
                                                        unsigned short* xh, float* a_src, float* a_dst) {
    if (blockIdx.x < TOTB) scatter_body(blockIdx.x, threadIdx.x, e0, e1, e2, blockOffT, pairbuf);
    else view_body(blockIdx.x - TOTB, threadIdx.x, h0, WT + 16384, as0, ad0, xh, a_src, a_dst);
}

__global__ __launch_bounds__(256) void gemm_view(const unsigned short* __restrict__ h0,
                                                 const unsigned short* __restrict__ WTv,
                                                 const float* __restrict__ asw,
                                                 const float* __restrict__ adw,
                                                 unsigned short* __restrict__ Out,
                                                 float* __restrict__ a_src,
                                                 float* __restrict__ a_dst) {
    view_body(blockIdx.x, threadIdx.x, h0, WTv, asw, adw, Out, a_src, a_dst);
}

// ================================================================ CSR small kernels
__global__ __launch_bounds__(256) void csr_bsum(const int* __restrict__ blockHistT,
                                                int* __restrict__ btot) {
    int wid = (blockIdx.x * 256 + threadIdx.x) >> 6;
    int lane = threadIdx.x & 63;
    if (wid >= 3 * NBUCK) return;
    int v = wid / NBUCK, b = wid - v * NBUCK;
    const int* row = blockHistT + (size_t)b * TOTB + v * PBLK;
    int s = 0;
    #pragma unroll
    for (int j = 0; j < 6; j++) s += row[lane * 6 + j];
    #pragma unroll
    for (int m = 1; m < 64; m <<= 1) s += __shfl_xor(s, m);
    if (lane == 0) btot[wid] = s;
}

__global__ __launch_bounds__(512) void csr_scan(const int* __restrict__ btot,
                                                int* __restrict__ ebstart,
                                                int* __restrict__ bstart) {
    int v = blockIdx.x, t = threadIdx.x;
    __shared__ int se[512], ss[512];
    int tot_e = (t < NBUCK) ? btot[v * NBUCK + t] : 0;
    int nval = (t < NBUCK) ? min(256, NN - t * 256) : 0;
    int tot_s = tot_e + nval;
    se[t] = tot_e; ss[t] = tot_s;
    __syncthreads();
    for (int s = 1; s < 512; s <<= 1) {
        int ae = (t >= s) ? se[t - s] : 0;
        int as_ = (t >= s) ? ss[t - s] : 0;
        __syncthreads();
        se[t] += ae; ss[t] += as_;
        __syncthreads();
    }
    if (t < NBUCK) {
        ebstart[v * (NBUCK + 1) + t] = se[t] - tot_e;
        bstart[v * (NBUCK + 1) + t] = ss[t] - tot_s;
    }
    if (t == NBUCK - 1) {
        ebstart[v * (NBUCK + 1) + NBUCK] = se[t];
        bstart[v * (NBUCK + 1) + NBUCK] = ss[t];
    }
}

__global__ __launch_bounds__(256) void csr_boff(const int* __restrict__ blockHistT,
                                                const int* __restrict__ ebstart,
                                                int* __restrict__ blockOffT) {
    int wid = (blockIdx.x * 256 + threadIdx.x) >> 6;
    int lane = threadIdx.x & 63;
    if (wid >= 3 * NBUCK) return;
    int v = wid / NBUCK, b = wid - v * NBUCK;
    const int* row = blockHistT + (size_t)b * TOTB + v * PBLK;
    int* orow = blockOffT + (size_t)b * TOTB + v * PBLK;
    int vals[6], lexcl[6];
    int ls = 0;
    #pragma unroll
    for (int j = 0; j < 6; j++) vals[j] = row[lane * 6 + j];
    #pragma unroll
    for (int j = 0; j < 6; j++) { lexcl[j] = ls; ls += vals[j]; }
    int incl = ls;
    #pragma unroll
    for (int m = 1; m < 64; m <<= 1) {
        int t = __shfl_up(incl, m);
        if (lane >= m) incl += t;
    }
    int wexcl = incl - ls;
    int base = ebstart[v * (NBUCK + 1) + b];
    #pragma unroll
    for (int j = 0; j < 6; j++) orow[lane * 6 + j] = base + wexcl + lexcl[j];
}

__global__ __launch_bounds__(256) void csr_fine(const unsigned int* __restrict__ pairbuf,
                                                const int* __restrict__ btot,
                                                const int* __restrict__ ebstart,
                                                const int* __restrict__ bstart,
                                                int* __restrict__ deg3,
                                                int* __restrict__ start3,
                                                unsigned int* __restrict__ ebuf3) {
    int v = blockIdx.x / NBUCK, b = blockIdx.x - v * NBUCK;
    int cnt   = btot[v * NBUCK + b];
    int pbase = ebstart[v * (NBUCK + 1) + b];
    int obase = bstart[v * (NBUCK + 1) + b];
    const unsigned int* pb = pairbuf + (size_t)v * EE + pbase;
    unsigned int* eb = ebuf3 + (size_t)v * EPV + obase;
    __shared__ int hist[256], scan[256], cur[256];
    int t = threadIdx.x;
    int node = b * 256 + t;
    int valid = (node < NN) ? 1 : 0;
    hist[t] = valid;
    __syncthreads();
    {
        int i = t;
        for (; i + 768 < cnt; i += 1024) {
            unsigned v0 = pb[i], v1 = pb[i + 256], v2 = pb[i + 512], v3 = pb[i + 768];
            atomicAdd(&hist[v0 & 255u], 1);
            atomicAdd(&hist[v1 & 255u], 1);
            atomicAdd(&hist[v2 & 255u], 1);
            atomicAdd(&hist[v3 & 255u], 1);
        }
        for (; i < cnt; i += 256) atomicAdd(&hist[pb[i] & 255u], 1);
    }
    __syncthreads();
    scan[t] = hist[t];
    __syncthreads();
    for (int s = 1; s < 256; s <<= 1) {
        int u = (t >= s) ? scan[t - s] : 0;
        __syncthreads();
        scan[t] += u;
        __syncthreads();
    }
    int excl = scan[t] - hist[t];
    cur[t] = excl + valid;
    if (valid) eb[excl] = (((unsigned)node) << 8) | ((unsigned)node & 255u);   // self-loop first
    __syncthreads();
    {
        int i = t;
        for (; i + 768 < cnt; i += 1024) {
            unsigned v0 = pb[i], v1 = pb[i + 256], v2 = pb[i + 512], v3 = pb[i + 768];
            int p0 = atomicAdd(&cur[v0 & 255u], 1);
            int p1 = atomicAdd(&cur[v1 & 255u], 1);
            int p2 = atomicAdd(&cur[v2 & 255u], 1);
            int p3 = atomicAdd(&cur[v3 & 255u], 1);
            eb[p0] = v0; eb[p1] = v1; eb[p2] = v2; eb[p3] = v3;
        }
        for (; i < cnt; i += 256) {
            unsigned int val = pb[i];
            int pos = atomicAdd(&cur[val & 255u], 1);
            eb[pos] = val;
        }
    }
    if (valid) {
        deg3[v * NN + node] = hist[t];
        start3[v * NN + node] = obase + excl;
    }
}

// ---------------------------------------------------------------- GAT aggregate (wave/dst, fp16 xh)
// Preamble: each lane computes all-4-head fp16 weights of its edge + per-lane den partials.
// Inner loop: both packs fetched via readlane, reader-side head select (CORRECT: the select
// must use the READER's head, so it happens after the broadcast, not before).
__global__ __launch_bounds__(256) void aggregate_kernel(const unsigned short* __restrict__ xh,
                                                        const int* __restrict__ start,
                                                        const int* __restrict__ deg,
                                                        const unsigned int* __restrict__ ebuf,
                                                        const float* __restrict__ a_src,
                                                        const float* __restrict__ a_dst,
                                                        const float* __restrict__ bias,
                                                        const float* __restrict__ gw,
                                                        const float* __restrict__ gb,
                                                        unsigned short* __restrict__ hvb,
                                                        float* __restrict__ gexpv) {
    int node = (blockIdx.x * 256 + threadIdx.x) >> 6;
    int lane = threadIdx.x & 63;
    if (node >= NN) return;
    int h = lane >> 4;
    int st = start[node];
    int cnt = deg[node];
    const char* xb = (const char*)xh;
    int laneoff = lane * 4;                 // byte offset within 256B fp16 row
    float4 ad4 = *(const float4*)(a_dst + (size_t)node * 4);
    int shamt = (h & 1) * 16;
    bool lowpair = (h < 2);

    float accx = 0.f, accy = 0.f;
    float d0s = 0.f, d1s = 0.f, d2s = 0.f, d3s = 0.f;
    for (int j0 = 0; j0 < cnt; j0 += 64) {
        int nj = min(64, cnt - j0);
        int src_l = 0;
        unsigned u01 = 0, u23 = 0;
        if (lane < nj) {
            src_l = (int)(ebuf[st + j0 + lane] >> 8);
            float4 as4 = *(const float4*)(a_src + (size_t)src_l * 4);
            float t0 = as4.x + ad4.x, t1 = as4.y + ad4.y;
            float t2 = as4.z + ad4.z, t3 = as4.w + ad4.w;
            t0 = fmaxf(t0, 0.f) + 0.2f * fminf(t0, 0.f);
            t1 = fmaxf(t1, 0.f) + 0.2f * fminf(t1, 0.f);
            t2 = fmaxf(t2, 0.f) + 0.2f * fminf(t2, 0.f);
            t3 = fmaxf(t3, 0.f) + 0.2f * fminf(t3, 0.f);
            unsigned short w0h = f2h(exp2f(t0 * LOG2E));
            unsigned short w1h = f2h(exp2f(t1 * LOG2E));
            unsigned short w2h = f2h(exp2f(t2 * LOG2E));
            unsigned short w3h = f2h(exp2f(t3 * LOG2E));
            d0s += h2f(w0h); d1s += h2f(w1h);   // den from the same rounded weights
            d2s += h2f(w2h); d3s += h2f(w3h);
            u01 = (unsigned)w0h | ((unsigned)w1h << 16);
            u23 = (unsigned)w2h | ((unsigned)w3h << 16);
        }
        int jj = 0;
        for (; jj + 4 <= nj; jj += 4) {
            int s0 = __builtin_amdgcn_readlane(src_l, jj);
            int s1 = __builtin_amdgcn_readlane(src_l, jj + 1);
            int s2 = __builtin_amdgcn_readlane(src_l, jj + 2);
            int s3 = __builtin_amdgcn_readlane(src_l, jj + 3);
            unsigned a0 = (unsigned)__builtin_amdgcn_readlane((int)u01, jj);
            unsigned b0 = (unsigned)__builtin_amdgcn_readlane((int)u23, jj);
            unsigned a1 = (unsigned)__builtin_amdgcn_readlane((int)u01, jj + 1);
            unsigned b1 = (unsigned)__builtin_amdgcn_readlane((int)u23, jj + 1);
            unsigned a2 = (unsigned)__builtin_amdgcn_readlane((int)u01, jj + 2);
            unsigned b2 = (unsigned)__builtin_amdgcn_readlane((int)u23, jj + 2);
            unsigned a3 = (unsigned)__builtin_amdgcn_readlane((int)u01, jj + 3);
            unsigned b3 = (unsigned)__builtin_amdgcn_readlane((int)u23, jj + 3);
            unsigned k0 = lowpair ? a0 : b0;
            unsigned k1 = lowpair ? a1 : b1;
            unsigned k2 = lowpair ? a2 : b2;
            unsigned k3 = lowpair ? a3 : b3;
            __half2 x0 = *(const __half2*)(xb + (((size_t)(unsigned)s0) << 8) + laneoff);
            __half2 x1 = *(const __half2*)(xb + (((size_t)(unsigned)s1) << 8) + laneoff);
            __half2 x2 = *(const __half2*)(xb + (((size_t)(unsigned)s2) << 8) + laneoff);
            __half2 x3 = *(const __half2*)(xb + (((size_t)(unsigned)s3) << 8) + laneoff);
            float w0 = h2f((unsigned short)(k0 >> shamt));
            float w1 = h2f((unsigned short)(k1 >> shamt));
            float w2 = h2f((unsigned short)(k2 >> shamt));
            float w3 = h2f((unsigned short)(k3 >> shamt));
            accx = fmaf(__low2float(x0), w0, accx);
            accy = fmaf(__high2float(x0), w0, accy);
            accx = fmaf(__low2float(x1), w1, accx);
            accy = fmaf(__high2float(x1), w1, accy);
            accx = fmaf(__low2float(x2), w2, accx);
            accy = fmaf(__high2float(x2), w2, accy);
            accx = fmaf(__low2float(x3), w3, accx);
            accy = fmaf(__high2float(x3), w3, accy);
        }
        for (; jj < nj; jj++) {
            int s = __builtin_amdgcn_readlane(src_l, jj);
            unsigned a = (unsigned)__builtin_amdgcn_readlane((int)u01, jj);
            unsigned bq = (unsigned)__builtin_amdgcn_readlane((int)u23, jj);
            unsigned k = lowpair ? a : bq;
            float w = h2f((unsigned short)(k >> shamt));
            __half2 xv = *(const __half2*)(xb + (((size_t)(unsigned)s) << 8) + laneoff);
            accx = fmaf(__low2float(xv), w, accx);
            accy = fmaf(__high2float(xv), w, accy);
        }
    }
    // reduce the 4 per-head denominators across lanes; select own head
    #pragma unroll
    for (int m = 1; m < 64; m <<= 1) {
        d0s += __shfl_xor(d0s, m);
        d1s += __shfl_xor(d1s, m);
        d2s += __shfl_xor(d2s, m);
        d3s += __shfl_xor(d3s, m);
    }
    float den = (h == 0) ? d0s : (h == 1) ? d1s : (h == 2) ? d2s : d3s;
    float inv = 1.0f / den;
    float2 bb = *(const float2*)(bias + lane * 2);
    float o0 = accx * inv + bb.x;
    float o1 = accy * inv + bb.y;
    o0 = o0 > 0.f ? o0 : exp2f(o0 * LOG2E) - 1.0f;   // ELU
    o1 = o1 > 0.f ? o1 : exp2f(o1 * LOG2E) - 1.0f;
    unsigned int packed = (unsigned)f2h(o0) | ((unsigned)f2h(o1) << 16);
    *(unsigned int*)(hvb + (size_t)node * 128 + lane * 2) = packed;
    float2 g2 = *(const float2*)(gw + lane * 2);
    float gp = o0 * g2.x + o1 * g2.y;
    #pragma unroll
    for (int m = 1; m < 64; m <<= 1) gp += __shfl_xor(gp, m);
    if (lane == 0) gexpv[node] = exp2f((gp + gb[0]) * LOG2E);
}

// ---------------------------------------------------------------- pool: block/graph (fp16 hv)
__global__ __launch_bounds__(1024) void pool_kernel(const unsigned short* __restrict__ hvb,
                                                    const float* __restrict__ gexpv,
                                                    const int* __restrict__ batch,
                                                    float* __restrict__ gout,
                                                    int voff) {
    int b = blockIdx.x;
    int g = threadIdx.x >> 7;
    int ch = threadIdx.x & 127;
    int l = 0, r = NN;
    while (l < r) { int m = (l + r) >> 1; if (batch[m] < b) l = m + 1; else r = m; }
    int s0 = l;
    r = NN;
    while (l < r) { int m = (l + r) >> 1; if (batch[m] < b + 1) l = m + 1; else r = m; }
    int s1 = l;
    float acc = 0.f, wsum = 0.f;
    for (int n = s0 + g; n < s1; n += 8) {
        float w = gexpv[n];
        wsum += w;
        acc = fmaf(w, h2f(hvb[(size_t)n * 128 + ch]), acc);
    }
    __shared__ float sacc[8][128];
    __shared__ float sws[8];
    sacc[g][ch] = acc;
    if (ch == 0) sws[g] = wsum;
    __syncthreads();
    if (g == 0) {
        float a = 0.f, w = 0.f;
        #pragma unroll
        for (int i = 0; i < 8; i++) { a += sacc[i][ch]; w += sws[i]; }
        gout[b * 384 + voff + ch] = (s1 > s0) ? a / w : 0.f;
    }
}

// ---------------------------------------------------------------- classifier
__global__ __launch_bounds__(128) void clf_kernel(const float* __restrict__ gout,
                                                  const float* __restrict__ W1,
                                                  const float* __restrict__ b1,
                                                  const float* __restrict__ W2,
                                                  const float* __restrict__ b2,
                                                  float* __restrict__ out) {
    int b = blockIdx.x;
    int j = threadIdx.x;
    float acc = b1[j];
    for (int k = 0; k < 384; k++) acc = fmaf(gout[b * 384 + k], W1[k * 128 + j], acc);
    acc = acc > 0.f ? acc : 0.01f * acc;
    float p = acc * W2[j];
    #pragma unroll
    for (int m = 1; m < 64; m <<= 1) p += __shfl_xor(p, m);
    __shared__ float sh[2];
    if ((j & 63) == 0) sh[j >> 6] = p;
    __syncthreads();
    if (j == 0) out[b] = sh[0] + sh[1] + b2[0];
}

// ---------------------------------------------------------------- launch
extern "C" void kernel_launch(void* const* d_in, const int* in_sizes, int n_in,
                              void* d_out, int out_size, void* d_ws, size_t ws_size,
                              hipStream_t stream) {
    const float* x      = (const float*)d_in[0];
    const int*   ei[3]  = {(const int*)d_in[1], (const int*)d_in[2], (const int*)d_in[3]};
    const int*   batch  = (const int*)d_in[4];
    const float* ln_g   = (const float*)d_in[5];
    const float* ln_b   = (const float*)d_in[6];
    const float* proj_W = (const float*)d_in[7];
    const float* proj_b = (const float*)d_in[8];
    const float* Wv[3]  = {(const float*)d_in[9],  (const float*)d_in[13], (const float*)d_in[17]};
    const float* asv[3] = {(const float*)d_in[10], (const float*)d_in[14], (const float*)d_in[18]};
    const float* adv[3] = {(const float*)d_in[11], (const float*)d_in[15], (const float*)d_in[19]};
    const float* bv[3]  = {(const float*)d_in[12], (const float*)d_in[16], (const float*)d_in[20]};
    const float* gate_W = (const float*)d_in[21];
    const float* gate_b = (const float*)d_in[22];
    const float* clf_W1 = (const float*)d_in[23];
    const float* clf_b1 = (const float*)d_in[24];
    const float* clf_W2 = (const float*)d_in[25];
    const float* clf_b2 = (const float*)d_in[26];
    float* out = (float*)d_out;

    (void)in_sizes; (void)n_in; (void)out_size; (void)ws_size;

    // ---- workspace layout ----
    char* base = (char*)d_ws;
    size_t off = 0;
    auto nxt = [&](size_t bytes) { char* r = base + off; off += (bytes + 255) & ~(size_t)255; return r; };
    unsigned short* h0   = (unsigned short*)nxt((size_t)ROWS_PAD * 128 * 2);   // bf16
    unsigned short* xh   = (unsigned short*)nxt((size_t)ROWS_PAD * 128 * 2);   // fp16
    unsigned short* hvb  = (unsigned short*)nxt((size_t)NN * 128 * 2);         // fp16
    unsigned short* WT   = (unsigned short*)nxt(4 * 16384 * 2);
    float* c12    = (float*)nxt(256 * 4);
    float* a_src  = (float*)nxt((size_t)ROWS_PAD * 4 * 4);
    float* a_dst  = (float*)nxt((size_t)ROWS_PAD * 4 * 4);
    float* gexpv  = (float*)nxt(NN * 4);
    float* gout   = (float*)nxt(BB * 384 * 4);
    int* deg3     = (int*)nxt(3 * NN * 4);
    int* start3   = (int*)nxt(3 * NN * 4);
    unsigned int* ebuf3 = (unsigned int*)nxt(((size_t)3 * EPV + 64) * 4);
    int* btot     = (int*)nxt(3 * NBUCK * 4);
    int* ebstart  = (int*)nxt(3 * (NBUCK + 1) * 4);
    int* bstart   = (int*)nxt(3 * (NBUCK + 1) * 4);
    int* blockHistT = (int*)nxt((size_t)NBUCK * TOTB * 4);
    int* blockOffT  = (int*)nxt((size_t)NBUCK * TOTB * 4);
    unsigned int* pairbuf = (unsigned int*)nxt((size_t)3 * EE * 4);

    // 1-2. weight packs + LN affine constants
    pack_wt<<<dim3(64, 4), 256, 0, stream>>>(proj_W, Wv[0], Wv[1], Wv[2], ln_g, WT);
    ln_consts<<<1, 128, 0, stream>>>(proj_W, ln_g, ln_b, c12);
    // 3. CSR histogram || proj GEMM (fused LN)
    fat_hist_proj<<<TOTB + 782, 256, 0, stream>>>(ei[0], ei[1], ei[2], blockHistT,
                                                  x, WT, c12, proj_b, h0);
    // 4-6. bucket totals, starts, per-block offsets
    csr_bsum<<<(3 * NBUCK + 3) / 4, 256, 0, stream>>>(blockHistT, btot);
    csr_scan<<<3, 512, 0, stream>>>(btot, ebstart, bstart);
    csr_boff<<<(3 * NBUCK + 3) / 4, 256, 0, stream>>>(blockHistT, ebstart, blockOffT);
    // 7. coarse scatter || view-0 GEMM
    fat_scatter_view<<<TOTB + 782, 256, 0, stream>>>(ei[0], ei[1], ei[2], blockOffT, pairbuf,
                                                     h0, WT, asv[0], adv[0], xh, a_src, a_dst);
    // 8. fine sort (+self-loops)
    csr_fine<<<3 * NBUCK, 256, 0, stream>>>(pairbuf, btot, ebstart, bstart, deg3, start3, ebuf3);
    // 9+. per view: (GEMM for v>0), aggregate, pool
    for (int v = 0; v < 3; v++) {
        if (v > 0)
            gemm_view<<<782, 256, 0, stream>>>(h0, WT + (size_t)(1 + v) * 16384,
                                               asv[v], adv[v], xh, a_src, a_dst);
        aggregate_kernel<<<25000, 256, 0, stream>>>(xh, start3 + v * NN, deg3 + v * NN,
                                                    ebuf3 + (size_t)v * EPV,
                                                    a_src, a_dst,
                                                    bv[v], gate_W, gate_b, hvb, gexpv);
        pool_kernel<<<256, 1024, 0, stream>>>(hvb, gexpv, batch, gout, v * 128);
    }
    // classifier
    clf_kernel<<<256, 128, 0, stream>>>(gout, clf_W1, clf_b1, clf_W2, clf_b2, out);
}

// Round 10
// 685.740 us; speedup vs baseline: 2.6929x; 1.0152x over previous
//
#include <hip/hip_runtime.h>
#include <hip/hip_bf16.h>
#include <hip/hip_fp16.h>
#include <math.h>

#define NN 100000
#define EE 1600000
#define BB 256
#define NBUCK 391          // ceil(NN/256) coarse buckets (dst>>8)
#define PBLK 384           // blocks per view in bucket pass
#define CH 4167            // edges per block (384*4167 >= EE)
#define TOTB (3 * PBLK)    // total bucket-pass blocks
#define ROWS_PAD 100096    // 782*128
#define EPV (EE + NN)      // entries per view incl self-loops
#define LOG2E 1.442695041f

typedef short bf16x8 __attribute__((ext_vector_type(8)));
typedef float f32x4 __attribute__((ext_vector_type(4)));

__device__ __forceinline__ unsigned short f2bf(float f) {
    __hip_bfloat16 h = __float2bfloat16(f);   // RNE
    return *(unsigned short*)&h;
}
__device__ __forceinline__ unsigned short f2h(float f) {
    __half h = __float2half(f);               // RNE
    return *(unsigned short*)&h;
}
__device__ __forceinline__ float h2f(unsigned short u) {
    __half h = *(__half*)&u;
    return __half2float(h);
}

// ---------------------------------------------------------------- pack W^T to bf16 [n][k]
// which==0 (proj): fold ln_g -> bf16(g[k]*W[k,n])
__global__ __launch_bounds__(256) void pack_wt(const float* __restrict__ W0,
                                               const float* __restrict__ W1,
                                               const float* __restrict__ W2,
                                               const float* __restrict__ W3,
                                               const float* __restrict__ ln_g,
                                               unsigned short* __restrict__ WT) {
    int which = blockIdx.y;
    const float* W = which == 0 ? W0 : which == 1 ? W1 : which == 2 ? W2 : W3;
    int i = blockIdx.x * 256 + threadIdx.x;   // 0..16383
    int n = i >> 7, k = i & 127;
    float v = W[k * 128 + n];
    if (which == 0) v *= ln_g[k];
    WT[which * 16384 + i] = f2bf(v);
}

// ---------------------------------------------------------------- LN affine constants
__global__ __launch_bounds__(128) void ln_consts(const float* __restrict__ W,
                                                 const float* __restrict__ g,
                                                 const float* __restrict__ b,
                                                 float* __restrict__ c12) {
    int n = threadIdx.x;
    float c1 = 0.f, c2 = 0.f;
    for (int k = 0; k < 128; k++) {
        float w = W[k * 128 + n];
        c1 = fmaf(g[k], w, c1);
        c2 = fmaf(b[k], w, c2);
    }
    c12[n] = c1;
    c12[128 + n] = c2;
}

// ================================================================ device bodies

// ---- coarse histogram body (blockHistT layout [bucket][TOTB])
__device__ __forceinline__ void hist_body(int bid, int tid,
                                          const int* __restrict__ e0,
                                          const int* __restrict__ e1,
                                          const int* __restrict__ e2,
                                          int* __restrict__ blockHistT) {
    int v = bid / PBLK, p = bid % PBLK;
    const int* ei = v == 0 ? e0 : v == 1 ? e1 : e2;
    __shared__ int h[NBUCK];
    for (int i = tid; i < NBUCK; i += 256) h[i] = 0;
    __syncthreads();
    int ea = p * CH, ebnd = min(EE, ea + CH);
    int e = ea + tid;
    for (; e + 768 < ebnd; e += 1024) {
        int d0 = ei[EE + e], d1 = ei[EE + e + 256];
        int d2 = ei[EE + e + 512], d3 = ei[EE + e + 768];
        atomicAdd(&h[((unsigned)d0) >> 8], 1);
        atomicAdd(&h[((unsigned)d1) >> 8], 1);
        atomicAdd(&h[((unsigned)d2) >> 8], 1);
        atomicAdd(&h[((unsigned)d3) >> 8], 1);
    }
    for (; e < ebnd; e += 256) atomicAdd(&h[((unsigned)ei[EE + e]) >> 8], 1);
    __syncthreads();
    for (int i = tid; i < NBUCK; i += 256) blockHistT[i * TOTB + bid] = h[i];
}

// ---- proj GEMM body (fused LayerNorm), writes h0 bf16
__device__ __forceinline__ void proj_body(int nb, int tid,
                                          const float* __restrict__ X,
                                          const unsigned short* __restrict__ WT,
                                          const float* __restrict__ c12,
                                          const float* __restrict__ pb,
                                          unsigned short* __restrict__ Out) {
    int w = tid >> 6, lane = tid & 63;
    int ln = lane & 15, oct = lane >> 4;
    int row0 = nb * 128 + w * 32;

    f32x4 acc[2][8];
    #pragma unroll
    for (int i = 0; i < 2; i++)
        #pragma unroll
        for (int j = 0; j < 8; j++) acc[i][j] = (f32x4){0.f, 0.f, 0.f, 0.f};

    const float* X0 = X + (size_t)min(row0 + ln, NN - 1) * 128;
    const float* X1 = X + (size_t)min(row0 + 16 + ln, NN - 1) * 128;
    const bf16x8* Wr = (const bf16x8*)(WT + (size_t)ln * 128);

    float s0 = 0.f, q0 = 0.f, s1 = 0.f, q1 = 0.f;
    #pragma unroll
    for (int kq = 0; kq < 4; kq++) {
        int koff = kq * 4 + oct;
        float4 xa = *(const float4*)(X0 + koff * 8);
        float4 xb = *(const float4*)(X0 + koff * 8 + 4);
        float4 ya = *(const float4*)(X1 + koff * 8);
        float4 yb = *(const float4*)(X1 + koff * 8 + 4);
        s0 += (xa.x + xa.y) + (xa.z + xa.w) + (xb.x + xb.y) + (xb.z + xb.w);
        q0 += xa.x * xa.x + xa.y * xa.y + xa.z * xa.z + xa.w * xa.w
            + xb.x * xb.x + xb.y * xb.y + xb.z * xb.z + xb.w * xb.w;
        s1 += (ya.x + ya.y) + (ya.z + ya.w) + (yb.x + yb.y) + (yb.z + yb.w);
        q1 += ya.x * ya.x + ya.y * ya.y + ya.z * ya.z + ya.w * ya.w
            + yb.x * yb.x + yb.y * yb.y + yb.z * yb.z + yb.w * yb.w;
        bf16x8 a0, a1;
        a0[0] = (short)f2bf(xa.x); a0[1] = (short)f2bf(xa.y); a0[2] = (short)f2bf(xa.z); a0[3] = (short)f2bf(xa.w);
        a0[4] = (short)f2bf(xb.x); a0[5] = (short)f2bf(xb.y); a0[6] = (short)f2bf(xb.z); a0[7] = (short)f2bf(xb.w);
        a1[0] = (short)f2bf(ya.x); a1[1] = (short)f2bf(ya.y); a1[2] = (short)f2bf(ya.z); a1[3] = (short)f2bf(ya.w);
        a1[4] = (short)f2bf(yb.x); a1[5] = (short)f2bf(yb.y); a1[6] = (short)f2bf(yb.z); a1[7] = (short)f2bf(yb.w);
        #pragma unroll
        for (int ct = 0; ct < 8; ct++) {
            bf16x8 bfr = Wr[ct * 16 * 16 + koff];
            acc[0][ct] = __builtin_amdgcn_mfma_f32_16x16x32_bf16(a0, bfr, acc[0][ct], 0, 0, 0);
            acc[1][ct] = __builtin_amdgcn_mfma_f32_16x16x32_bf16(a1, bfr, acc[1][ct], 0, 0, 0);
        }
    }
    #pragma unroll
    for (int m = 16; m < 64; m <<= 1) {
        s0 += __shfl_xor(s0, m); q0 += __shfl_xor(q0, m);
        s1 += __shfl_xor(s1, m); q1 += __shfl_xor(q1, m);
    }
    float mu0 = s0 * (1.0f / 128.0f);
    float rs0 = rsqrtf(q0 * (1.0f / 128.0f) - mu0 * mu0 + 1e-5f);
    float mu1 = s1 * (1.0f / 128.0f);
    float rs1 = rsqrtf(q1 * (1.0f / 128.0f) - mu1 * mu1 + 1e-5f);

    float c1v[8], c2v[8], pbv[8];
    #pragma unroll
    for (int ct = 0; ct < 8; ct++) {
        c1v[ct] = c12[ct * 16 + ln];
        c2v[ct] = c12[128 + ct * 16 + ln];
        pbv[ct] = pb[ct * 16 + ln];
    }
    #pragma unroll
    for (int rt = 0; rt < 2; rt++) {
        #pragma unroll
        for (int r = 0; r < 4; r++) {
            int src = oct * 4 + r;
            float rs_r = __shfl(rt ? rs1 : rs0, src);
            float mu_r = __shfl(rt ? mu1 : mu0, src);
            int row = row0 + rt * 16 + oct * 4 + r;
            #pragma unroll
            for (int ct = 0; ct < 8; ct++) {
                float v = rs_r * acc[rt][ct][r] - rs_r * mu_r * c1v[ct] + c2v[ct] + pbv[ct];
                v = v > 0.f ? v : 0.01f * v;
                Out[(size_t)row * 128 + ct * 16 + ln] = f2bf(v);
            }
        }
    }
}

// ---- coarse scatter body
__device__ __forceinline__ void scatter_body(int bid, int tid,
                                             const int* __restrict__ e0,
                                             const int* __restrict__ e1,
                                             const int* __restrict__ e2,
                                             const int* __restrict__ blockOffT,
                                             unsigned int* __restrict__ pairbuf) {
    int v = bid / PBLK, p = bid % PBLK;
    const int* ei = v == 0 ? e0 : v == 1 ? e1 : e2;
    __shared__ int cur[NBUCK];
    for (int i = tid; i < NBUCK; i += 256) cur[i] = blockOffT[(size_t)i * TOTB + bid];
    __syncthreads();
    int ea = p * CH, ebnd = min(EE, ea + CH);
    unsigned int* pbuf = pairbuf + (size_t)v * EE;
    int e = ea + tid;
    for (; e + 768 < ebnd; e += 1024) {
        unsigned s0 = (unsigned)ei[e],       d0 = (unsigned)ei[EE + e];
        unsigned s1 = (unsigned)ei[e + 256], d1 = (unsigned)ei[EE + e + 256];
        unsigned s2 = (unsigned)ei[e + 512], d2 = (unsigned)ei[EE + e + 512];
        unsigned s3 = (unsigned)ei[e + 768], d3 = (unsigned)ei[EE + e + 768];
        int p0 = atomicAdd(&cur[d0 >> 8], 1);
        int p1 = atomicAdd(&cur[d1 >> 8], 1);
        int p2 = atomicAdd(&cur[d2 >> 8], 1);
        int p3 = atomicAdd(&cur[d3 >> 8], 1);
        pbuf[p0] = (s0 << 8) | (d0 & 255u);
        pbuf[p1] = (s1 << 8) | (d1 & 255u);
        pbuf[p2] = (s2 << 8) | (d2 & 255u);
        pbuf[p3] = (s3 << 8) | (d3 & 255u);
    }
    for (; e < ebnd; e += 256) {
        unsigned s = (unsigned)ei[e], d = (unsigned)ei[EE + e];
        int pos = atomicAdd(&cur[d >> 8], 1);
        pbuf[pos] = (s << 8) | (d & 255u);
    }
}

// ---- view GEMM body (bf16 A in, fp16 xh out, fused att reduction)
__device__ __forceinline__ void view_body(int nb, int tid,
                                          const unsigned short* __restrict__ h0,
                                          const unsigned short* __restrict__ WTv,
                                          const float* __restrict__ asw,
                                          const float* __restrict__ adw,
                                          unsigned short* __restrict__ Out,
                                          float* __restrict__ a_src,
                                          float* __restrict__ a_dst) {
    int w = tid >> 6, lane = tid & 63;
    int ln = lane & 15, oct = lane >> 4;
    int row0 = nb * 128 + w * 32;

    f32x4 acc[2][8];
    #pragma unroll
    for (int i = 0; i < 2; i++)
        #pragma unroll
        for (int j = 0; j < 8; j++) acc[i][j] = (f32x4){0.f, 0.f, 0.f, 0.f};

    const bf16x8* Ar0 = (const bf16x8*)(h0 + (size_t)(row0 + ln) * 128);
    const bf16x8* Ar1 = (const bf16x8*)(h0 + (size_t)(row0 + 16 + ln) * 128);
    const bf16x8* Wr  = (const bf16x8*)(WTv + (size_t)ln * 128);

    #pragma unroll
    for (int kq = 0; kq < 4; kq++) {
        int koff = kq * 4 + oct;
        bf16x8 a0 = Ar0[koff];
        bf16x8 a1 = Ar1[koff];
        #pragma unroll
        for (int ct = 0; ct < 8; ct++) {
            bf16x8 bfr = Wr[ct * 16 * 16 + koff];
            acc[0][ct] = __builtin_amdgcn_mfma_f32_16x16x32_bf16(a0, bfr, acc[0][ct], 0, 0, 0);
            acc[1][ct] = __builtin_amdgcn_mfma_f32_16x16x32_bf16(a1, bfr, acc[1][ct], 0, 0, 0);
        }
    }
    float aswv[8], adwv[8];
    #pragma unroll
    for (int ct = 0; ct < 8; ct++) { aswv[ct] = asw[ct * 16 + ln]; adwv[ct] = adw[ct * 16 + ln]; }

    #pragma unroll
    for (int rt = 0; rt < 2; rt++) {
        #pragma unroll
        for (int r = 0; r < 4; r++) {
            int row = row0 + rt * 16 + oct * 4 + r;
            float sh_[4] = {0.f, 0.f, 0.f, 0.f}, dh_[4] = {0.f, 0.f, 0.f, 0.f};
            #pragma unroll
            for (int ct = 0; ct < 8; ct++) {
                float vv = acc[rt][ct][r];
                Out[(size_t)row * 128 + ct * 16 + ln] = f2h(vv);
                sh_[ct >> 1] = fmaf(vv, aswv[ct], sh_[ct >> 1]);
                dh_[ct >> 1] = fmaf(vv, adwv[ct], dh_[ct >> 1]);
            }
            #pragma unroll
            for (int off = 1; off < 16; off <<= 1) {
                #pragma unroll
                for (int h = 0; h < 4; h++) {
                    sh_[h] += __shfl_xor(sh_[h], off);
                    dh_[h] += __shfl_xor(dh_[h], off);
                }
            }
            if (ln == 0) {
                *(float4*)(a_src + (size_t)row * 4) = make_float4(sh_[0], sh_[1], sh_[2], sh_[3]);
                *(float4*)(a_dst + (size_t)row * 4) = make_float4(dh_[0], dh_[1], dh_[2], dh_[3]);
            }
        }
    }
}

// ================================================================ fat/merged kernels (simple concatenation)
__global__ __launch_bounds__(256) void fat_hist_proj(const int* e0, const int* e1, const int* e2,
                                                     int* blockHistT,
                                                     const float* X, const unsigned short* WT,
                                                     const float* c12, const float* pb,
                                                     unsigned short* h0) {
    if (blockIdx.x < TOTB) hist_body(blockIdx.x, threadIdx.x, e0, e1, e2, blockHistT);
    else proj_body(blockIdx.x - TOTB, threadIdx.x, X, WT, c12, pb, h0);
}

__global__ __launch_bounds__(256) void fat_scatter_view(const int* e0, const int* e1, const int* e2,
                                                        const int* blockOffT, unsigned int* pairbuf,
                                                        const unsigned short* h0, const unsigned short* WT,
                                                        const float* as0, const float* ad0,
                                                        unsigned short* xh, float* a_src, float* a_dst) {
    if (blockIdx.x < TOTB) scatter_body(blockIdx.x, threadIdx.x, e0, e1, e2, blockOffT, pairbuf);
    else view_body(blockIdx.x - TOTB, threadIdx.x, h0, WT + 16384, as0, ad0, xh, a_src, a_dst);
}

__global__ __launch_bounds__(256) void gemm_view(const unsigned short* __restrict__ h0,
                                                 const unsigned short* __restrict__ WTv,
                                                 const float* __restrict__ asw,
                                                 const float* __restrict__ adw,
                                                 unsigned short* __restrict__ Out,
                                                 float* __restrict__ a_src,
                                                 float* __restrict__ a_dst) {
    view_body(blockIdx.x, threadIdx.x, h0, WTv, asw, adw, Out, a_src, a_dst);
}

// ================================================================ CSR small kernels
__global__ __launch_bounds__(256) void csr_bsum(const int* __restrict__ blockHistT,
                                                int* __restrict__ btot) {
    int wid = (blockIdx.x * 256 + threadIdx.x) >> 6;
    int lane = threadIdx.x & 63;
    if (wid >= 3 * NBUCK) return;
    int v = wid / NBUCK, b = wid - v * NBUCK;
    const int* row = blockHistT + (size_t)b * TOTB + v * PBLK;
    int s = 0;
    #pragma unroll
    for (int j = 0; j < 6; j++) s += row[lane * 6 + j];
    #pragma unroll
    for (int m = 1; m < 64; m <<= 1) s += __shfl_xor(s, m);
    if (lane == 0) btot[wid] = s;
}

__global__ __launch_bounds__(512) void csr_scan(const int* __restrict__ btot,
                                                int* __restrict__ ebstart,
                                                int* __restrict__ bstart) {
    int v = blockIdx.x, t = threadIdx.x;
    __shared__ int se[512], ss[512];
    int tot_e = (t < NBUCK) ? btot[v * NBUCK + t] : 0;
    int nval = (t < NBUCK) ? min(256, NN - t * 256) : 0;
    int tot_s = tot_e + nval;
    se[t] = tot_e; ss[t] = tot_s;
    __syncthreads();
    for (int s = 1; s < 512; s <<= 1) {
        int ae = (t >= s) ? se[t - s] : 0;
        int as_ = (t >= s) ? ss[t - s] : 0;
        __syncthreads();
        se[t] += ae; ss[t] += as_;
        __syncthreads();
    }
    if (t < NBUCK) {
        ebstart[v * (NBUCK + 1) + t] = se[t] - tot_e;
        bstart[v * (NBUCK + 1) + t] = ss[t] - tot_s;
    }
    if (t == NBUCK - 1) {
        ebstart[v * (NBUCK + 1) + NBUCK] = se[t];
        bstart[v * (NBUCK + 1) + NBUCK] = ss[t];
    }
}

__global__ __launch_bounds__(256) void csr_boff(const int* __restrict__ blockHistT,
                                                const int* __restrict__ ebstart,
                                                int* __restrict__ blockOffT) {
    int wid = (blockIdx.x * 256 + threadIdx.x) >> 6;
    int lane = threadIdx.x & 63;
    if (wid >= 3 * NBUCK) return;
    int v = wid / NBUCK, b = wid - v * NBUCK;
    const int* row = blockHistT + (size_t)b * TOTB + v * PBLK;
    int* orow = blockOffT + (size_t)b * TOTB + v * PBLK;
    int vals[6], lexcl[6];
    int ls = 0;
    #pragma unroll
    for (int j = 0; j < 6; j++) vals[j] = row[lane * 6 + j];
    #pragma unroll
    for (int j = 0; j < 6; j++) { lexcl[j] = ls; ls += vals[j]; }
    int incl = ls;
    #pragma unroll
    for (int m = 1; m < 64; m <<= 1) {
        int t = __shfl_up(incl, m);
        if (lane >= m) incl += t;
    }
    int wexcl = incl - ls;
    int base = ebstart[v * (NBUCK + 1) + b];
    #pragma unroll
    for (int j = 0; j < 6; j++) orow[lane * 6 + j] = base + wexcl + lexcl[j];
}

__global__ __launch_bounds__(256) void csr_fine(const unsigned int* __restrict__ pairbuf,
                                                const int* __restrict__ btot,
                                                const int* __restrict__ ebstart,
                                                const int* __restrict__ bstart,
                                                int* __restrict__ deg3,
                                                int* __restrict__ start3,
                                                unsigned int* __restrict__ ebuf3) {
    int v = blockIdx.x / NBUCK, b = blockIdx.x - v * NBUCK;
    int cnt   = btot[v * NBUCK + b];
    int pbase = ebstart[v * (NBUCK + 1) + b];
    int obase = bstart[v * (NBUCK + 1) + b];
    const unsigned int* pb = pairbuf + (size_t)v * EE + pbase;
    unsigned int* eb = ebuf3 + (size_t)v * EPV + obase;
    __shared__ int hist[256], scan[256], cur[256];
    int t = threadIdx.x;
    int node = b * 256 + t;
    int valid = (node < NN) ? 1 : 0;
    hist[t] = valid;
    __syncthreads();
    {
        int i = t;
        for (; i + 768 < cnt; i += 1024) {
            unsigned v0 = pb[i], v1 = pb[i + 256], v2 = pb[i + 512], v3 = pb[i + 768];
            atomicAdd(&hist[v0 & 255u], 1);
            atomicAdd(&hist[v1 & 255u], 1);
            atomicAdd(&hist[v2 & 255u], 1);
            atomicAdd(&hist[v3 & 255u], 1);
        }
        for (; i < cnt; i += 256) atomicAdd(&hist[pb[i] & 255u], 1);
    }
    __syncthreads();
    scan[t] = hist[t];
    __syncthreads();
    for (int s = 1; s < 256; s <<= 1) {
        int u = (t >= s) ? scan[t - s] : 0;
        __syncthreads();
        scan[t] += u;
        __syncthreads();
    }
    int excl = scan[t] - hist[t];
    cur[t] = excl + valid;
    if (valid) eb[excl] = (((unsigned)node) << 8) | ((unsigned)node & 255u);   // self-loop first
    __syncthreads();
    {
        int i = t;
        for (; i + 768 < cnt; i += 1024) {
            unsigned v0 = pb[i], v1 = pb[i + 256], v2 = pb[i + 512], v3 = pb[i + 768];
            int p0 = atomicAdd(&cur[v0 & 255u], 1);
            int p1 = atomicAdd(&cur[v1 & 255u], 1);
            int p2 = atomicAdd(&cur[v2 & 255u], 1);
            int p3 = atomicAdd(&cur[v3 & 255u], 1);
            eb[p0] = v0; eb[p1] = v1; eb[p2] = v2; eb[p3] = v3;
        }
        for (; i < cnt; i += 256) {
            unsigned int val = pb[i];
            int pos = atomicAdd(&cur[val & 255u], 1);
            eb[pos] = val;
        }
    }
    if (valid) {
        deg3[v * NN + node] = hist[t];
        start3[v * NN + node] = obase + excl;
    }
}

// ---------------------------------------------------------------- GAT aggregate (wave/dst, fp16 xh)
// Preamble per 64-edge tile: each lane computes its edge's 4 head weights in FP32, writes them
// TRANSPOSED to LDS w[h][j] (stride 65 -> conflict-free), accumulates per-lane den partials.
// Inner loop per edge: 1 readlane(src) + 1 ds_read_b32 (16-lane broadcast, fp32 weight ready)
// + 1 global load + 2 fma. No fp16 weight round-trip at all.
__global__ __launch_bounds__(256) void aggregate_kernel(const unsigned short* __restrict__ xh,
                                                        const int* __restrict__ start,
                                                        const int* __restrict__ deg,
                                                        const unsigned int* __restrict__ ebuf,
                                                        const float* __restrict__ a_src,
                                                        const float* __restrict__ a_dst,
                                                        const float* __restrict__ bias,
                                                        const float* __restrict__ gw,
                                                        const float* __restrict__ gb,
                                                        unsigned short* __restrict__ hvb,
                                                        float* __restrict__ gexpv) {
    __shared__ float wlds[4 * 260];   // per-wave region: 260 floats = 4 heads * 65 (stride pad)
    int node = (blockIdx.x * 256 + threadIdx.x) >> 6;
    int lane = threadIdx.x & 63;
    if (node >= NN) return;
    int h = lane >> 4;
    int st = start[node];
    int cnt = deg[node];
    const char* xb = (const char*)xh;
    int laneoff = lane * 4;                 // byte offset within 256B fp16 row
    float4 ad4 = *(const float4*)(a_dst + (size_t)node * 4);
    float* ww = wlds + (threadIdx.x >> 6) * 260;     // this wave's region
    const float* wr = ww + h * 65;                   // this lane's head row

    float accx = 0.f, accy = 0.f;
    float d0s = 0.f, d1s = 0.f, d2s = 0.f, d3s = 0.f;
    for (int j0 = 0; j0 < cnt; j0 += 64) {
        int nj = min(64, cnt - j0);
        int src_l = 0;
        if (lane < nj) {
            src_l = (int)(ebuf[st + j0 + lane] >> 8);
            float4 as4 = *(const float4*)(a_src + (size_t)src_l * 4);
            float t0 = as4.x + ad4.x, t1 = as4.y + ad4.y;
            float t2 = as4.z + ad4.z, t3 = as4.w + ad4.w;
            t0 = fmaxf(t0, 0.f) + 0.2f * fminf(t0, 0.f);
            t1 = fmaxf(t1, 0.f) + 0.2f * fminf(t1, 0.f);
            t2 = fmaxf(t2, 0.f) + 0.2f * fminf(t2, 0.f);
            t3 = fmaxf(t3, 0.f) + 0.2f * fminf(t3, 0.f);
            float w0 = exp2f(t0 * LOG2E);
            float w1 = exp2f(t1 * LOG2E);
            float w2 = exp2f(t2 * LOG2E);
            float w3 = exp2f(t3 * LOG2E);
            d0s += w0; d1s += w1; d2s += w2; d3s += w3;
            ww[0 * 65 + lane] = w0;
            ww[1 * 65 + lane] = w1;
            ww[2 * 65 + lane] = w2;
            ww[3 * 65 + lane] = w3;
        }
        // same wave produces and consumes: compiler inserts lgkmcnt wait, no barrier needed
        int jj = 0;
        for (; jj + 4 <= nj; jj += 4) {
            int s0 = __builtin_amdgcn_readlane(src_l, jj);
            int s1 = __builtin_amdgcn_readlane(src_l, jj + 1);
            int s2 = __builtin_amdgcn_readlane(src_l, jj + 2);
            int s3 = __builtin_amdgcn_readlane(src_l, jj + 3);
            float w0 = wr[jj];
            float w1 = wr[jj + 1];
            float w2 = wr[jj + 2];
            float w3 = wr[jj + 3];
            __half2 x0 = *(const __half2*)(xb + (((size_t)(unsigned)s0) << 8) + laneoff);
            __half2 x1 = *(const __half2*)(xb + (((size_t)(unsigned)s1) << 8) + laneoff);
            __half2 x2 = *(const __half2*)(xb + (((size_t)(unsigned)s2) << 8) + laneoff);
            __half2 x3 = *(const __half2*)(xb + (((size_t)(unsigned)s3) << 8) + laneoff);
            accx = fmaf(__low2float(x0), w0, accx);
            accy = fmaf(__high2float(x0), w0, accy);
            accx = fmaf(__low2float(x1), w1, accx);
            accy = fmaf(__high2float(x1), w1, accy);
            accx = fmaf(__low2float(x2), w2, accx);
            accy = fmaf(__high2float(x2), w2, accy);
            accx = fmaf(__low2float(x3), w3, accx);
            accy = fmaf(__high2float(x3), w3, accy);
        }
        for (; jj < nj; jj++) {
            int s = __builtin_amdgcn_readlane(src_l, jj);
            float w = wr[jj];
            __half2 xv = *(const __half2*)(xb + (((size_t)(unsigned)s) << 8) + laneoff);
            accx = fmaf(__low2float(xv), w, accx);
            accy = fmaf(__high2float(xv), w, accy);
        }
    }
    // reduce the 4 per-head denominators across lanes; select own head
    #pragma unroll
    for (int m = 1; m < 64; m <<= 1) {
        d0s += __shfl_xor(d0s, m);
        d1s += __shfl_xor(d1s, m);
        d2s += __shfl_xor(d2s, m);
        d3s += __shfl_xor(d3s, m);
    }
    float den = (h == 0) ? d0s : (h == 1) ? d1s : (h == 2) ? d2s : d3s;
    float inv = 1.0f / den;
    float2 bb = *(const float2*)(bias + lane * 2);
    float o0 = accx * inv + bb.x;
    float o1 = accy * inv + bb.y;
    o0 = o0 > 0.f ? o0 : exp2f(o0 * LOG2E) - 1.0f;   // ELU
    o1 = o1 > 0.f ? o1 : exp2f(o1 * LOG2E) - 1.0f;
    unsigned int packed = (unsigned)f2h(o0) | ((unsigned)f2h(o1) << 16);
    *(unsigned int*)(hvb + (size_t)node * 128 + lane * 2) = packed;
    float2 g2 = *(const float2*)(gw + lane * 2);
    float gp = o0 * g2.x + o1 * g2.y;
    #pragma unroll
    for (int m = 1; m < 64; m <<= 1) gp += __shfl_xor(gp, m);
    if (lane == 0) gexpv[node] = exp2f((gp + gb[0]) * LOG2E);
}

// ---------------------------------------------------------------- pool: block/graph (fp16 hv)
__global__ __launch_bounds__(1024) void pool_kernel(const unsigned short* __restrict__ hvb,
                                                    const float* __restrict__ gexpv,
                                                    const int* __restrict__ batch,
                                                    float* __restrict__ gout,
                                                    int voff) {
    int b = blockIdx.x;
    int g = threadIdx.x >> 7;
    int ch = threadIdx.x & 127;
    int l = 0, r = NN;
    while (l < r) { int m = (l + r) >> 1; if (batch[m] < b) l = m + 1; else r = m; }
    int s0 = l;
    r = NN;
    while (l < r) { int m = (l + r) >> 1; if (batch[m] < b + 1) l = m + 1; else r = m; }
    int s1 = l;
    float acc = 0.f, wsum = 0.f;
    for (int n = s0 + g; n < s1; n += 8) {
        float w = gexpv[n];
        wsum += w;
        acc = fmaf(w, h2f(hvb[(size_t)n * 128 + ch]), acc);
    }
    __shared__ float sacc[8][128];
    __shared__ float sws[8];
    sacc[g][ch] = acc;
    if (ch == 0) sws[g] = wsum;
    __syncthreads();
    if (g == 0) {
        float a = 0.f, w = 0.f;
        #pragma unroll
        for (int i = 0; i < 8; i++) { a += sacc[i][ch]; w += sws[i]; }
        gout[b * 384 + voff + ch] = (s1 > s0) ? a / w : 0.f;
    }
}

// ---------------------------------------------------------------- classifier
__global__ __launch_bounds__(128) void clf_kernel(const float* __restrict__ gout,
                                                  const float* __restrict__ W1,
                                                  const float* __restrict__ b1,
                                                  const float* __restrict__ W2,
                                                  const float* __restrict__ b2,
                                                  float* __restrict__ out) {
    int b = blockIdx.x;
    int j = threadIdx.x;
    float acc = b1[j];
    for (int k = 0; k < 384; k++) acc = fmaf(gout[b * 384 + k], W1[k * 128 + j], acc);
    acc = acc > 0.f ? acc : 0.01f * acc;
    float p = acc * W2[j];
    #pragma unroll
    for (int m = 1; m < 64; m <<= 1) p += __shfl_xor(p, m);
    __shared__ float sh[2];
    if ((j & 63) == 0) sh[j >> 6] = p;
    __syncthreads();
    if (j == 0) out[b] = sh[0] + sh[1] + b2[0];
}

// ---------------------------------------------------------------- launch
extern "C" void kernel_launch(void* const* d_in, const int* in_sizes, int n_in,
                              void* d_out, int out_size, void* d_ws, size_t ws_size,
                              hipStream_t stream) {
    const float* x      = (const float*)d_in[0];
    const int*   ei[3]  = {(const int*)d_in[1], (const int*)d_in[2], (const int*)d_in[3]};
    const int*   batch  = (const int*)d_in[4];
    const float* ln_g   = (const float*)d_in[5];
    const float* ln_b   = (const float*)d_in[6];
    const float* proj_W = (const float*)d_in[7];
    const float* proj_b = (const float*)d_in[8];
    const float* Wv[3]  = {(const float*)d_in[9],  (const float*)d_in[13], (const float*)d_in[17]};
    const float* asv[3] = {(const float*)d_in[10], (const float*)d_in[14], (const float*)d_in[18]};
    const float* adv[3] = {(const float*)d_in[11], (const float*)d_in[15], (const float*)d_in[19]};
    const float* bv[3]  = {(const float*)d_in[12], (const float*)d_in[16], (const float*)d_in[20]};
    const float* gate_W = (const float*)d_in[21];
    const float* gate_b = (const float*)d_in[22];
    const float* clf_W1 = (const float*)d_in[23];
    const float* clf_b1 = (const float*)d_in[24];
    const float* clf_W2 = (const float*)d_in[25];
    const float* clf_b2 = (const float*)d_in[26];
    float* out = (float*)d_out;

    (void)in_sizes; (void)n_in; (void)out_size; (void)ws_size;

    // ---- workspace layout ----
    char* base = (char*)d_ws;
    size_t off = 0;
    auto nxt = [&](size_t bytes) { char* r = base + off; off += (bytes + 255) & ~(size_t)255; return r; };
    unsigned short* h0   = (unsigned short*)nxt((size_t)ROWS_PAD * 128 * 2);   // bf16
    unsigned short* xh   = (unsigned short*)nxt((size_t)ROWS_PAD * 128 * 2);   // fp16
    unsigned short* hvb  = (unsigned short*)nxt((size_t)NN * 128 * 2);         // fp16
    unsigned short* WT   = (unsigned short*)nxt(4 * 16384 * 2);
    float* c12    = (float*)nxt(256 * 4);
    float* a_src  = (float*)nxt((size_t)ROWS_PAD * 4 * 4);
    float* a_dst  = (float*)nxt((size_t)ROWS_PAD * 4 * 4);
    float* gexpv  = (float*)nxt(NN * 4);
    float* gout   = (float*)nxt(BB * 384 * 4);
    int* deg3     = (int*)nxt(3 * NN * 4);
    int* start3   = (int*)nxt(3 * NN * 4);
    unsigned int* ebuf3 = (unsigned int*)nxt(((size_t)3 * EPV + 64) * 4);
    int* btot     = (int*)nxt(3 * NBUCK * 4);
    int* ebstart  = (int*)nxt(3 * (NBUCK + 1) * 4);
    int* bstart   = (int*)nxt(3 * (NBUCK + 1) * 4);
    int* blockHistT = (int*)nxt((size_t)NBUCK * TOTB * 4);
    int* blockOffT  = (int*)nxt((size_t)NBUCK * TOTB * 4);
    unsigned int* pairbuf = (unsigned int*)nxt((size_t)3 * EE * 4);

    // 1-2. weight packs + LN affine constants
    pack_wt<<<dim3(64, 4), 256, 0, stream>>>(proj_W, Wv[0], Wv[1], Wv[2], ln_g, WT);
    ln_consts<<<1, 128, 0, stream>>>(proj_W, ln_g, ln_b, c12);
    // 3. CSR histogram || proj GEMM (fused LN)
    fat_hist_proj<<<TOTB + 782, 256, 0, stream>>>(ei[0], ei[1], ei[2], blockHistT,
                                                  x, WT, c12, proj_b, h0);
    // 4-6. bucket totals, starts, per-block offsets
    csr_bsum<<<(3 * NBUCK + 3) / 4, 256, 0, stream>>>(blockHistT, btot);
    csr_scan<<<3, 512, 0, stream>>>(btot, ebstart, bstart);
    csr_boff<<<(3 * NBUCK + 3) / 4, 256, 0, stream>>>(blockHistT, ebstart, blockOffT);
    // 7. coarse scatter || view-0 GEMM
    fat_scatter_view<<<TOTB + 782, 256, 0, stream>>>(ei[0], ei[1], ei[2], blockOffT, pairbuf,
                                                     h0, WT, asv[0], adv[0], xh, a_src, a_dst);
    // 8. fine sort (+self-loops)
    csr_fine<<<3 * NBUCK, 256, 0, stream>>>(pairbuf, btot, ebstart, bstart, deg3, start3, ebuf3);
    // 9+. per view: (GEMM for v>0), aggregate, pool
    for (int v = 0; v < 3; v++) {
        if (v > 0)
            gemm_view<<<782, 256, 0, stream>>>(h0, WT + (size_t)(1 + v) * 16384,
                                               asv[v], adv[v], xh, a_src, a_dst);
        aggregate_kernel<<<25000, 256, 0, stream>>>(xh, start3 + v * NN, deg3 + v * NN,
                                                    ebuf3 + (size_t)v * EPV,
                                                    a_src, a_dst,
                                                    bv[v], gate_W, gate_b, hvb, gexpv);
        pool_kernel<<<256, 1024, 0, stream>>>(hvb, gexpv, batch, gout, v * 128);
    }
    // classifier
    clf_kernel<<<256, 128, 0, stream>>>(gout, clf_W1, clf_b1, clf_W2, clf_b2, out);
}